// Round 2
// baseline (1082.992 us; speedup 1.0000x reference)
//
#include <hip/hip_runtime.h>
#include <hip/hip_bf16.h>

typedef __hip_bfloat16 bf16;

#define B_ 2
#define TIN_ 12
#define N_ 800
#define F_ 2
#define H_ 6
#define D_ 8
#define C_ 48
#define TP_ 10
#define KW_ 14
#define SCALE 0.35355339059327373f  // 1/sqrt(8)

__device__ __forceinline__ float b2f(bf16 v) { return __bfloat162float(v); }
__device__ __forceinline__ float sigm(float x) { return 1.0f / (1.0f + __expf(-x)); }
__device__ __forceinline__ float tanh_(float x) {
  float e = __expf(-2.0f * x);
  return 2.0f / (1.0f + e) - 1.0f;   // safe at +/-inf
}
// dual-dtype load/store: flag==1 -> buffers are float32, else bf16
__device__ __forceinline__ float LD(const void* p, size_t i, int f32) {
  return f32 ? ((const float*)p)[i] : __bfloat162float(((const bf16*)p)[i]);
}
__device__ __forceinline__ void STO(void* p, size_t i, float v, int f32) {
  if (f32) ((float*)p)[i] = v;
  else ((bf16*)p)[i] = __float2bfloat16(v);
}

// ---------------- Kernel 0: dtype detector --------------------------------
// Inspect low 16-bit halves of first 64 u32 words of x. True-bf16 data has
// plausible exponents there; f32 data has random mantissa bits -> outliers.
__global__ void k_detect(const unsigned int* __restrict__ xw, int* __restrict__ flag) {
  int lane = threadIdx.x;  // 64
  unsigned int w = xw[lane];
  int e = (w >> 7) & 0xFF;                      // exponent of LOW bf16 slot
  int bad = ((e >= 1 && e < 96) || (e > 150)) ? 1 : 0;
  unsigned long long m = __ballot(bad);
  if (lane == 0) *flag = (__popcll(m) >= 16) ? 1 : 0;
}

// ---------------- Kernel A: temporal causal attention (t = 1..11 only) -----
__global__ void k_temporal(const int* __restrict__ dtf,
                           const void* __restrict__ x,
                           const void* __restrict__ Wq, const void* __restrict__ Wk,
                           const void* __restrict__ Wv,
                           const void* __restrict__ bq, const void* __restrict__ bk,
                           const void* __restrict__ bv,
                           float* __restrict__ att_t) {
  const int f32 = *dtf;
  int gid = blockIdx.x * blockDim.x + threadIdx.x;
  const int total = B_ * (TIN_ - 1) * H_ * N_;
  if (gid >= total) return;
  int n = gid % N_;
  int r = gid / N_;
  int h = r % H_;  r /= H_;
  int t = (r % (TIN_ - 1)) + 1;
  int b = r / (TIN_ - 1);

  float wq[F_][D_], wk[F_][D_], wv[F_][D_], bqv[D_], bkv[D_], bvv[D_];
#pragma unroll
  for (int f = 0; f < F_; ++f)
#pragma unroll
    for (int d = 0; d < D_; ++d) {
      wq[f][d] = LD(Wq, (h * F_ + f) * D_ + d, f32);
      wk[f][d] = LD(Wk, (h * F_ + f) * D_ + d, f32);
      wv[f][d] = LD(Wv, (h * F_ + f) * D_ + d, f32);
    }
#pragma unroll
  for (int d = 0; d < D_; ++d) {
    bqv[d] = LD(bq, h * D_ + d, f32);
    bkv[d] = LD(bk, h * D_ + d, f32);
    bvv[d] = LD(bv, h * D_ + d, f32);
  }

  float xt0 = LD(x, ((b * TIN_ + t) * N_ + n) * F_ + 0, f32);
  float xt1 = LD(x, ((b * TIN_ + t) * N_ + n) * F_ + 1, f32);
  float q[D_];
#pragma unroll
  for (int d = 0; d < D_; ++d) q[d] = xt0 * wq[0][d] + xt1 * wq[1][d] + bqv[d];

  float sc[TIN_];
  float mx = -1e30f;
#pragma unroll
  for (int s = 0; s < TIN_; ++s) {
    float xs0 = LD(x, ((b * TIN_ + s) * N_ + n) * F_ + 0, f32);
    float xs1 = LD(x, ((b * TIN_ + s) * N_ + n) * F_ + 1, f32);
    float dot = 0.f;
#pragma unroll
    for (int d = 0; d < D_; ++d)
      dot += q[d] * (xs0 * wk[0][d] + xs1 * wk[1][d] + bkv[d]);
    dot *= SCALE;
    sc[s] = (s <= t) ? dot : -1e30f;
    mx = fmaxf(mx, sc[s]);
  }
  float sum = 0.f;
#pragma unroll
  for (int s = 0; s < TIN_; ++s) {
    float p = __expf(sc[s] - mx);
    sc[s] = p;
    sum += p;
  }
  float inv = 1.0f / sum;
  float acc[D_];
#pragma unroll
  for (int d = 0; d < D_; ++d) acc[d] = 0.f;
#pragma unroll
  for (int s = 0; s < TIN_; ++s) {
    float xs0 = LD(x, ((b * TIN_ + s) * N_ + n) * F_ + 0, f32);
    float xs1 = LD(x, ((b * TIN_ + s) * N_ + n) * F_ + 1, f32);
#pragma unroll
    for (int d = 0; d < D_; ++d)
      acc[d] += sc[s] * (xs0 * wv[0][d] + xs1 * wv[1][d] + bvv[d]);
  }
  float* o = att_t + ((size_t)((b * TIN_ + t) * N_ + n)) * C_ + h * D_;
#pragma unroll
  for (int d = 0; d < D_; ++d) o[d] = acc[d] * inv;
}

// ---------------- Kernel B: spatial attention (t = 1..11 only) -------------
#define ROWT 4
#define RPB 200
__global__ __launch_bounds__(256) void k_spatial(
    const int* __restrict__ dtf,
    const void* __restrict__ x,
    const void* __restrict__ Wq, const void* __restrict__ Wk, const void* __restrict__ Wv,
    const void* __restrict__ bq, const void* __restrict__ bk, const void* __restrict__ bv,
    float* __restrict__ att_st) {
  const int f32 = *dtf;
  __shared__ float4 Ks[N_][2];
  __shared__ float4 Vs[N_][2];
  int rt = blockIdx.x % ROWT;
  int r = blockIdx.x / ROWT;
  int h = r % H_;  r /= H_;
  int t = (r % (TIN_ - 1)) + 1;
  int b = r / (TIN_ - 1);
  int tid = threadIdx.x;

  float wk[F_][D_], wv[F_][D_], bkv[D_], bvv[D_];
#pragma unroll
  for (int f = 0; f < F_; ++f)
#pragma unroll
    for (int d = 0; d < D_; ++d) {
      wk[f][d] = LD(Wk, (h * F_ + f) * D_ + d, f32);
      wv[f][d] = LD(Wv, (h * F_ + f) * D_ + d, f32);
    }
#pragma unroll
  for (int d = 0; d < D_; ++d) {
    bkv[d] = LD(bk, h * D_ + d, f32);
    bvv[d] = LD(bv, h * D_ + d, f32);
  }
  for (int m = tid; m < N_; m += 256) {
    float x0 = LD(x, ((b * TIN_ + t) * N_ + m) * F_ + 0, f32);
    float x1 = LD(x, ((b * TIN_ + t) * N_ + m) * F_ + 1, f32);
    float kk[D_], vv[D_];
#pragma unroll
    for (int d = 0; d < D_; ++d) {
      kk[d] = x0 * wk[0][d] + x1 * wk[1][d] + bkv[d];
      vv[d] = x0 * wv[0][d] + x1 * wv[1][d] + bvv[d];
    }
    Ks[m][0] = make_float4(kk[0], kk[1], kk[2], kk[3]);
    Ks[m][1] = make_float4(kk[4], kk[5], kk[6], kk[7]);
    Vs[m][0] = make_float4(vv[0], vv[1], vv[2], vv[3]);
    Vs[m][1] = make_float4(vv[4], vv[5], vv[6], vv[7]);
  }
  __syncthreads();
  if (tid >= RPB) return;
  int n = rt * RPB + tid;

  float wq[F_][D_], bqv[D_];
#pragma unroll
  for (int f = 0; f < F_; ++f)
#pragma unroll
    for (int d = 0; d < D_; ++d) wq[f][d] = LD(Wq, (h * F_ + f) * D_ + d, f32);
#pragma unroll
  for (int d = 0; d < D_; ++d) bqv[d] = LD(bq, h * D_ + d, f32);
  float x0 = LD(x, ((b * TIN_ + t) * N_ + n) * F_ + 0, f32);
  float x1 = LD(x, ((b * TIN_ + t) * N_ + n) * F_ + 1, f32);
  float q[D_];
#pragma unroll
  for (int d = 0; d < D_; ++d) q[d] = (x0 * wq[0][d] + x1 * wq[1][d] + bqv[d]) * SCALE;

  float sum = 0.f;
  float a0 = 0, a1 = 0, a2 = 0, a3 = 0, a4 = 0, a5 = 0, a6 = 0, a7 = 0;
  for (int m = 0; m < N_; ++m) {
    float4 ka = Ks[m][0], kb = Ks[m][1];
    float s = q[0] * ka.x + q[1] * ka.y + q[2] * ka.z + q[3] * ka.w +
              q[4] * kb.x + q[5] * kb.y + q[6] * kb.z + q[7] * kb.w;
    float p = __expf(s);  // |s| small; no max-subtract needed (f32-safe)
    sum += p;
    float4 va = Vs[m][0], vb = Vs[m][1];
    a0 += p * va.x; a1 += p * va.y; a2 += p * va.z; a3 += p * va.w;
    a4 += p * vb.x; a5 += p * vb.y; a6 += p * vb.z; a7 += p * vb.w;
  }
  float inv = 1.0f / sum;
  float* o = att_st + ((size_t)((b * TIN_ + t) * N_ + n)) * C_ + h * D_;
  o[0] = a0 * inv; o[1] = a1 * inv; o[2] = a2 * inv; o[3] = a3 * inv;
  o[4] = a4 * inv; o[5] = a5 * inv; o[6] = a6 * inv; o[7] = a7 * inv;
}

// ---------------- Kernel C: output projections + concat --------------------
__global__ void k_proj(const int* __restrict__ dtf,
                       const float* __restrict__ att_t, const float* __restrict__ att_st,
                       const void* __restrict__ Wpt, const void* __restrict__ bpt,
                       const void* __restrict__ Wps, const void* __restrict__ bps,
                       float* __restrict__ att_stt) {
  const int f32 = *dtf;
  int gid = blockIdx.x * blockDim.x + threadIdx.x;
  const int total = B_ * (TIN_ - 1) * N_ * 96;
  if (gid >= total) return;
  int j = gid % 96;
  int rr = gid / 96;
  int n = rr % N_;
  int r2 = rr / N_;
  int t = (r2 % (TIN_ - 1)) + 1;
  int b = r2 / (TIN_ - 1);
  size_t row48 = ((size_t)((b * TIN_ + t) * N_ + n)) * C_;
  const float* src;
  const void *W, *bias;
  int jj;
  if (j < C_) { src = att_t + row48;  W = Wpt; bias = bpt; jj = j; }
  else        { src = att_st + row48; W = Wps; bias = bps; jj = j - C_; }
  float a = LD(bias, jj, f32);
#pragma unroll
  for (int i = 0; i < C_; ++i) a += src[i] * LD(W, i * C_ + jj, f32);
  att_stt[((size_t)((b * TIN_ + t) * N_ + n)) * 96 + j] = a;
}

// ---------------- Kernel D: fused encoder-GRU + conv1 + decoder-GRU + out --
__global__ __launch_bounds__(128) void k_fused(
    const int* __restrict__ dtf,
    const float* __restrict__ att_stt,
    const void* __restrict__ x, const void* __restrict__ T,
    const void* __restrict__ conv1_w, const void* __restrict__ conv1_b,
    const void* __restrict__ xhr_wz, const void* __restrict__ xhr_wr, const void* __restrict__ xhr_wh,
    const void* __restrict__ xhr_bz, const void* __restrict__ xhr_br, const void* __restrict__ xhr_bh,
    const void* __restrict__ last_wz, const void* __restrict__ last_wr, const void* __restrict__ last_wh,
    const void* __restrict__ last_bz, const void* __restrict__ last_br, const void* __restrict__ last_bh,
    const void* __restrict__ Wout, const void* __restrict__ bout,
    void* __restrict__ out) {
  const int f32 = *dtf;
  int b = blockIdx.x / N_;
  int n = blockIdx.x % N_;
  int tid = threadIdx.x;
  __shared__ float xh[144];           // [0:96] xi, [96:144] h (enc) / [48:96] h (dec)
  __shared__ float rh[C_];
  __shared__ float pre[TP_][C_];
  __shared__ float tpxl[TIN_ + TP_ + 1][2];

  if (tid < C_) xh[96 + tid] = 0.f;   // h0 = 0
  if (tid < TIN_ + TP_ + 1) {         // conv time-extended input (23 steps)
    int tau = tid;
    float v0, v1;
    if (tau < TIN_) {
      v0 = LD(x, ((b * TIN_ + tau) * N_ + n) * F_ + 0, f32);
      v1 = LD(x, ((b * TIN_ + tau) * N_ + n) * F_ + 1, f32);
    } else if (tau < TIN_ + TP_) {
      v0 = 0.f;
      v1 = LD(T, (b * TP_ + (tau - TIN_)) * N_ + n, f32);
    } else {  // wrap: tpx[:, :1] = x[:, 0:1]
      v0 = LD(x, ((b * TIN_ + 0) * N_ + n) * F_ + 0, f32);
      v1 = LD(x, ((b * TIN_ + 0) * N_ + n) * F_ + 1, f32);
    }
    tpxl[tau][0] = v0;
    tpxl[tau][1] = v1;
  }
  __syncthreads();
  for (int idx = tid; idx < TP_ * C_; idx += 128) {   // conv1 -> pre[t][c]
    int t = idx / C_, c = idx % C_;
    float a = LD(conv1_b, c, f32);
#pragma unroll
    for (int k = 0; k < KW_; ++k) {
      a += tpxl[t + k][0] * LD(conv1_w, (c * F_ + 0) * KW_ + k, f32);
      a += tpxl[t + k][1] * LD(conv1_w, (c * F_ + 1) * KW_ + k, f32);
    }
    pre[t][c] = a;
  }

  // ---- encoder GRU: t = 1..11, per-step weights ----
  float hnew = 0.f;
  for (int t = 1; t < TIN_; ++t) {
    __syncthreads();
    if (tid < 96) xh[tid] = att_stt[(((size_t)(b * TIN_ + t)) * N_ + n) * 96 + tid];
    __syncthreads();
    size_t wofs = (size_t)t * 144 * C_;
    float az = 0.f, h_old = 0.f;
    if (tid < C_) {
      int j = tid;
      az = LD(xhr_bz, ((size_t)t * N_ + n) * C_ + j, f32);
      for (int i = 0; i < 144; ++i) az += xh[i] * LD(xhr_wz, wofs + i * C_ + j, f32);
      h_old = xh[96 + j];
    } else if (tid < 96) {
      int j = tid - C_;
      float ar = LD(xhr_br, ((size_t)t * N_ + n) * C_ + j, f32);
      for (int i = 0; i < 144; ++i) ar += xh[i] * LD(xhr_wr, wofs + i * C_ + j, f32);
      rh[j] = sigm(ar) * xh[96 + j];
    }
    __syncthreads();
    if (tid < C_) {
      int j = tid;
      float ah = LD(xhr_bh, ((size_t)t * N_ + n) * C_ + j, f32);
      for (int i = 0; i < 96; ++i) ah += xh[i] * LD(xhr_wh, wofs + i * C_ + j, f32);
#pragma unroll
      for (int i = 0; i < C_; ++i) ah += rh[i] * LD(xhr_wh, wofs + (96 + i) * C_ + j, f32);
      float z = sigm(az);
      hnew = (1.f - z) * h_old + z * tanh_(ah);
    }
    __syncthreads();
    if (tid < C_) xh[96 + tid] = hnew;
  }
  __syncthreads();
  if (tid < C_) xh[C_ + tid] = xh[96 + tid];   // move h to dec slot [48:96]

  // ---- decoder GRU: t = 0..9, per-step weights; emit output each step ----
  for (int t = 0; t < TP_; ++t) {
    __syncthreads();
    if (tid < C_) xh[tid] = pre[t][tid];
    __syncthreads();
    size_t wofs = (size_t)t * 96 * C_;
    float az = 0.f, h_old = 0.f;
    if (tid < C_) {
      int j = tid;
      az = LD(last_bz, ((size_t)t * N_ + n) * C_ + j, f32);
      for (int i = 0; i < 96; ++i) az += xh[i] * LD(last_wz, wofs + i * C_ + j, f32);
      h_old = xh[C_ + j];
    } else if (tid < 96) {
      int j = tid - C_;
      float ar = LD(last_br, ((size_t)t * N_ + n) * C_ + j, f32);
      for (int i = 0; i < 96; ++i) ar += xh[i] * LD(last_wr, wofs + i * C_ + j, f32);
      rh[j] = sigm(ar) * xh[C_ + j];
    }
    __syncthreads();
    if (tid < C_) {
      int j = tid;
      float ah = LD(last_bh, ((size_t)t * N_ + n) * C_ + j, f32);
#pragma unroll
      for (int i = 0; i < C_; ++i) ah += xh[i] * LD(last_wh, wofs + i * C_ + j, f32);
#pragma unroll
      for (int i = 0; i < C_; ++i) ah += rh[i] * LD(last_wh, wofs + (C_ + i) * C_ + j, f32);
      float z = sigm(az);
      hnew = (1.f - z) * h_old + z * tanh_(ah);
    }
    __syncthreads();
    if (tid < C_) xh[C_ + tid] = hnew;
    __syncthreads();
    if (tid < 64) {   // out[b,t,n] = h . Wout + bout  (wave-0 reduce)
      float c = (tid < C_) ? xh[C_ + tid] * LD(Wout, tid, f32) : 0.f;
      for (int off = 32; off > 0; off >>= 1) c += __shfl_down(c, off, 64);
      if (tid == 0) STO(out, (b * TP_ + t) * N_ + n, c + LD(bout, 0, f32), f32);
    }
  }
}

// ---------------------------------------------------------------------------
extern "C" void kernel_launch(void* const* d_in, const int* in_sizes, int n_in,
                              void* d_out, int out_size, void* d_ws, size_t ws_size,
                              hipStream_t stream) {
  (void)in_sizes; (void)n_in; (void)out_size; (void)ws_size;
  const void* x       = d_in[0];
  const void* T       = d_in[1];
  /* d_in[2] = adj: all-True, multiplicative mask of 1.0 -> unused */
  const void* Wq_t    = d_in[3];
  const void* Wk_t    = d_in[4];
  const void* Wv_t    = d_in[5];
  const void* Wq_st   = d_in[6];
  const void* Wk_st   = d_in[7];
  const void* Wv_st   = d_in[8];
  const void* bq_t    = d_in[9];
  const void* bk_t    = d_in[10];
  const void* bv_t    = d_in[11];
  const void* bq_st   = d_in[12];
  const void* bk_st   = d_in[13];
  const void* bv_st   = d_in[14];
  const void* conv1_w = d_in[15];
  const void* conv1_b = d_in[16];
  const void* Wproj_t = d_in[17];
  const void* bproj_t = d_in[18];
  const void* Wproj_st= d_in[19];
  const void* bproj_st= d_in[20];
  const void* xhr_wz  = d_in[21];
  const void* xhr_wr  = d_in[22];
  const void* xhr_wh  = d_in[23];
  const void* xhr_bz  = d_in[24];
  const void* xhr_br  = d_in[25];
  const void* xhr_bh  = d_in[26];
  const void* last_wz = d_in[27];
  const void* last_wr = d_in[28];
  const void* last_wh = d_in[29];
  const void* last_bz = d_in[30];
  const void* last_br = d_in[31];
  const void* last_bh = d_in[32];
  const void* Wout    = d_in[33];
  const void* bout    = d_in[34];

  int* dtf = (int*)d_ws;
  float* att_t  = (float*)d_ws + 16;
  float* att_st = att_t + (size_t)B_ * TIN_ * N_ * C_;
  float* att_stt = att_st + (size_t)B_ * TIN_ * N_ * C_;

  k_detect<<<1, 64, 0, stream>>>((const unsigned int*)x, dtf);
  {
    int total = B_ * (TIN_ - 1) * H_ * N_;
    k_temporal<<<(total + 255) / 256, 256, 0, stream>>>(
        dtf, x, Wq_t, Wk_t, Wv_t, bq_t, bk_t, bv_t, att_t);
  }
  {
    int blocks = B_ * (TIN_ - 1) * H_ * ROWT;
    k_spatial<<<blocks, 256, 0, stream>>>(
        dtf, x, Wq_st, Wk_st, Wv_st, bq_st, bk_st, bv_st, att_st);
  }
  {
    int total = B_ * (TIN_ - 1) * N_ * 96;
    k_proj<<<(total + 255) / 256, 256, 0, stream>>>(
        dtf, att_t, att_st, Wproj_t, bproj_t, Wproj_st, bproj_st, att_stt);
  }
  k_fused<<<B_ * N_, 128, 0, stream>>>(
      dtf, att_stt, x, T, conv1_w, conv1_b,
      xhr_wz, xhr_wr, xhr_wh, xhr_bz, xhr_br, xhr_bh,
      last_wz, last_wr, last_wh, last_bz, last_br, last_bh,
      Wout, bout, out_size ? d_out : d_out);
}

// Round 3
// 426.901 us; speedup vs baseline: 2.5369x; 2.5369x over previous
//
#include <hip/hip_runtime.h>
#include <hip/hip_bf16.h>

typedef __hip_bfloat16 bf16;

#define B_ 2
#define TIN_ 12
#define N_ 800
#define F_ 2
#define H_ 6
#define D_ 8
#define C_ 48
#define TP_ 10
#define KW_ 14
#define SCALE 0.35355339059327373f  // 1/sqrt(8)

__device__ __forceinline__ float sigm(float x) { return 1.0f / (1.0f + __expf(-x)); }
__device__ __forceinline__ float tanh_(float x) {
  float e = __expf(-2.0f * x);
  return 2.0f / (1.0f + e) - 1.0f;
}
// dual-dtype scalar loads (overload on pointer type; kernels template on TI)
__device__ __forceinline__ float ldc(const float* p, size_t i) { return p[i]; }
__device__ __forceinline__ float ldc(const bf16* p, size_t i) { return __bfloat162float(p[i]); }
__device__ __forceinline__ void ld4(const float* p, size_t i, float o[4]) {
  float4 v = *(const float4*)(p + i);
  o[0] = v.x; o[1] = v.y; o[2] = v.z; o[3] = v.w;
}
__device__ __forceinline__ void ld4(const bf16* p, size_t i, float o[4]) {
  ushort4 v = *(const ushort4*)((const unsigned short*)p + i);
  o[0] = __uint_as_float((unsigned)v.x << 16);
  o[1] = __uint_as_float((unsigned)v.y << 16);
  o[2] = __uint_as_float((unsigned)v.z << 16);
  o[3] = __uint_as_float((unsigned)v.w << 16);
}
__device__ __forceinline__ void sto(float* p, size_t i, float v) { p[i] = v; }
__device__ __forceinline__ void sto(bf16* p, size_t i, float v) { p[i] = __float2bfloat16(v); }
// scratch bf16 helpers (scratch is ALWAYS bf16 regardless of input dtype)
__device__ __forceinline__ float sld(const bf16* p, size_t i) { return __bfloat162float(p[i]); }
__device__ __forceinline__ void ld4s(const bf16* p, size_t i, float o[4]) { ld4(p, i, o); }
__device__ __forceinline__ void st4s(bf16* p, size_t i, const float v[4]) {
  ushort4 u;
  u.x = __bfloat16_as_ushort(__float2bfloat16(v[0]));
  u.y = __bfloat16_as_ushort(__float2bfloat16(v[1]));
  u.z = __bfloat16_as_ushort(__float2bfloat16(v[2]));
  u.w = __bfloat16_as_ushort(__float2bfloat16(v[3]));
  *(ushort4*)((unsigned short*)p + i) = u;
}

// ---------------- Kernel 0: dtype detector --------------------------------
__global__ void k_detect(const unsigned int* __restrict__ xw, int* __restrict__ flag) {
  int lane = threadIdx.x;  // 64
  unsigned int w = xw[lane];
  int e = (w >> 7) & 0xFF;  // exponent of LOW bf16 slot
  int bad = ((e >= 1 && e < 96) || (e > 150)) ? 1 : 0;
  unsigned long long m = __ballot(bad);
  if (lane == 0) *flag = (__popcll(m) >= 16) ? 1 : 0;
}

// ---------------- Kernel A: temporal causal attention (t=1..11) -----------
template <typename TI>
__device__ __forceinline__ void temporal_body(
    const TI* x, const TI* Wq, const TI* Wk, const TI* Wv,
    const TI* bq, const TI* bk, const TI* bv, bf16* att_t) {
  int gid = blockIdx.x * blockDim.x + threadIdx.x;
  const int total = B_ * (TIN_ - 1) * H_ * N_;
  if (gid >= total) return;
  int n = gid % N_;
  int r = gid / N_;
  int h = r % H_;  r /= H_;
  int t = (r % (TIN_ - 1)) + 1;
  int b = r / (TIN_ - 1);

  float wq[F_][D_], wk[F_][D_], wv[F_][D_], bqv[D_], bkv[D_], bvv[D_];
#pragma unroll
  for (int f = 0; f < F_; ++f)
#pragma unroll
    for (int d = 0; d < D_; ++d) {
      wq[f][d] = ldc(Wq, (h * F_ + f) * D_ + d);
      wk[f][d] = ldc(Wk, (h * F_ + f) * D_ + d);
      wv[f][d] = ldc(Wv, (h * F_ + f) * D_ + d);
    }
#pragma unroll
  for (int d = 0; d < D_; ++d) {
    bqv[d] = ldc(bq, h * D_ + d);
    bkv[d] = ldc(bk, h * D_ + d);
    bvv[d] = ldc(bv, h * D_ + d);
  }
  float xt0 = ldc(x, ((b * TIN_ + t) * N_ + n) * F_ + 0);
  float xt1 = ldc(x, ((b * TIN_ + t) * N_ + n) * F_ + 1);
  float q[D_];
#pragma unroll
  for (int d = 0; d < D_; ++d) q[d] = xt0 * wq[0][d] + xt1 * wq[1][d] + bqv[d];

  float sc[TIN_];
  float mx = -1e30f;
#pragma unroll
  for (int s = 0; s < TIN_; ++s) {
    float xs0 = ldc(x, ((b * TIN_ + s) * N_ + n) * F_ + 0);
    float xs1 = ldc(x, ((b * TIN_ + s) * N_ + n) * F_ + 1);
    float dot = 0.f;
#pragma unroll
    for (int d = 0; d < D_; ++d)
      dot += q[d] * (xs0 * wk[0][d] + xs1 * wk[1][d] + bkv[d]);
    dot *= SCALE;
    sc[s] = (s <= t) ? dot : -1e30f;
    mx = fmaxf(mx, sc[s]);
  }
  float sum = 0.f;
#pragma unroll
  for (int s = 0; s < TIN_; ++s) {
    float p = __expf(sc[s] - mx);
    sc[s] = p;
    sum += p;
  }
  float inv = 1.0f / sum;
  float acc[D_];
#pragma unroll
  for (int d = 0; d < D_; ++d) acc[d] = 0.f;
#pragma unroll
  for (int s = 0; s < TIN_; ++s) {
    float xs0 = ldc(x, ((b * TIN_ + s) * N_ + n) * F_ + 0);
    float xs1 = ldc(x, ((b * TIN_ + s) * N_ + n) * F_ + 1);
#pragma unroll
    for (int d = 0; d < D_; ++d)
      acc[d] += sc[s] * (xs0 * wv[0][d] + xs1 * wv[1][d] + bvv[d]);
  }
  bf16* o = att_t + ((size_t)((b * 11 + (t - 1)) * N_ + n)) * C_ + h * D_;
#pragma unroll
  for (int d = 0; d < D_; ++d) o[d] = __float2bfloat16(acc[d] * inv);
}
__global__ void k_temporal(const int* dtf, const void* x, const void* Wq, const void* Wk,
                           const void* Wv, const void* bq, const void* bk, const void* bv,
                           bf16* att_t) {
  if (*dtf)
    temporal_body<float>((const float*)x, (const float*)Wq, (const float*)Wk, (const float*)Wv,
                         (const float*)bq, (const float*)bk, (const float*)bv, att_t);
  else
    temporal_body<bf16>((const bf16*)x, (const bf16*)Wq, (const bf16*)Wk, (const bf16*)Wv,
                        (const bf16*)bq, (const bf16*)bk, (const bf16*)bv, att_t);
}

// ---------------- Kernel B: spatial attention (t=1..11) -------------------
#define ROWT 4
#define RPB 200
template <typename TI>
__device__ __forceinline__ void spatial_body(
    const TI* x, const TI* Wq, const TI* Wk, const TI* Wv,
    const TI* bq, const TI* bk, const TI* bv, bf16* att_st) {
  __shared__ float4 Ks[N_][2];
  __shared__ float4 Vs[N_][2];
  int rt = blockIdx.x % ROWT;
  int r = blockIdx.x / ROWT;
  int h = r % H_;  r /= H_;
  int t = (r % (TIN_ - 1)) + 1;
  int b = r / (TIN_ - 1);
  int tid = threadIdx.x;

  float wk[F_][D_], wv[F_][D_], bkv[D_], bvv[D_];
#pragma unroll
  for (int f = 0; f < F_; ++f)
#pragma unroll
    for (int d = 0; d < D_; ++d) {
      wk[f][d] = ldc(Wk, (h * F_ + f) * D_ + d);
      wv[f][d] = ldc(Wv, (h * F_ + f) * D_ + d);
    }
#pragma unroll
  for (int d = 0; d < D_; ++d) {
    bkv[d] = ldc(bk, h * D_ + d);
    bvv[d] = ldc(bv, h * D_ + d);
  }
  for (int m = tid; m < N_; m += 256) {
    float x0 = ldc(x, ((b * TIN_ + t) * N_ + m) * F_ + 0);
    float x1 = ldc(x, ((b * TIN_ + t) * N_ + m) * F_ + 1);
    float kk[D_], vv[D_];
#pragma unroll
    for (int d = 0; d < D_; ++d) {
      kk[d] = x0 * wk[0][d] + x1 * wk[1][d] + bkv[d];
      vv[d] = x0 * wv[0][d] + x1 * wv[1][d] + bvv[d];
    }
    Ks[m][0] = make_float4(kk[0], kk[1], kk[2], kk[3]);
    Ks[m][1] = make_float4(kk[4], kk[5], kk[6], kk[7]);
    Vs[m][0] = make_float4(vv[0], vv[1], vv[2], vv[3]);
    Vs[m][1] = make_float4(vv[4], vv[5], vv[6], vv[7]);
  }
  __syncthreads();
  if (tid >= RPB) return;
  int n = rt * RPB + tid;

  float wq[F_][D_], bqv[D_];
#pragma unroll
  for (int f = 0; f < F_; ++f)
#pragma unroll
    for (int d = 0; d < D_; ++d) wq[f][d] = ldc(Wq, (h * F_ + f) * D_ + d);
#pragma unroll
  for (int d = 0; d < D_; ++d) bqv[d] = ldc(bq, h * D_ + d);
  float x0 = ldc(x, ((b * TIN_ + t) * N_ + n) * F_ + 0);
  float x1 = ldc(x, ((b * TIN_ + t) * N_ + n) * F_ + 1);
  float q[D_];
#pragma unroll
  for (int d = 0; d < D_; ++d) q[d] = (x0 * wq[0][d] + x1 * wq[1][d] + bqv[d]) * SCALE;

  float sum = 0.f;
  float a0 = 0, a1 = 0, a2 = 0, a3 = 0, a4 = 0, a5 = 0, a6 = 0, a7 = 0;
  for (int m = 0; m < N_; ++m) {
    float4 ka = Ks[m][0], kb = Ks[m][1];
    float s = q[0] * ka.x + q[1] * ka.y + q[2] * ka.z + q[3] * ka.w +
              q[4] * kb.x + q[5] * kb.y + q[6] * kb.z + q[7] * kb.w;
    float p = __expf(s);
    sum += p;
    float4 va = Vs[m][0], vb = Vs[m][1];
    a0 += p * va.x; a1 += p * va.y; a2 += p * va.z; a3 += p * va.w;
    a4 += p * vb.x; a5 += p * vb.y; a6 += p * vb.z; a7 += p * vb.w;
  }
  float inv = 1.0f / sum;
  bf16* o = att_st + ((size_t)((b * 11 + (t - 1)) * N_ + n)) * C_ + h * D_;
  o[0] = __float2bfloat16(a0 * inv); o[1] = __float2bfloat16(a1 * inv);
  o[2] = __float2bfloat16(a2 * inv); o[3] = __float2bfloat16(a3 * inv);
  o[4] = __float2bfloat16(a4 * inv); o[5] = __float2bfloat16(a5 * inv);
  o[6] = __float2bfloat16(a6 * inv); o[7] = __float2bfloat16(a7 * inv);
}
__global__ __launch_bounds__(256) void k_spatial(
    const int* dtf, const void* x, const void* Wq, const void* Wk, const void* Wv,
    const void* bq, const void* bk, const void* bv, bf16* att_st) {
  if (*dtf)
    spatial_body<float>((const float*)x, (const float*)Wq, (const float*)Wk, (const float*)Wv,
                        (const float*)bq, (const float*)bk, (const float*)bv, att_st);
  else
    spatial_body<bf16>((const bf16*)x, (const bf16*)Wq, (const bf16*)Wk, (const bf16*)Wv,
                       (const bf16*)bq, (const bf16*)bk, (const bf16*)bv, att_st);
}

// ---------------- Kernel C: proj + encoder x-parts ------------------------
// grid (13 tiles, 11 t, 2 b), 192 threads = 16 rowgroups x 12 j-lanes.
template <typename TI>
__device__ __forceinline__ void projx_body(
    const bf16* att_t, const bf16* att_st,
    const TI* Wpt, const TI* bpt, const TI* Wps, const TI* bps,
    const TI* xhr_wz, const TI* xhr_wr, const TI* xhr_wh,
    const TI* xhr_bz, const TI* xhr_br, const TI* xhr_bh,
    bf16* encx) {
  __shared__ unsigned short raw[64][96];
  __shared__ float catS[64][100];
  __shared__ float Wp[2][48][48];
  int tile = blockIdx.x, ty = blockIdx.y, b = blockIdx.z;
  int t = ty + 1;
  int tid = threadIdx.x;
  int rw = tid / 12, jl = tid % 12;

  for (int p = 0; p < 24; ++p) {  // stage Wp (4608)
    int e = tid + p * 192;
    int half = e / 2304, k = (e % 2304) / 48, i = e % 48;
    Wp[half][k][i] = half ? ldc(Wps, k * 48 + i) : ldc(Wpt, k * 48 + i);
  }
  for (int p = 0; p < 32; ++p) {  // stage raw att rows (6144)
    int e = tid + p * 192;
    int rr = e / 96, c = e % 96;
    int n = tile * 64 + rr; if (n > 799) n = 799;
    size_t base = ((size_t)((b * 11 + ty) * N_ + n)) * C_;
    bf16 v = (c < 48) ? att_t[base + c] : att_st[base + (c - 48)];
    raw[rr][c] = __bfloat16_as_ushort(v);
  }
  __syncthreads();
  // cat phase: rows rw*4..+3, outputs i0 = jl*8 (jl<6: att_t half, else att_st)
  {
    int half = (jl >= 6);
    int ii0 = jl * 8 - half * 48;
    float acc[4][8];
#pragma unroll
    for (int q = 0; q < 4; ++q)
#pragma unroll
      for (int m = 0; m < 8; ++m)
        acc[q][m] = half ? ldc(bps, ii0 + m) : ldc(bpt, ii0 + m);
    for (int k = 0; k < 48; ++k) {
      float rv[4];
#pragma unroll
      for (int q = 0; q < 4; ++q)
        rv[q] = __uint_as_float((unsigned)raw[rw * 4 + q][half * 48 + k] << 16);
      const float4 wa = *(const float4*)&Wp[half][k][ii0];
      const float4 wb = *(const float4*)&Wp[half][k][ii0 + 4];
      float w8[8] = {wa.x, wa.y, wa.z, wa.w, wb.x, wb.y, wb.z, wb.w};
#pragma unroll
      for (int q = 0; q < 4; ++q)
#pragma unroll
        for (int m = 0; m < 8; ++m) acc[q][m] += rv[q] * w8[m];
    }
#pragma unroll
    for (int q = 0; q < 4; ++q) {
      *(float4*)&catS[rw * 4 + q][jl * 8] = make_float4(acc[q][0], acc[q][1], acc[q][2], acc[q][3]);
      *(float4*)&catS[rw * 4 + q][jl * 8 + 4] = make_float4(acc[q][4], acc[q][5], acc[q][6], acc[q][7]);
    }
  }
  __syncthreads();
  // encx phase: 12 outputs j0r=jl*12 (single gate per lane), weights from global
  {
    int j0r = jl * 12;
    int g = j0r / 48, jj0 = j0r % 48;
    const TI* wx = (g == 0) ? xhr_wz : (g == 1) ? xhr_wr : xhr_wh;
    const TI* bx = (g == 0) ? xhr_bz : (g == 1) ? xhr_br : xhr_bh;
    float acc[4][12];
#pragma unroll
    for (int q = 0; q < 4; ++q)
#pragma unroll
      for (int m = 0; m < 12; ++m) acc[q][m] = 0.f;
    for (int i = 0; i < 96; ++i) {
      float w12[12];
      size_t wb = ((size_t)t * 144 + i) * 48 + jj0;
      ld4(wx, wb, w12); ld4(wx, wb + 4, w12 + 4); ld4(wx, wb + 8, w12 + 8);
      float cv[4];
#pragma unroll
      for (int q = 0; q < 4; ++q) cv[q] = catS[rw * 4 + q][i];
#pragma unroll
      for (int q = 0; q < 4; ++q)
#pragma unroll
        for (int m = 0; m < 12; ++m) acc[q][m] += cv[q] * w12[m];
    }
#pragma unroll
    for (int q = 0; q < 4; ++q) {
      int n = tile * 64 + rw * 4 + q;
      if (n < 800) {
        float v[12];
#pragma unroll
        for (int m = 0; m < 12; ++m)
          v[m] = acc[q][m] + ldc(bx, ((size_t)t * N_ + n) * C_ + jj0 + m);
        size_t ob = ((size_t)((b * 11 + ty) * N_ + n)) * 144 + j0r;
        st4s(encx, ob, v); st4s(encx, ob + 4, v + 4); st4s(encx, ob + 8, v + 8);
      }
    }
  }
}
__global__ __launch_bounds__(192) void k_projx(
    const int* dtf, const bf16* att_t, const bf16* att_st,
    const void* Wpt, const void* bpt, const void* Wps, const void* bps,
    const void* xwz, const void* xwr, const void* xwh,
    const void* xbz, const void* xbr, const void* xbh, bf16* encx) {
  if (*dtf)
    projx_body<float>(att_t, att_st, (const float*)Wpt, (const float*)bpt, (const float*)Wps,
                      (const float*)bps, (const float*)xwz, (const float*)xwr, (const float*)xwh,
                      (const float*)xbz, (const float*)xbr, (const float*)xbh, encx);
  else
    projx_body<bf16>(att_t, att_st, (const bf16*)Wpt, (const bf16*)bpt, (const bf16*)Wps,
                     (const bf16*)bps, (const bf16*)xwz, (const bf16*)xwr, (const bf16*)xwh,
                     (const bf16*)xbz, (const bf16*)xbr, (const bf16*)xbh, encx);
}

// ---------------- Kernel D: conv1 + decoder x-parts -----------------------
// grid (13 tiles, 10 t, 2 b), 192 threads.
template <typename TI>
__device__ __forceinline__ void convx_body(
    const TI* x, const TI* T,
    const TI* conv1_w, const TI* conv1_b,
    const TI* lwz, const TI* lwr, const TI* lwh,
    const TI* lbz, const TI* lbr, const TI* lbh,
    bf16* decx) {
  __shared__ float tpw[64][KW_][2];
  __shared__ float cw[2][KW_][48];
  __shared__ float preS[64][48];
  __shared__ float Wlx[48][144];
  int tile = blockIdx.x, t = blockIdx.y, b = blockIdx.z;
  int tid = threadIdx.x;
  int rw = tid / 12, jl = tid % 12;

  for (int p = 0; p < 7; ++p) {  // conv weights transposed (1344)
    int e = tid + p * 192;
    int f = e / (KW_ * 48), rem = e % (KW_ * 48), k = rem / 48, c = rem % 48;
    cw[f][k][c] = ldc(conv1_w, (c * F_ + f) * KW_ + k);
  }
  for (int p = 0; p < 10; ++p) {  // time window (1792)
    int e = tid + p * 192;
    if (e < 64 * KW_ * 2) {
      int rr = e / (KW_ * 2), rem = e % (KW_ * 2), k = rem / 2, f = rem % 2;
      int n = tile * 64 + rr; if (n > 799) n = 799;
      int tau = t + k;
      float v;
      if (tau < TIN_) v = ldc(x, ((size_t)(b * TIN_ + tau) * N_ + n) * F_ + f);
      else if (tau < TIN_ + TP_) v = (f == 0) ? 0.f : ldc(T, (size_t)(b * TP_ + (tau - TIN_)) * N_ + n);
      else v = ldc(x, ((size_t)(b * TIN_ + 0) * N_ + n) * F_ + f);
      tpw[rr][k][f] = v;
    }
  }
  for (int p = 0; p < 36; ++p) {  // last_w x-part rows 0:48 (6912)
    int e = tid + p * 192;
    int i = e / 144, jg = e % 144, g = jg / 48, j = jg % 48;
    const TI* w = (g == 0) ? lwz : (g == 1) ? lwr : lwh;
    Wlx[i][jg] = ldc(w, ((size_t)t * 96 + i) * 48 + j);
  }
  __syncthreads();
  {  // conv: 4 rows x 4 channels
    int c0 = jl * 4;
    float acc[4][4];
#pragma unroll
    for (int q = 0; q < 4; ++q)
#pragma unroll
      for (int m = 0; m < 4; ++m) acc[q][m] = ldc(conv1_b, c0 + m);
#pragma unroll
    for (int f = 0; f < 2; ++f)
      for (int k = 0; k < KW_; ++k) {
        const float4 w4 = *(const float4*)&cw[f][k][c0];
        float wv[4] = {w4.x, w4.y, w4.z, w4.w};
#pragma unroll
        for (int q = 0; q < 4; ++q) {
          float tv = tpw[rw * 4 + q][k][f];
#pragma unroll
          for (int m = 0; m < 4; ++m) acc[q][m] += tv * wv[m];
        }
      }
#pragma unroll
    for (int q = 0; q < 4; ++q)
      *(float4*)&preS[rw * 4 + q][c0] = make_float4(acc[q][0], acc[q][1], acc[q][2], acc[q][3]);
  }
  __syncthreads();
  {  // decx: 4 rows x 12 outputs
    int j0r = jl * 12;
    int g = j0r / 48, jj0 = j0r % 48;
    const TI* bx = (g == 0) ? lbz : (g == 1) ? lbr : lbh;
    float acc[4][12];
#pragma unroll
    for (int q = 0; q < 4; ++q)
#pragma unroll
      for (int m = 0; m < 12; ++m) acc[q][m] = 0.f;
    for (int i = 0; i < 48; ++i) {
      const float4 wa = *(const float4*)&Wlx[i][j0r];
      const float4 wb = *(const float4*)&Wlx[i][j0r + 4];
      const float4 wc = *(const float4*)&Wlx[i][j0r + 8];
      float w12[12] = {wa.x, wa.y, wa.z, wa.w, wb.x, wb.y, wb.z, wb.w, wc.x, wc.y, wc.z, wc.w};
      float pv[4];
#pragma unroll
      for (int q = 0; q < 4; ++q) pv[q] = preS[rw * 4 + q][i];
#pragma unroll
      for (int q = 0; q < 4; ++q)
#pragma unroll
        for (int m = 0; m < 12; ++m) acc[q][m] += pv[q] * w12[m];
    }
#pragma unroll
    for (int q = 0; q < 4; ++q) {
      int n = tile * 64 + rw * 4 + q;
      if (n < 800) {
        float v[12];
#pragma unroll
        for (int m = 0; m < 12; ++m)
          v[m] = acc[q][m] + ldc(bx, ((size_t)t * N_ + n) * C_ + jj0 + m);
        size_t ob = ((size_t)((b * TP_ + t) * N_ + n)) * 144 + j0r;
        st4s(decx, ob, v); st4s(decx, ob + 4, v + 4); st4s(decx, ob + 8, v + 8);
      }
    }
  }
}
__global__ __launch_bounds__(192) void k_convx(
    const int* dtf, const void* x, const void* T, const void* cw, const void* cb,
    const void* lwz, const void* lwr, const void* lwh,
    const void* lbz, const void* lbr, const void* lbh, bf16* decx) {
  if (*dtf)
    convx_body<float>((const float*)x, (const float*)T, (const float*)cw, (const float*)cb,
                      (const float*)lwz, (const float*)lwr, (const float*)lwh,
                      (const float*)lbz, (const float*)lbr, (const float*)lbh, decx);
  else
    convx_body<bf16>((const bf16*)x, (const bf16*)T, (const bf16*)cw, (const bf16*)cb,
                     (const bf16*)lwz, (const bf16*)lwr, (const bf16*)lwh,
                     (const bf16*)lbz, (const bf16*)lbr, (const bf16*)lbh, decx);
}

// ---------------- Kernel E: serial GRU chains (recurrent parts only) ------
// 100 blocks x 192 thr = 16 rows x 12 j-lanes (4 j each).
template <typename TI, typename TO>
__device__ __forceinline__ void gru_body(
    const bf16* encx, const bf16* decx,
    const TI* xwz, const TI* xwr, const TI* xwh,
    const TI* lwz, const TI* lwr, const TI* lwh,
    const TI* Wout, const TI* bout, TO* out) {
  __shared__ float Wz[48][48], Wr[48][48], Wh[48][48];
  __shared__ float hS[16][49], rhS[16][49];
  __shared__ float woutS[48];
  __shared__ float boutS;
  int tid = threadIdx.x;
  int rw = tid / 12, jl = tid % 12, j0 = jl * 4;
  int row = blockIdx.x * 16 + rw;
  int b = row / N_, n = row % N_;

  if (tid < 48) woutS[tid] = ldc(Wout, tid);
  if (tid == 48) boutS = ldc(bout, 0);
#pragma unroll
  for (int k = 0; k < 4; ++k) hS[rw][j0 + k] = 0.f;
  __syncthreads();

  // ---- encoder: t = 1..11 ----
  for (int t = 1; t < TIN_; ++t) {
#pragma unroll
    for (int p = 0; p < 12; ++p) {  // stage recurrent weights rows 96:144
      int e = tid + p * 192;
      int i = e / 48, j = e % 48;
      size_t src = ((size_t)t * 144 + 96 + i) * 48 + j;
      Wz[i][j] = ldc(xwz, src);
      Wr[i][j] = ldc(xwr, src);
      Wh[i][j] = ldc(xwh, src);
    }
    __syncthreads();
    float exz[4], exr[4], exh[4];
    size_t eb = ((size_t)((b * 11 + (t - 1)) * N_ + n)) * 144;
    ld4s(encx, eb + j0, exz);
    ld4s(encx, eb + 48 + j0, exr);
    ld4s(encx, eb + 96 + j0, exh);
    float az[4] = {0, 0, 0, 0}, ar[4] = {0, 0, 0, 0};
    for (int i = 0; i < 48; ++i) {
      float hv = hS[rw][i];
      const float4 wz4 = *(const float4*)&Wz[i][j0];
      const float4 wr4 = *(const float4*)&Wr[i][j0];
      az[0] += hv * wz4.x; az[1] += hv * wz4.y; az[2] += hv * wz4.z; az[3] += hv * wz4.w;
      ar[0] += hv * wr4.x; ar[1] += hv * wr4.y; ar[2] += hv * wr4.z; ar[3] += hv * wr4.w;
    }
    float ho[4], z[4], rr4[4];
#pragma unroll
    for (int k = 0; k < 4; ++k) {
      ho[k] = hS[rw][j0 + k];
      z[k] = sigm(az[k] + exz[k]);
      rr4[k] = sigm(ar[k] + exr[k]);
      rhS[rw][j0 + k] = rr4[k] * ho[k];
    }
    __syncthreads();
    float ah[4] = {0, 0, 0, 0};
    for (int i = 0; i < 48; ++i) {
      float rv = rhS[rw][i];
      const float4 wh4 = *(const float4*)&Wh[i][j0];
      ah[0] += rv * wh4.x; ah[1] += rv * wh4.y; ah[2] += rv * wh4.z; ah[3] += rv * wh4.w;
    }
    float hn[4];
#pragma unroll
    for (int k = 0; k < 4; ++k)
      hn[k] = (1.f - z[k]) * ho[k] + z[k] * tanh_(ah[k] + exh[k]);
    __syncthreads();
#pragma unroll
    for (int k = 0; k < 4; ++k) hS[rw][j0 + k] = hn[k];
    __syncthreads();
  }

  // ---- decoder: t = 0..9 ----
  for (int t = 0; t < TP_; ++t) {
#pragma unroll
    for (int p = 0; p < 12; ++p) {  // stage recurrent weights rows 48:96
      int e = tid + p * 192;
      int i = e / 48, j = e % 48;
      size_t src = ((size_t)t * 96 + 48 + i) * 48 + j;
      Wz[i][j] = ldc(lwz, src);
      Wr[i][j] = ldc(lwr, src);
      Wh[i][j] = ldc(lwh, src);
    }
    __syncthreads();
    float exz[4], exr[4], exh[4];
    size_t eb = ((size_t)((b * TP_ + t) * N_ + n)) * 144;
    ld4s(decx, eb + j0, exz);
    ld4s(decx, eb + 48 + j0, exr);
    ld4s(decx, eb + 96 + j0, exh);
    float az[4] = {0, 0, 0, 0}, ar[4] = {0, 0, 0, 0};
    for (int i = 0; i < 48; ++i) {
      float hv = hS[rw][i];
      const float4 wz4 = *(const float4*)&Wz[i][j0];
      const float4 wr4 = *(const float4*)&Wr[i][j0];
      az[0] += hv * wz4.x; az[1] += hv * wz4.y; az[2] += hv * wz4.z; az[3] += hv * wz4.w;
      ar[0] += hv * wr4.x; ar[1] += hv * wr4.y; ar[2] += hv * wr4.z; ar[3] += hv * wr4.w;
    }
    float ho[4], z[4], rr4[4];
#pragma unroll
    for (int k = 0; k < 4; ++k) {
      ho[k] = hS[rw][j0 + k];
      z[k] = sigm(az[k] + exz[k]);
      rr4[k] = sigm(ar[k] + exr[k]);
      rhS[rw][j0 + k] = rr4[k] * ho[k];
    }
    __syncthreads();
    float ah[4] = {0, 0, 0, 0};
    for (int i = 0; i < 48; ++i) {
      float rv = rhS[rw][i];
      const float4 wh4 = *(const float4*)&Wh[i][j0];
      ah[0] += rv * wh4.x; ah[1] += rv * wh4.y; ah[2] += rv * wh4.z; ah[3] += rv * wh4.w;
    }
    float hn[4];
#pragma unroll
    for (int k = 0; k < 4; ++k)
      hn[k] = (1.f - z[k]) * ho[k] + z[k] * tanh_(ah[k] + exh[k]);
    __syncthreads();
#pragma unroll
    for (int k = 0; k < 4; ++k) hS[rw][j0 + k] = hn[k];
    __syncthreads();
    if (tid < 16) {  // output for this step's 16 rows
      int row2 = blockIdx.x * 16 + tid;
      int b2 = row2 / N_, n2 = row2 % N_;
      float s = boutS;
      for (int j = 0; j < 48; ++j) s += hS[tid][j] * woutS[j];
      sto(out, ((size_t)b2 * TP_ + t) * N_ + n2, s);
    }
  }
}
__global__ __launch_bounds__(192) void k_gru(
    const int* dtf, const bf16* encx, const bf16* decx,
    const void* xwz, const void* xwr, const void* xwh,
    const void* lwz, const void* lwr, const void* lwh,
    const void* Wout, const void* bout, void* out) {
  if (*dtf)
    gru_body<float, float>(encx, decx, (const float*)xwz, (const float*)xwr, (const float*)xwh,
                           (const float*)lwz, (const float*)lwr, (const float*)lwh,
                           (const float*)Wout, (const float*)bout, (float*)out);
  else
    gru_body<bf16, bf16>(encx, decx, (const bf16*)xwz, (const bf16*)xwr, (const bf16*)xwh,
                         (const bf16*)lwz, (const bf16*)lwr, (const bf16*)lwh,
                         (const bf16*)Wout, (const bf16*)bout, (bf16*)out);
}

// ---------------------------------------------------------------------------
extern "C" void kernel_launch(void* const* d_in, const int* in_sizes, int n_in,
                              void* d_out, int out_size, void* d_ws, size_t ws_size,
                              hipStream_t stream) {
  (void)in_sizes; (void)n_in; (void)out_size; (void)ws_size;
  const void* x       = d_in[0];
  const void* T       = d_in[1];
  const void* Wq_t    = d_in[3];
  const void* Wk_t    = d_in[4];
  const void* Wv_t    = d_in[5];
  const void* Wq_st   = d_in[6];
  const void* Wk_st   = d_in[7];
  const void* Wv_st   = d_in[8];
  const void* bq_t    = d_in[9];
  const void* bk_t    = d_in[10];
  const void* bv_t    = d_in[11];
  const void* bq_st   = d_in[12];
  const void* bk_st   = d_in[13];
  const void* bv_st   = d_in[14];
  const void* conv1_w = d_in[15];
  const void* conv1_b = d_in[16];
  const void* Wproj_t = d_in[17];
  const void* bproj_t = d_in[18];
  const void* Wproj_st= d_in[19];
  const void* bproj_st= d_in[20];
  const void* xhr_wz  = d_in[21];
  const void* xhr_wr  = d_in[22];
  const void* xhr_wh  = d_in[23];
  const void* xhr_bz  = d_in[24];
  const void* xhr_br  = d_in[25];
  const void* xhr_bh  = d_in[26];
  const void* last_wz = d_in[27];
  const void* last_wr = d_in[28];
  const void* last_wh = d_in[29];
  const void* last_bz = d_in[30];
  const void* last_br = d_in[31];
  const void* last_bh = d_in[32];
  const void* Wout    = d_in[33];
  const void* bout    = d_in[34];

  // ws layout (13.1 MB; <= 14.8 MB proven safe in round 2)
  char* wsb = (char*)d_ws;
  int* dtf     = (int*)wsb;                        // 256 B
  bf16* att_t  = (bf16*)(wsb + 256);               // 2*11*800*48
  bf16* att_st = att_t + (size_t)2 * 11 * 800 * 48;
  bf16* encx   = att_st + (size_t)2 * 11 * 800 * 48;   // 2*11*800*144
  bf16* decx   = encx + (size_t)2 * 11 * 800 * 144;    // 2*10*800*144

  k_detect<<<1, 64, 0, stream>>>((const unsigned int*)x, dtf);
  {
    int total = B_ * (TIN_ - 1) * H_ * N_;
    k_temporal<<<(total + 255) / 256, 256, 0, stream>>>(
        dtf, x, Wq_t, Wk_t, Wv_t, bq_t, bk_t, bv_t, att_t);
  }
  k_spatial<<<B_ * (TIN_ - 1) * H_ * ROWT, 256, 0, stream>>>(
      dtf, x, Wq_st, Wk_st, Wv_st, bq_st, bk_st, bv_st, att_st);
  k_projx<<<dim3(13, 11, 2), 192, 0, stream>>>(
      dtf, att_t, att_st, Wproj_t, bproj_t, Wproj_st, bproj_st,
      xhr_wz, xhr_wr, xhr_wh, xhr_bz, xhr_br, xhr_bh, encx);
  k_convx<<<dim3(13, 10, 2), 192, 0, stream>>>(
      dtf, x, T, conv1_w, conv1_b, last_wz, last_wr, last_wh,
      last_bz, last_br, last_bh, decx);
  k_gru<<<100, 192, 0, stream>>>(
      dtf, encx, decx, xhr_wz, xhr_wr, xhr_wh, last_wz, last_wr, last_wh,
      Wout, bout, d_out);
}

// Round 5
// 267.219 us; speedup vs baseline: 4.0528x; 1.5976x over previous
//
#include <hip/hip_runtime.h>
#include <hip/hip_bf16.h>

typedef __hip_bfloat16 bf16;

#define B_ 2
#define TIN_ 12
#define N_ 800
#define F_ 2
#define H_ 6
#define D_ 8
#define C_ 48
#define TP_ 10
#define KW_ 14
#define SCALE 0.35355339059327373f  // 1/sqrt(8)
#define LOG2E 1.4426950408889634f

__device__ __forceinline__ float sigm(float x) { return 1.0f / (1.0f + __expf(-x)); }
__device__ __forceinline__ float tanh_(float x) {
  float e = __expf(-2.0f * x);
  return 2.0f / (1.0f + e) - 1.0f;
}
__device__ __forceinline__ float exp2_(float x) { return __builtin_amdgcn_exp2f(x); }
__device__ __forceinline__ float bfu(unsigned short u) {
  return __uint_as_float((unsigned)u << 16);
}
// dual-dtype scalar loads (overload on pointer type; kernels template on TI)
__device__ __forceinline__ float ldc(const float* p, size_t i) { return p[i]; }
__device__ __forceinline__ float ldc(const bf16* p, size_t i) { return __bfloat162float(p[i]); }
__device__ __forceinline__ void ld4(const float* p, size_t i, float o[4]) {
  float4 v = *(const float4*)(p + i);
  o[0] = v.x; o[1] = v.y; o[2] = v.z; o[3] = v.w;
}
__device__ __forceinline__ void ld4(const bf16* p, size_t i, float o[4]) {
  ushort4 v = *(const ushort4*)((const unsigned short*)p + i);
  o[0] = bfu(v.x); o[1] = bfu(v.y); o[2] = bfu(v.z); o[3] = bfu(v.w);
}
__device__ __forceinline__ void sto(float* p, size_t i, float v) { p[i] = v; }
__device__ __forceinline__ void sto(bf16* p, size_t i, float v) { p[i] = __float2bfloat16(v); }
__device__ __forceinline__ void ld4s(const bf16* p, size_t i, float o[4]) { ld4(p, i, o); }
__device__ __forceinline__ void st4s(bf16* p, size_t i, const float v[4]) {
  ushort4 u;
  u.x = __bfloat16_as_ushort(__float2bfloat16(v[0]));
  u.y = __bfloat16_as_ushort(__float2bfloat16(v[1]));
  u.z = __bfloat16_as_ushort(__float2bfloat16(v[2]));
  u.w = __bfloat16_as_ushort(__float2bfloat16(v[3]));
  *(ushort4*)((unsigned short*)p + i) = u;
}

// ---------------- Kernel 0: dtype detector --------------------------------
__global__ void k_detect(const unsigned int* __restrict__ xw, int* __restrict__ flag) {
  int lane = threadIdx.x;  // 64
  unsigned int w = xw[lane];
  int e = (w >> 7) & 0xFF;  // exponent of LOW bf16 slot
  int bad = ((e >= 1 && e < 96) || (e > 150)) ? 1 : 0;
  unsigned long long m = __ballot(bad);
  if (lane == 0) *flag = (__popcll(m) >= 16) ? 1 : 0;
}

// ---------------- Kernel P: pack recurrent GRU weights to bf16 ------------
// pw[step][6912]: steps 0..10 = xhr rows 96:144 (t=1..11); 11..20 = last rows 48:96.
template <typename TI>
__device__ __forceinline__ void pack_body(
    const TI* xwz, const TI* xwr, const TI* xwh,
    const TI* lwz, const TI* lwr, const TI* lwh, bf16* pw) {
  int gid = blockIdx.x * 256 + threadIdx.x;
  const int total = 21 * 6912;
  if (gid >= total) return;
  int step = gid / 6912, e = gid % 6912;
  int g = e / 2304, i = (e % 2304) / 48, j = e % 48;
  float v;
  if (step < 11) {
    int t = step + 1;
    const TI* w = (g == 0) ? xwz : (g == 1) ? xwr : xwh;
    v = ldc(w, ((size_t)t * 144 + 96 + i) * 48 + j);
  } else {
    int t = step - 11;
    const TI* w = (g == 0) ? lwz : (g == 1) ? lwr : lwh;
    v = ldc(w, ((size_t)t * 96 + 48 + i) * 48 + j);
  }
  pw[gid] = __float2bfloat16(v);
}
__global__ void k_pack(const int* dtf, const void* xwz, const void* xwr, const void* xwh,
                       const void* lwz, const void* lwr, const void* lwh, bf16* pw) {
  if (*dtf)
    pack_body<float>((const float*)xwz, (const float*)xwr, (const float*)xwh,
                     (const float*)lwz, (const float*)lwr, (const float*)lwh, pw);
  else
    pack_body<bf16>((const bf16*)xwz, (const bf16*)xwr, (const bf16*)xwh,
                    (const bf16*)lwz, (const bf16*)lwr, (const bf16*)lwh, pw);
}

// ---------------- Kernel A: temporal causal attention (t=1..11) -----------
template <typename TI>
__device__ __forceinline__ void temporal_body(
    const TI* x, const TI* Wq, const TI* Wk, const TI* Wv,
    const TI* bq, const TI* bk, const TI* bv, bf16* att_t) {
  int gid = blockIdx.x * blockDim.x + threadIdx.x;
  const int total = B_ * (TIN_ - 1) * H_ * N_;
  if (gid >= total) return;
  int n = gid % N_;
  int r = gid / N_;
  int h = r % H_;  r /= H_;
  int t = (r % (TIN_ - 1)) + 1;
  int b = r / (TIN_ - 1);

  float wq[F_][D_], wk[F_][D_], wv[F_][D_], bqv[D_], bkv[D_], bvv[D_];
#pragma unroll
  for (int f = 0; f < F_; ++f)
#pragma unroll
    for (int d = 0; d < D_; ++d) {
      wq[f][d] = ldc(Wq, (h * F_ + f) * D_ + d);
      wk[f][d] = ldc(Wk, (h * F_ + f) * D_ + d);
      wv[f][d] = ldc(Wv, (h * F_ + f) * D_ + d);
    }
#pragma unroll
  for (int d = 0; d < D_; ++d) {
    bqv[d] = ldc(bq, h * D_ + d);
    bkv[d] = ldc(bk, h * D_ + d);
    bvv[d] = ldc(bv, h * D_ + d);
  }
  float xt0 = ldc(x, ((b * TIN_ + t) * N_ + n) * F_ + 0);
  float xt1 = ldc(x, ((b * TIN_ + t) * N_ + n) * F_ + 1);
  float q[D_];
#pragma unroll
  for (int d = 0; d < D_; ++d) q[d] = xt0 * wq[0][d] + xt1 * wq[1][d] + bqv[d];

  float sc[TIN_];
  float mx = -1e30f;
#pragma unroll
  for (int s = 0; s < TIN_; ++s) {
    float xs0 = ldc(x, ((b * TIN_ + s) * N_ + n) * F_ + 0);
    float xs1 = ldc(x, ((b * TIN_ + s) * N_ + n) * F_ + 1);
    float dot = 0.f;
#pragma unroll
    for (int d = 0; d < D_; ++d)
      dot += q[d] * (xs0 * wk[0][d] + xs1 * wk[1][d] + bkv[d]);
    dot *= SCALE;
    sc[s] = (s <= t) ? dot : -1e30f;
    mx = fmaxf(mx, sc[s]);
  }
  float sum = 0.f;
#pragma unroll
  for (int s = 0; s < TIN_; ++s) {
    float p = __expf(sc[s] - mx);
    sc[s] = p;
    sum += p;
  }
  float inv = 1.0f / sum;
  float acc[D_];
#pragma unroll
  for (int d = 0; d < D_; ++d) acc[d] = 0.f;
#pragma unroll
  for (int s = 0; s < TIN_; ++s) {
    float xs0 = ldc(x, ((b * TIN_ + s) * N_ + n) * F_ + 0);
    float xs1 = ldc(x, ((b * TIN_ + s) * N_ + n) * F_ + 1);
#pragma unroll
    for (int d = 0; d < D_; ++d)
      acc[d] += sc[s] * (xs0 * wv[0][d] + xs1 * wv[1][d] + bvv[d]);
  }
  bf16* o = att_t + ((size_t)((b * 11 + (t - 1)) * N_ + n)) * C_ + h * D_;
#pragma unroll
  for (int d = 0; d < D_; ++d) o[d] = __float2bfloat16(acc[d] * inv);
}
__global__ void k_temporal(const int* dtf, const void* x, const void* Wq, const void* Wk,
                           const void* Wv, const void* bq, const void* bk, const void* bv,
                           bf16* att_t) {
  if (*dtf)
    temporal_body<float>((const float*)x, (const float*)Wq, (const float*)Wk, (const float*)Wv,
                         (const float*)bq, (const float*)bk, (const float*)bv, att_t);
  else
    temporal_body<bf16>((const bf16*)x, (const bf16*)Wq, (const bf16*)Wk, (const bf16*)Wv,
                        (const bf16*)bq, (const bf16*)bk, (const bf16*)bv, att_t);
}

// ---------------- Kernel B: spatial attention, rank-2 form ----------------
// s_nm = A_n*x0_m + B_n*x1_m + C_n (F=2!). PV = (S0*wv0 + S1*wv1 + Sp*bv)/Sp.
// grid (4 row-tiles, 11 t, 2 b) x 832 thr (200 rows x 4 m-splits).
#define ST_ROWS 200
#define ST_MS 4
template <typename TI>
__device__ __forceinline__ void spatial2_body(
    const TI* x, const TI* Wq, const TI* Wk, const TI* Wv,
    const TI* bq, const TI* bk, const TI* bv, bf16* att_st) {
  __shared__ float2 xs[N_];                 // 6.4 KB
  __shared__ float M[H_][9];                // 3x3 per head, SCALE*LOG2E folded
  __shared__ float Vw[H_][3][D_];           // wv0, wv1, bv
  __shared__ float pt[ST_MS][ST_ROWS][19];  // partials Sp,S0,S1 x 6 heads
  int tile = blockIdx.x, ty = blockIdx.y, b = blockIdx.z;
  int t = ty + 1;
  int tid = threadIdx.x;

  for (int m = tid; m < N_; m += 832)
    xs[m] = make_float2(ldc(x, ((b * TIN_ + t) * N_ + m) * F_ + 0),
                        ldc(x, ((b * TIN_ + t) * N_ + m) * F_ + 1));
  if (tid < 54) {  // M[h][a*3+bb] = dot(qa, kb) * SCALE * LOG2E
    int h = tid / 9, e = tid % 9, a = e / 3, bb = e % 3;
    float acc = 0.f;
    for (int d = 0; d < 8; ++d) {
      float qa = (a == 0) ? ldc(Wq, (h * 2 + 0) * 8 + d)
               : (a == 1) ? ldc(Wq, (h * 2 + 1) * 8 + d) : ldc(bq, h * 8 + d);
      float kb = (bb == 0) ? ldc(Wk, (h * 2 + 0) * 8 + d)
               : (bb == 1) ? ldc(Wk, (h * 2 + 1) * 8 + d) : ldc(bk, h * 8 + d);
      acc += qa * kb;
    }
    M[h][e] = acc * SCALE * LOG2E;
  }
  if (tid >= 64 && tid < 64 + 144) {
    int e = tid - 64;
    int h = e / 24, a = (e % 24) / 8, d = e % 8;
    Vw[h][a][d] = (a == 0) ? ldc(Wv, (h * 2 + 0) * 8 + d)
                : (a == 1) ? ldc(Wv, (h * 2 + 1) * 8 + d) : ldc(bv, h * 8 + d);
  }
  __syncthreads();
  if (tid < ST_ROWS * ST_MS) {
    int ms = tid / ST_ROWS, nl = tid % ST_ROWS;
    int n = tile * ST_ROWS + nl;
    float x0 = xs[n].x, x1 = xs[n].y;
    float A[6], Bc[6], Cc[6];
#pragma unroll
    for (int h = 0; h < 6; ++h) {
      A[h]  = M[h][0] * x0 + M[h][3] * x1 + M[h][6];
      Bc[h] = M[h][1] * x0 + M[h][4] * x1 + M[h][7];
      Cc[h] = M[h][2] * x0 + M[h][5] * x1 + M[h][8];
    }
    float Sp[6] = {0, 0, 0, 0, 0, 0}, S0[6] = {0, 0, 0, 0, 0, 0}, S1[6] = {0, 0, 0, 0, 0, 0};
    for (int m = ms * 200; m < ms * 200 + 200; ++m) {
      float2 xm = xs[m];
#pragma unroll
      for (int h = 0; h < 6; ++h) {
        float p = exp2_(A[h] * xm.x + Bc[h] * xm.y + Cc[h]);
        Sp[h] += p;
        S0[h] += p * xm.x;
        S1[h] += p * xm.y;
      }
    }
#pragma unroll
    for (int h = 0; h < 6; ++h) {
      pt[ms][nl][h * 3 + 0] = Sp[h];
      pt[ms][nl][h * 3 + 1] = S0[h];
      pt[ms][nl][h * 3 + 2] = S1[h];
    }
  }
  __syncthreads();
  if (tid < ST_ROWS) {
    int n = tile * ST_ROWS + tid;
    bf16* o = att_st + ((size_t)((b * 11 + ty) * N_ + n)) * C_;
#pragma unroll
    for (int h = 0; h < 6; ++h) {
      float Sp = pt[0][tid][h * 3] + pt[1][tid][h * 3] + pt[2][tid][h * 3] + pt[3][tid][h * 3];
      float S0 = pt[0][tid][h * 3 + 1] + pt[1][tid][h * 3 + 1] + pt[2][tid][h * 3 + 1] + pt[3][tid][h * 3 + 1];
      float S1 = pt[0][tid][h * 3 + 2] + pt[1][tid][h * 3 + 2] + pt[2][tid][h * 3 + 2] + pt[3][tid][h * 3 + 2];
      float inv = 1.f / Sp;
#pragma unroll
      for (int d = 0; d < 8; ++d)
        o[h * 8 + d] = __float2bfloat16((S0 * Vw[h][0][d] + S1 * Vw[h][1][d] + Sp * Vw[h][2][d]) * inv);
    }
  }
}
__global__ __launch_bounds__(832) void k_spatial2(
    const int* dtf, const void* x, const void* Wq, const void* Wk, const void* Wv,
    const void* bq, const void* bk, const void* bv, bf16* att_st) {
  if (*dtf)
    spatial2_body<float>((const float*)x, (const float*)Wq, (const float*)Wk, (const float*)Wv,
                         (const float*)bq, (const float*)bk, (const float*)bv, att_st);
  else
    spatial2_body<bf16>((const bf16*)x, (const bf16*)Wq, (const bf16*)Wk, (const bf16*)Wv,
                        (const bf16*)bq, (const bf16*)bk, (const bf16*)bv, att_st);
}

// ---------------- Kernel C: proj + encoder x-parts ------------------------
template <typename TI>
__device__ __forceinline__ void projx_body(
    const bf16* att_t, const bf16* att_st,
    const TI* Wpt, const TI* bpt, const TI* Wps, const TI* bps,
    const TI* xhr_wz, const TI* xhr_wr, const TI* xhr_wh,
    const TI* xhr_bz, const TI* xhr_br, const TI* xhr_bh,
    bf16* encx) {
  __shared__ unsigned short raw[64][96];
  __shared__ float catS[64][100];
  __shared__ float Wp[2][48][48];
  int tile = blockIdx.x, ty = blockIdx.y, b = blockIdx.z;
  int t = ty + 1;
  int tid = threadIdx.x;
  int rw = tid / 12, jl = tid % 12;

  for (int p = 0; p < 24; ++p) {
    int e = tid + p * 192;
    int half = e / 2304, k = (e % 2304) / 48, i = e % 48;
    Wp[half][k][i] = half ? ldc(Wps, k * 48 + i) : ldc(Wpt, k * 48 + i);
  }
  for (int p = 0; p < 32; ++p) {
    int e = tid + p * 192;
    int rr = e / 96, c = e % 96;
    int n = tile * 64 + rr; if (n > 799) n = 799;
    size_t base = ((size_t)((b * 11 + ty) * N_ + n)) * C_;
    bf16 v = (c < 48) ? att_t[base + c] : att_st[base + (c - 48)];
    raw[rr][c] = __bfloat16_as_ushort(v);
  }
  __syncthreads();
  {
    int half = (jl >= 6);
    int ii0 = jl * 8 - half * 48;
    float acc[4][8];
#pragma unroll
    for (int q = 0; q < 4; ++q)
#pragma unroll
      for (int m = 0; m < 8; ++m)
        acc[q][m] = half ? ldc(bps, ii0 + m) : ldc(bpt, ii0 + m);
    for (int k = 0; k < 48; ++k) {
      float rv[4];
#pragma unroll
      for (int q = 0; q < 4; ++q)
        rv[q] = __uint_as_float((unsigned)raw[rw * 4 + q][half * 48 + k] << 16);
      const float4 wa = *(const float4*)&Wp[half][k][ii0];
      const float4 wb = *(const float4*)&Wp[half][k][ii0 + 4];
      float w8[8] = {wa.x, wa.y, wa.z, wa.w, wb.x, wb.y, wb.z, wb.w};
#pragma unroll
      for (int q = 0; q < 4; ++q)
#pragma unroll
        for (int m = 0; m < 8; ++m) acc[q][m] += rv[q] * w8[m];
    }
#pragma unroll
    for (int q = 0; q < 4; ++q) {
      *(float4*)&catS[rw * 4 + q][jl * 8] = make_float4(acc[q][0], acc[q][1], acc[q][2], acc[q][3]);
      *(float4*)&catS[rw * 4 + q][jl * 8 + 4] = make_float4(acc[q][4], acc[q][5], acc[q][6], acc[q][7]);
    }
  }
  __syncthreads();
  {
    int j0r = jl * 12;
    int g = j0r / 48, jj0 = j0r % 48;
    const TI* wx = (g == 0) ? xhr_wz : (g == 1) ? xhr_wr : xhr_wh;
    const TI* bx = (g == 0) ? xhr_bz : (g == 1) ? xhr_br : xhr_bh;
    float acc[4][12];
#pragma unroll
    for (int q = 0; q < 4; ++q)
#pragma unroll
      for (int m = 0; m < 12; ++m) acc[q][m] = 0.f;
    for (int i = 0; i < 96; ++i) {
      float w12[12];
      size_t wb = ((size_t)t * 144 + i) * 48 + jj0;
      ld4(wx, wb, w12); ld4(wx, wb + 4, w12 + 4); ld4(wx, wb + 8, w12 + 8);
      float cv[4];
#pragma unroll
      for (int q = 0; q < 4; ++q) cv[q] = catS[rw * 4 + q][i];
#pragma unroll
      for (int q = 0; q < 4; ++q)
#pragma unroll
        for (int m = 0; m < 12; ++m) acc[q][m] += cv[q] * w12[m];
    }
#pragma unroll
    for (int q = 0; q < 4; ++q) {
      int n = tile * 64 + rw * 4 + q;
      if (n < 800) {
        float v[12];
#pragma unroll
        for (int m = 0; m < 12; ++m)
          v[m] = acc[q][m] + ldc(bx, ((size_t)t * N_ + n) * C_ + jj0 + m);
        size_t ob = ((size_t)((b * 11 + ty) * N_ + n)) * 144 + j0r;
        st4s(encx, ob, v); st4s(encx, ob + 4, v + 4); st4s(encx, ob + 8, v + 8);
      }
    }
  }
}
__global__ __launch_bounds__(192) void k_projx(
    const int* dtf, const bf16* att_t, const bf16* att_st,
    const void* Wpt, const void* bpt, const void* Wps, const void* bps,
    const void* xwz, const void* xwr, const void* xwh,
    const void* xbz, const void* xbr, const void* xbh, bf16* encx) {
  if (*dtf)
    projx_body<float>(att_t, att_st, (const float*)Wpt, (const float*)bpt, (const float*)Wps,
                      (const float*)bps, (const float*)xwz, (const float*)xwr, (const float*)xwh,
                      (const float*)xbz, (const float*)xbr, (const float*)xbh, encx);
  else
    projx_body<bf16>(att_t, att_st, (const bf16*)Wpt, (const bf16*)bpt, (const bf16*)Wps,
                     (const bf16*)bps, (const bf16*)xwz, (const bf16*)xwr, (const bf16*)xwh,
                     (const bf16*)xbz, (const bf16*)xbr, (const bf16*)xbh, encx);
}

// ---------------- Kernel D: conv1 + decoder x-parts -----------------------
template <typename TI>
__device__ __forceinline__ void convx_body(
    const TI* x, const TI* T,
    const TI* conv1_w, const TI* conv1_b,
    const TI* lwz, const TI* lwr, const TI* lwh,
    const TI* lbz, const TI* lbr, const TI* lbh,
    bf16* decx) {
  __shared__ float tpw[64][KW_][2];
  __shared__ float cw[2][KW_][48];
  __shared__ float preS[64][48];
  __shared__ float Wlx[48][144];
  int tile = blockIdx.x, t = blockIdx.y, b = blockIdx.z;
  int tid = threadIdx.x;
  int rw = tid / 12, jl = tid % 12;

  for (int p = 0; p < 7; ++p) {
    int e = tid + p * 192;
    int f = e / (KW_ * 48), rem = e % (KW_ * 48), k = rem / 48, c = rem % 48;
    cw[f][k][c] = ldc(conv1_w, (c * F_ + f) * KW_ + k);
  }
  for (int p = 0; p < 10; ++p) {
    int e = tid + p * 192;
    if (e < 64 * KW_ * 2) {
      int rr = e / (KW_ * 2), rem = e % (KW_ * 2), k = rem / 2, f = rem % 2;
      int n = tile * 64 + rr; if (n > 799) n = 799;
      int tau = t + k;
      float v;
      if (tau < TIN_) v = ldc(x, ((size_t)(b * TIN_ + tau) * N_ + n) * F_ + f);
      else if (tau < TIN_ + TP_) v = (f == 0) ? 0.f : ldc(T, (size_t)(b * TP_ + (tau - TIN_)) * N_ + n);
      else v = ldc(x, ((size_t)(b * TIN_ + 0) * N_ + n) * F_ + f);
      tpw[rr][k][f] = v;
    }
  }
  for (int p = 0; p < 36; ++p) {
    int e = tid + p * 192;
    int i = e / 144, jg = e % 144, g = jg / 48, j = jg % 48;
    const TI* w = (g == 0) ? lwz : (g == 1) ? lwr : lwh;
    Wlx[i][jg] = ldc(w, ((size_t)t * 96 + i) * 48 + j);
  }
  __syncthreads();
  {
    int c0 = jl * 4;
    float acc[4][4];
#pragma unroll
    for (int q = 0; q < 4; ++q)
#pragma unroll
      for (int m = 0; m < 4; ++m) acc[q][m] = ldc(conv1_b, c0 + m);
#pragma unroll
    for (int f = 0; f < 2; ++f)
      for (int k = 0; k < KW_; ++k) {
        const float4 w4 = *(const float4*)&cw[f][k][c0];
        float wv[4] = {w4.x, w4.y, w4.z, w4.w};
#pragma unroll
        for (int q = 0; q < 4; ++q) {
          float tv = tpw[rw * 4 + q][k][f];
#pragma unroll
          for (int m = 0; m < 4; ++m) acc[q][m] += tv * wv[m];
        }
      }
#pragma unroll
    for (int q = 0; q < 4; ++q)
      *(float4*)&preS[rw * 4 + q][c0] = make_float4(acc[q][0], acc[q][1], acc[q][2], acc[q][3]);
  }
  __syncthreads();
  {
    int j0r = jl * 12;
    int g = j0r / 48, jj0 = j0r % 48;
    const TI* bx = (g == 0) ? lbz : (g == 1) ? lbr : lbh;
    float acc[4][12];
#pragma unroll
    for (int q = 0; q < 4; ++q)
#pragma unroll
      for (int m = 0; m < 12; ++m) acc[q][m] = 0.f;
    for (int i = 0; i < 48; ++i) {
      const float4 wa = *(const float4*)&Wlx[i][j0r];
      const float4 wb = *(const float4*)&Wlx[i][j0r + 4];
      const float4 wc = *(const float4*)&Wlx[i][j0r + 8];
      float w12[12] = {wa.x, wa.y, wa.z, wa.w, wb.x, wb.y, wb.z, wb.w, wc.x, wc.y, wc.z, wc.w};
      float pv[4];
#pragma unroll
      for (int q = 0; q < 4; ++q) pv[q] = preS[rw * 4 + q][i];
#pragma unroll
      for (int q = 0; q < 4; ++q)
#pragma unroll
        for (int m = 0; m < 12; ++m) acc[q][m] += pv[q] * w12[m];
    }
#pragma unroll
    for (int q = 0; q < 4; ++q) {
      int n = tile * 64 + rw * 4 + q;
      if (n < 800) {
        float v[12];
#pragma unroll
        for (int m = 0; m < 12; ++m)
          v[m] = acc[q][m] + ldc(bx, ((size_t)t * N_ + n) * C_ + jj0 + m);
        size_t ob = ((size_t)((b * TP_ + t) * N_ + n)) * 144 + j0r;
        st4s(decx, ob, v); st4s(decx, ob + 4, v + 4); st4s(decx, ob + 8, v + 8);
      }
    }
  }
}
__global__ __launch_bounds__(192) void k_convx(
    const int* dtf, const void* x, const void* T, const void* cw, const void* cb,
    const void* lwz, const void* lwr, const void* lwh,
    const void* lbz, const void* lbr, const void* lbh, bf16* decx) {
  if (*dtf)
    convx_body<float>((const float*)x, (const float*)T, (const float*)cw, (const float*)cb,
                      (const float*)lwz, (const float*)lwr, (const float*)lwh,
                      (const float*)lbz, (const float*)lbr, (const float*)lbh, decx);
  else
    convx_body<bf16>((const bf16*)x, (const bf16*)T, (const bf16*)cw, (const bf16*)cb,
                     (const bf16*)lwz, (const bf16*)lwr, (const bf16*)lwh,
                     (const bf16*)lbz, (const bf16*)lbr, (const bf16*)lbh, decx);
}

// ---------------- Kernel E: serial GRU (prefetched bf16 weights) ----------
// 100 blocks x 192 thr = 16 rows x 12 j-lanes. Unified 21-step loop.
template <typename TI, typename TO>
__device__ __forceinline__ void gru2_body(
    const bf16* encx, const bf16* decx, const bf16* pw,
    const TI* Wout, const TI* bout, TO* out) {
  __shared__ unsigned short Wl[3][48][48];   // bf16 raw, 13.8 KB
  __shared__ float hS[16][52], rhS[16][52];
  __shared__ float woutS[48];
  __shared__ float boutS;
  int tid = threadIdx.x;
  int rw = tid / 12, jl = tid % 12, j0 = jl * 4;
  int row = blockIdx.x * 16 + rw;
  int b = row / N_, n = row % N_;

  if (tid < 48) woutS[tid] = ldc(Wout, tid);
  if (tid == 48) boutS = ldc(bout, 0);
  *(float4*)&hS[rw][j0] = make_float4(0.f, 0.f, 0.f, 0.f);

  const unsigned short* pwu = (const unsigned short*)pw;
  size_t pbase = (size_t)tid * 36;
  ushort4 pf[9];
#pragma unroll
  for (int k = 0; k < 9; ++k) pf[k] = *(const ushort4*)(pwu + pbase + k * 4);
  __syncthreads();

  for (int step = 0; step < 21; ++step) {
    unsigned short* wflat = &Wl[0][0][0];
#pragma unroll
    for (int k = 0; k < 9; ++k) *(ushort4*)(wflat + tid * 36 + k * 4) = pf[k];
    __syncthreads();  // A: W ready; also orders prev-step hS write vs reads below
    if (step < 20) {
#pragma unroll
      for (int k = 0; k < 9; ++k)
        pf[k] = *(const ushort4*)(pwu + (size_t)(step + 1) * 6912 + pbase + k * 4);
    }
    const bf16* xsrc = (step < 11) ? encx : decx;
    size_t eb = (step < 11)
        ? (((size_t)(b * 11 + step)) * N_ + n) * 144
        : (((size_t)(b * 10 + (step - 11))) * N_ + n) * 144;
    float exz[4], exr[4], exh[4];
    ld4s(xsrc, eb + j0, exz);
    ld4s(xsrc, eb + 48 + j0, exr);
    ld4s(xsrc, eb + 96 + j0, exh);
    float az[4] = {0, 0, 0, 0}, ar[4] = {0, 0, 0, 0};
#pragma unroll
    for (int i4 = 0; i4 < 12; ++i4) {
      float4 h4 = *(const float4*)&hS[rw][i4 * 4];
#pragma unroll
      for (int u = 0; u < 4; ++u) {
        int i = i4 * 4 + u;
        float hv = (u == 0) ? h4.x : (u == 1) ? h4.y : (u == 2) ? h4.z : h4.w;
        ushort4 wz4 = *(const ushort4*)&Wl[0][i][j0];
        ushort4 wr4 = *(const ushort4*)&Wl[1][i][j0];
        az[0] += hv * bfu(wz4.x); az[1] += hv * bfu(wz4.y);
        az[2] += hv * bfu(wz4.z); az[3] += hv * bfu(wz4.w);
        ar[0] += hv * bfu(wr4.x); ar[1] += hv * bfu(wr4.y);
        ar[2] += hv * bfu(wr4.z); ar[3] += hv * bfu(wr4.w);
      }
    }
    float ho[4], z[4], rh4[4];
#pragma unroll
    for (int k = 0; k < 4; ++k) {
      ho[k] = hS[rw][j0 + k];
      z[k] = sigm(az[k] + exz[k]);
      rh4[k] = sigm(ar[k] + exr[k]) * ho[k];
    }
    *(float4*)&rhS[rw][j0] = make_float4(rh4[0], rh4[1], rh4[2], rh4[3]);
    __syncthreads();  // B: rhS ready; all hS reads (az/ar, ho) done
    float ah[4] = {0, 0, 0, 0};
#pragma unroll
    for (int i4 = 0; i4 < 12; ++i4) {
      float4 r4 = *(const float4*)&rhS[rw][i4 * 4];
#pragma unroll
      for (int u = 0; u < 4; ++u) {
        int i = i4 * 4 + u;
        float rv = (u == 0) ? r4.x : (u == 1) ? r4.y : (u == 2) ? r4.z : r4.w;
        ushort4 wh4 = *(const ushort4*)&Wl[2][i][j0];
        ah[0] += rv * bfu(wh4.x); ah[1] += rv * bfu(wh4.y);
        ah[2] += rv * bfu(wh4.z); ah[3] += rv * bfu(wh4.w);
      }
    }
    float hn[4];
#pragma unroll
    for (int k = 0; k < 4; ++k)
      hn[k] = (1.f - z[k]) * ho[k] + z[k] * tanh_(ah[k] + exh[k]);
    *(float4*)&hS[rw][j0] = make_float4(hn[0], hn[1], hn[2], hn[3]);  // safe: hS reads ended pre-B
    __syncthreads();  // C: hS fully updated; rhS/W reads done -> next ds_write safe
    if (step >= 11 && tid < 16) {
      int row2 = blockIdx.x * 16 + tid;
      int b2 = row2 / N_, n2 = row2 % N_;
      float s = boutS;
#pragma unroll
      for (int i4 = 0; i4 < 12; ++i4) {
        float4 h4 = *(const float4*)&hS[tid][i4 * 4];
        float4 w4 = *(const float4*)&woutS[i4 * 4];
        s += h4.x * w4.x + h4.y * w4.y + h4.z * w4.z + h4.w * w4.w;
      }
      sto(out, ((size_t)b2 * TP_ + (step - 11)) * N_ + n2, s);
    }
  }
}
__global__ __launch_bounds__(192) void k_gru2(
    const int* dtf, const bf16* encx, const bf16* decx, const bf16* pw,
    const void* Wout, const void* bout, void* out) {
  if (*dtf)
    gru2_body<float, float>(encx, decx, pw, (const float*)Wout, (const float*)bout, (float*)out);
  else
    gru2_body<bf16, bf16>(encx, decx, pw, (const bf16*)Wout, (const bf16*)bout, (bf16*)out);
}

// ---------------------------------------------------------------------------
extern "C" void kernel_launch(void* const* d_in, const int* in_sizes, int n_in,
                              void* d_out, int out_size, void* d_ws, size_t ws_size,
                              hipStream_t stream) {
  (void)in_sizes; (void)n_in; (void)out_size; (void)ws_size;
  const void* x       = d_in[0];
  const void* T       = d_in[1];
  const void* Wq_t    = d_in[3];
  const void* Wk_t    = d_in[4];
  const void* Wv_t    = d_in[5];
  const void* Wq_st   = d_in[6];
  const void* Wk_st   = d_in[7];
  const void* Wv_st   = d_in[8];
  const void* bq_t    = d_in[9];
  const void* bk_t    = d_in[10];
  const void* bv_t    = d_in[11];
  const void* bq_st   = d_in[12];
  const void* bk_st   = d_in[13];
  const void* bv_st   = d_in[14];
  const void* conv1_w = d_in[15];
  const void* conv1_b = d_in[16];
  const void* Wproj_t = d_in[17];
  const void* bproj_t = d_in[18];
  const void* Wproj_st= d_in[19];
  const void* bproj_st= d_in[20];
  const void* xhr_wz  = d_in[21];
  const void* xhr_wr  = d_in[22];
  const void* xhr_wh  = d_in[23];
  const void* xhr_bz  = d_in[24];
  const void* xhr_br  = d_in[25];
  const void* xhr_bh  = d_in[26];
  const void* last_wz = d_in[27];
  const void* last_wr = d_in[28];
  const void* last_wh = d_in[29];
  const void* last_bz = d_in[30];
  const void* last_br = d_in[31];
  const void* last_bh = d_in[32];
  const void* Wout    = d_in[33];
  const void* bout    = d_in[34];

  // ws layout (~13.4 MB; 14.8 MB proven safe in round 2)
  char* wsb = (char*)d_ws;
  int* dtf     = (int*)wsb;                              // 256 B
  bf16* att_t  = (bf16*)(wsb + 256);                     // 2*11*800*48
  bf16* att_st = att_t + (size_t)2 * 11 * 800 * 48;
  bf16* encx   = att_st + (size_t)2 * 11 * 800 * 48;     // 2*11*800*144
  bf16* decx   = encx + (size_t)2 * 11 * 800 * 144;      // 2*10*800*144
  bf16* pw     = decx + (size_t)2 * 10 * 800 * 144;      // 21*6912

  k_detect<<<1, 64, 0, stream>>>((const unsigned int*)x, dtf);
  k_pack<<<(21 * 6912 + 255) / 256, 256, 0, stream>>>(
      dtf, xhr_wz, xhr_wr, xhr_wh, last_wz, last_wr, last_wh, pw);
  {
    int total = B_ * (TIN_ - 1) * H_ * N_;
    k_temporal<<<(total + 255) / 256, 256, 0, stream>>>(
        dtf, x, Wq_t, Wk_t, Wv_t, bq_t, bk_t, bv_t, att_t);
  }
  k_spatial2<<<dim3(4, 11, 2), 832, 0, stream>>>(
      dtf, x, Wq_st, Wk_st, Wv_st, bq_st, bk_st, bv_st, att_st);
  k_projx<<<dim3(13, 11, 2), 192, 0, stream>>>(
      dtf, att_t, att_st, Wproj_t, bproj_t, Wproj_st, bproj_st,
      xhr_wz, xhr_wr, xhr_wh, xhr_bz, xhr_br, xhr_bh, encx);
  k_convx<<<dim3(13, 10, 2), 192, 0, stream>>>(
      dtf, x, T, conv1_w, conv1_b, last_wz, last_wr, last_wh,
      last_bz, last_br, last_bh, decx);
  k_gru2<<<100, 192, 0, stream>>>(
      dtf, encx, decx, pw, Wout, bout, d_out);
}

// Round 6
// 263.794 us; speedup vs baseline: 4.1054x; 1.0130x over previous
//
#include <hip/hip_runtime.h>
#include <hip/hip_bf16.h>

typedef __hip_bfloat16 bf16;

#define B_ 2
#define TIN_ 12
#define N_ 800
#define F_ 2
#define H_ 6
#define D_ 8
#define C_ 48
#define TP_ 10
#define KW_ 14
#define SCALE 0.35355339059327373f  // 1/sqrt(8)
#define LOG2E 1.4426950408889634f

__device__ __forceinline__ float sigm(float x) { return 1.0f / (1.0f + __expf(-x)); }
__device__ __forceinline__ float tanh_(float x) {
  float e = __expf(-2.0f * x);
  return 2.0f / (1.0f + e) - 1.0f;
}
__device__ __forceinline__ float exp2_(float x) { return __builtin_amdgcn_exp2f(x); }
__device__ __forceinline__ float bfu(unsigned short u) {
  return __uint_as_float((unsigned)u << 16);
}
// dual-dtype scalar loads (overload on pointer type; kernels template on TI)
__device__ __forceinline__ float ldc(const float* p, size_t i) { return p[i]; }
__device__ __forceinline__ float ldc(const bf16* p, size_t i) { return __bfloat162float(p[i]); }
__device__ __forceinline__ void ld4(const float* p, size_t i, float o[4]) {
  float4 v = *(const float4*)(p + i);
  o[0] = v.x; o[1] = v.y; o[2] = v.z; o[3] = v.w;
}
__device__ __forceinline__ void ld4(const bf16* p, size_t i, float o[4]) {
  ushort4 v = *(const ushort4*)((const unsigned short*)p + i);
  o[0] = bfu(v.x); o[1] = bfu(v.y); o[2] = bfu(v.z); o[3] = bfu(v.w);
}
__device__ __forceinline__ void sto(float* p, size_t i, float v) { p[i] = v; }
__device__ __forceinline__ void sto(bf16* p, size_t i, float v) { p[i] = __float2bfloat16(v); }
__device__ __forceinline__ void ld4s(const bf16* p, size_t i, float o[4]) { ld4(p, i, o); }
__device__ __forceinline__ void st4s(bf16* p, size_t i, const float v[4]) {
  ushort4 u;
  u.x = __bfloat16_as_ushort(__float2bfloat16(v[0]));
  u.y = __bfloat16_as_ushort(__float2bfloat16(v[1]));
  u.z = __bfloat16_as_ushort(__float2bfloat16(v[2]));
  u.w = __bfloat16_as_ushort(__float2bfloat16(v[3]));
  *(ushort4*)((unsigned short*)p + i) = u;
}

// ---------------- Kernel 0: dtype detector --------------------------------
__global__ void k_detect(const unsigned int* __restrict__ xw, int* __restrict__ flag) {
  int lane = threadIdx.x;  // 64
  unsigned int w = xw[lane];
  int e = (w >> 7) & 0xFF;  // exponent of LOW bf16 slot
  int bad = ((e >= 1 && e < 96) || (e > 150)) ? 1 : 0;
  unsigned long long m = __ballot(bad);
  if (lane == 0) *flag = (__popcll(m) >= 16) ? 1 : 0;
}

// ---------------- Kernel P: pack recurrent GRU weights to f32 -------------
// pwf[step][6912]: steps 0..10 = xhr rows 96:144 (t=1..11); 11..20 = last rows 48:96.
template <typename TI>
__device__ __forceinline__ void pack_body(
    const TI* xwz, const TI* xwr, const TI* xwh,
    const TI* lwz, const TI* lwr, const TI* lwh, float* pwf) {
  int gid = blockIdx.x * 256 + threadIdx.x;
  const int total = 21 * 6912;
  if (gid >= total) return;
  int step = gid / 6912, e = gid % 6912;
  int g = e / 2304, i = (e % 2304) / 48, j = e % 48;
  float v;
  if (step < 11) {
    int t = step + 1;
    const TI* w = (g == 0) ? xwz : (g == 1) ? xwr : xwh;
    v = ldc(w, ((size_t)t * 144 + 96 + i) * 48 + j);
  } else {
    int t = step - 11;
    const TI* w = (g == 0) ? lwz : (g == 1) ? lwr : lwh;
    v = ldc(w, ((size_t)t * 96 + 48 + i) * 48 + j);
  }
  pwf[gid] = v;
}
__global__ void k_pack(const int* dtf, const void* xwz, const void* xwr, const void* xwh,
                       const void* lwz, const void* lwr, const void* lwh, float* pwf) {
  if (*dtf)
    pack_body<float>((const float*)xwz, (const float*)xwr, (const float*)xwh,
                     (const float*)lwz, (const float*)lwr, (const float*)lwh, pwf);
  else
    pack_body<bf16>((const bf16*)xwz, (const bf16*)xwr, (const bf16*)xwh,
                    (const bf16*)lwz, (const bf16*)lwr, (const bf16*)lwh, pwf);
}

// ---------------- Kernel A: temporal causal attention (t=1..11) -----------
template <typename TI>
__device__ __forceinline__ void temporal_body(
    const TI* x, const TI* Wq, const TI* Wk, const TI* Wv,
    const TI* bq, const TI* bk, const TI* bv, bf16* att_t) {
  int gid = blockIdx.x * blockDim.x + threadIdx.x;
  const int total = B_ * (TIN_ - 1) * H_ * N_;
  if (gid >= total) return;
  int n = gid % N_;
  int r = gid / N_;
  int h = r % H_;  r /= H_;
  int t = (r % (TIN_ - 1)) + 1;
  int b = r / (TIN_ - 1);

  float wq[F_][D_], wk[F_][D_], wv[F_][D_], bqv[D_], bkv[D_], bvv[D_];
#pragma unroll
  for (int f = 0; f < F_; ++f)
#pragma unroll
    for (int d = 0; d < D_; ++d) {
      wq[f][d] = ldc(Wq, (h * F_ + f) * D_ + d);
      wk[f][d] = ldc(Wk, (h * F_ + f) * D_ + d);
      wv[f][d] = ldc(Wv, (h * F_ + f) * D_ + d);
    }
#pragma unroll
  for (int d = 0; d < D_; ++d) {
    bqv[d] = ldc(bq, h * D_ + d);
    bkv[d] = ldc(bk, h * D_ + d);
    bvv[d] = ldc(bv, h * D_ + d);
  }
  float xt0 = ldc(x, ((b * TIN_ + t) * N_ + n) * F_ + 0);
  float xt1 = ldc(x, ((b * TIN_ + t) * N_ + n) * F_ + 1);
  float q[D_];
#pragma unroll
  for (int d = 0; d < D_; ++d) q[d] = xt0 * wq[0][d] + xt1 * wq[1][d] + bqv[d];

  float sc[TIN_];
  float mx = -1e30f;
#pragma unroll
  for (int s = 0; s < TIN_; ++s) {
    float xs0 = ldc(x, ((b * TIN_ + s) * N_ + n) * F_ + 0);
    float xs1 = ldc(x, ((b * TIN_ + s) * N_ + n) * F_ + 1);
    float dot = 0.f;
#pragma unroll
    for (int d = 0; d < D_; ++d)
      dot += q[d] * (xs0 * wk[0][d] + xs1 * wk[1][d] + bkv[d]);
    dot *= SCALE;
    sc[s] = (s <= t) ? dot : -1e30f;
    mx = fmaxf(mx, sc[s]);
  }
  float sum = 0.f;
#pragma unroll
  for (int s = 0; s < TIN_; ++s) {
    float p = __expf(sc[s] - mx);
    sc[s] = p;
    sum += p;
  }
  float inv = 1.0f / sum;
  float acc[D_];
#pragma unroll
  for (int d = 0; d < D_; ++d) acc[d] = 0.f;
#pragma unroll
  for (int s = 0; s < TIN_; ++s) {
    float xs0 = ldc(x, ((b * TIN_ + s) * N_ + n) * F_ + 0);
    float xs1 = ldc(x, ((b * TIN_ + s) * N_ + n) * F_ + 1);
#pragma unroll
    for (int d = 0; d < D_; ++d)
      acc[d] += sc[s] * (xs0 * wv[0][d] + xs1 * wv[1][d] + bvv[d]);
  }
  bf16* o = att_t + ((size_t)((b * 11 + (t - 1)) * N_ + n)) * C_ + h * D_;
#pragma unroll
  for (int d = 0; d < D_; ++d) o[d] = __float2bfloat16(acc[d] * inv);
}
__global__ void k_temporal(const int* dtf, const void* x, const void* Wq, const void* Wk,
                           const void* Wv, const void* bq, const void* bk, const void* bv,
                           bf16* att_t) {
  if (*dtf)
    temporal_body<float>((const float*)x, (const float*)Wq, (const float*)Wk, (const float*)Wv,
                         (const float*)bq, (const float*)bk, (const float*)bv, att_t);
  else
    temporal_body<bf16>((const bf16*)x, (const bf16*)Wq, (const bf16*)Wk, (const bf16*)Wv,
                        (const bf16*)bq, (const bf16*)bk, (const bf16*)bv, att_t);
}

// ---------------- Kernel B: spatial attention, rank-2 form ----------------
#define ST_ROWS 200
#define ST_MS 4
template <typename TI>
__device__ __forceinline__ void spatial2_body(
    const TI* x, const TI* Wq, const TI* Wk, const TI* Wv,
    const TI* bq, const TI* bk, const TI* bv, bf16* att_st) {
  __shared__ float2 xs[N_];                 // 6.4 KB
  __shared__ float M[H_][9];                // 3x3 per head, SCALE*LOG2E folded
  __shared__ float Vw[H_][3][D_];           // wv0, wv1, bv
  __shared__ float pt[ST_MS][ST_ROWS][19];  // partials Sp,S0,S1 x 6 heads
  int tile = blockIdx.x, ty = blockIdx.y, b = blockIdx.z;
  int t = ty + 1;
  int tid = threadIdx.x;

  for (int m = tid; m < N_; m += 832)
    xs[m] = make_float2(ldc(x, ((b * TIN_ + t) * N_ + m) * F_ + 0),
                        ldc(x, ((b * TIN_ + t) * N_ + m) * F_ + 1));
  if (tid < 54) {  // M[h][a*3+bb] = dot(qa, kb) * SCALE * LOG2E
    int h = tid / 9, e = tid % 9, a = e / 3, bb = e % 3;
    float acc = 0.f;
    for (int d = 0; d < 8; ++d) {
      float qa = (a == 0) ? ldc(Wq, (h * 2 + 0) * 8 + d)
               : (a == 1) ? ldc(Wq, (h * 2 + 1) * 8 + d) : ldc(bq, h * 8 + d);
      float kb = (bb == 0) ? ldc(Wk, (h * 2 + 0) * 8 + d)
               : (bb == 1) ? ldc(Wk, (h * 2 + 1) * 8 + d) : ldc(bk, h * 8 + d);
      acc += qa * kb;
    }
    M[h][e] = acc * SCALE * LOG2E;
  }
  if (tid >= 64 && tid < 64 + 144) {
    int e = tid - 64;
    int h = e / 24, a = (e % 24) / 8, d = e % 8;
    Vw[h][a][d] = (a == 0) ? ldc(Wv, (h * 2 + 0) * 8 + d)
                : (a == 1) ? ldc(Wv, (h * 2 + 1) * 8 + d) : ldc(bv, h * 8 + d);
  }
  __syncthreads();
  if (tid < ST_ROWS * ST_MS) {
    int ms = tid / ST_ROWS, nl = tid % ST_ROWS;
    int n = tile * ST_ROWS + nl;
    float x0 = xs[n].x, x1 = xs[n].y;
    float A[6], Bc[6], Cc[6];
#pragma unroll
    for (int h = 0; h < 6; ++h) {
      A[h]  = M[h][0] * x0 + M[h][3] * x1 + M[h][6];
      Bc[h] = M[h][1] * x0 + M[h][4] * x1 + M[h][7];
      Cc[h] = M[h][2] * x0 + M[h][5] * x1 + M[h][8];
    }
    float Sp[6] = {0, 0, 0, 0, 0, 0}, S0[6] = {0, 0, 0, 0, 0, 0}, S1[6] = {0, 0, 0, 0, 0, 0};
    for (int m = ms * 200; m < ms * 200 + 200; ++m) {
      float2 xm = xs[m];
#pragma unroll
      for (int h = 0; h < 6; ++h) {
        float p = exp2_(A[h] * xm.x + Bc[h] * xm.y + Cc[h]);
        Sp[h] += p;
        S0[h] += p * xm.x;
        S1[h] += p * xm.y;
      }
    }
#pragma unroll
    for (int h = 0; h < 6; ++h) {
      pt[ms][nl][h * 3 + 0] = Sp[h];
      pt[ms][nl][h * 3 + 1] = S0[h];
      pt[ms][nl][h * 3 + 2] = S1[h];
    }
  }
  __syncthreads();
  if (tid < ST_ROWS) {
    int n = tile * ST_ROWS + tid;
    bf16* o = att_st + ((size_t)((b * 11 + ty) * N_ + n)) * C_;
#pragma unroll
    for (int h = 0; h < 6; ++h) {
      float Sp = pt[0][tid][h * 3] + pt[1][tid][h * 3] + pt[2][tid][h * 3] + pt[3][tid][h * 3];
      float S0 = pt[0][tid][h * 3 + 1] + pt[1][tid][h * 3 + 1] + pt[2][tid][h * 3 + 1] + pt[3][tid][h * 3 + 1];
      float S1 = pt[0][tid][h * 3 + 2] + pt[1][tid][h * 3 + 2] + pt[2][tid][h * 3 + 2] + pt[3][tid][h * 3 + 2];
      float inv = 1.f / Sp;
#pragma unroll
      for (int d = 0; d < 8; ++d)
        o[h * 8 + d] = __float2bfloat16((S0 * Vw[h][0][d] + S1 * Vw[h][1][d] + Sp * Vw[h][2][d]) * inv);
    }
  }
}
__global__ __launch_bounds__(832) void k_spatial2(
    const int* dtf, const void* x, const void* Wq, const void* Wk, const void* Wv,
    const void* bq, const void* bk, const void* bv, bf16* att_st) {
  if (*dtf)
    spatial2_body<float>((const float*)x, (const float*)Wq, (const float*)Wk, (const float*)Wv,
                         (const float*)bq, (const float*)bk, (const float*)bv, att_st);
  else
    spatial2_body<bf16>((const bf16*)x, (const bf16*)Wq, (const bf16*)Wk, (const bf16*)Wv,
                        (const bf16*)bq, (const bf16*)bk, (const bf16*)bv, att_st);
}

// ---------------- Kernel C: proj + encoder x-parts ------------------------
template <typename TI>
__device__ __forceinline__ void projx_body(
    const bf16* att_t, const bf16* att_st,
    const TI* Wpt, const TI* bpt, const TI* Wps, const TI* bps,
    const TI* xhr_wz, const TI* xhr_wr, const TI* xhr_wh,
    const TI* xhr_bz, const TI* xhr_br, const TI* xhr_bh,
    bf16* encx) {
  __shared__ unsigned short raw[64][96];
  __shared__ float catS[64][100];
  __shared__ float Wp[2][48][48];
  int tile = blockIdx.x, ty = blockIdx.y, b = blockIdx.z;
  int t = ty + 1;
  int tid = threadIdx.x;
  int rw = tid / 12, jl = tid % 12;

  for (int p = 0; p < 24; ++p) {
    int e = tid + p * 192;
    int half = e / 2304, k = (e % 2304) / 48, i = e % 48;
    Wp[half][k][i] = half ? ldc(Wps, k * 48 + i) : ldc(Wpt, k * 48 + i);
  }
  for (int p = 0; p < 32; ++p) {
    int e = tid + p * 192;
    int rr = e / 96, c = e % 96;
    int n = tile * 64 + rr; if (n > 799) n = 799;
    size_t base = ((size_t)((b * 11 + ty) * N_ + n)) * C_;
    bf16 v = (c < 48) ? att_t[base + c] : att_st[base + (c - 48)];
    raw[rr][c] = __bfloat16_as_ushort(v);
  }
  __syncthreads();
  {
    int half = (jl >= 6);
    int ii0 = jl * 8 - half * 48;
    float acc[4][8];
#pragma unroll
    for (int q = 0; q < 4; ++q)
#pragma unroll
      for (int m = 0; m < 8; ++m)
        acc[q][m] = half ? ldc(bps, ii0 + m) : ldc(bpt, ii0 + m);
    for (int k = 0; k < 48; ++k) {
      float rv[4];
#pragma unroll
      for (int q = 0; q < 4; ++q)
        rv[q] = __uint_as_float((unsigned)raw[rw * 4 + q][half * 48 + k] << 16);
      const float4 wa = *(const float4*)&Wp[half][k][ii0];
      const float4 wb = *(const float4*)&Wp[half][k][ii0 + 4];
      float w8[8] = {wa.x, wa.y, wa.z, wa.w, wb.x, wb.y, wb.z, wb.w};
#pragma unroll
      for (int q = 0; q < 4; ++q)
#pragma unroll
        for (int m = 0; m < 8; ++m) acc[q][m] += rv[q] * w8[m];
    }
#pragma unroll
    for (int q = 0; q < 4; ++q) {
      *(float4*)&catS[rw * 4 + q][jl * 8] = make_float4(acc[q][0], acc[q][1], acc[q][2], acc[q][3]);
      *(float4*)&catS[rw * 4 + q][jl * 8 + 4] = make_float4(acc[q][4], acc[q][5], acc[q][6], acc[q][7]);
    }
  }
  __syncthreads();
  {
    int j0r = jl * 12;
    int g = j0r / 48, jj0 = j0r % 48;
    const TI* wx = (g == 0) ? xhr_wz : (g == 1) ? xhr_wr : xhr_wh;
    const TI* bx = (g == 0) ? xhr_bz : (g == 1) ? xhr_br : xhr_bh;
    float acc[4][12];
#pragma unroll
    for (int q = 0; q < 4; ++q)
#pragma unroll
      for (int m = 0; m < 12; ++m) acc[q][m] = 0.f;
    for (int i = 0; i < 96; ++i) {
      float w12[12];
      size_t wb = ((size_t)t * 144 + i) * 48 + jj0;
      ld4(wx, wb, w12); ld4(wx, wb + 4, w12 + 4); ld4(wx, wb + 8, w12 + 8);
      float cv[4];
#pragma unroll
      for (int q = 0; q < 4; ++q) cv[q] = catS[rw * 4 + q][i];
#pragma unroll
      for (int q = 0; q < 4; ++q)
#pragma unroll
        for (int m = 0; m < 12; ++m) acc[q][m] += cv[q] * w12[m];
    }
#pragma unroll
    for (int q = 0; q < 4; ++q) {
      int n = tile * 64 + rw * 4 + q;
      if (n < 800) {
        float v[12];
#pragma unroll
        for (int m = 0; m < 12; ++m)
          v[m] = acc[q][m] + ldc(bx, ((size_t)t * N_ + n) * C_ + jj0 + m);
        size_t ob = ((size_t)((b * 11 + ty) * N_ + n)) * 144 + j0r;
        st4s(encx, ob, v); st4s(encx, ob + 4, v + 4); st4s(encx, ob + 8, v + 8);
      }
    }
  }
}
__global__ __launch_bounds__(192) void k_projx(
    const int* dtf, const bf16* att_t, const bf16* att_st,
    const void* Wpt, const void* bpt, const void* Wps, const void* bps,
    const void* xwz, const void* xwr, const void* xwh,
    const void* xbz, const void* xbr, const void* xbh, bf16* encx) {
  if (*dtf)
    projx_body<float>(att_t, att_st, (const float*)Wpt, (const float*)bpt, (const float*)Wps,
                      (const float*)bps, (const float*)xwz, (const float*)xwr, (const float*)xwh,
                      (const float*)xbz, (const float*)xbr, (const float*)xbh, encx);
  else
    projx_body<bf16>(att_t, att_st, (const bf16*)Wpt, (const bf16*)bpt, (const bf16*)Wps,
                     (const bf16*)bps, (const bf16*)xwz, (const bf16*)xwr, (const bf16*)xwh,
                     (const bf16*)xbz, (const bf16*)xbr, (const bf16*)xbh, encx);
}

// ---------------- Kernel D: conv1 + decoder x-parts -----------------------
template <typename TI>
__device__ __forceinline__ void convx_body(
    const TI* x, const TI* T,
    const TI* conv1_w, const TI* conv1_b,
    const TI* lwz, const TI* lwr, const TI* lwh,
    const TI* lbz, const TI* lbr, const TI* lbh,
    bf16* decx) {
  __shared__ float tpw[64][KW_][2];
  __shared__ float cw[2][KW_][48];
  __shared__ float preS[64][48];
  __shared__ float Wlx[48][144];
  int tile = blockIdx.x, t = blockIdx.y, b = blockIdx.z;
  int tid = threadIdx.x;
  int rw = tid / 12, jl = tid % 12;

  for (int p = 0; p < 7; ++p) {
    int e = tid + p * 192;
    int f = e / (KW_ * 48), rem = e % (KW_ * 48), k = rem / 48, c = rem % 48;
    cw[f][k][c] = ldc(conv1_w, (c * F_ + f) * KW_ + k);
  }
  for (int p = 0; p < 10; ++p) {
    int e = tid + p * 192;
    if (e < 64 * KW_ * 2) {
      int rr = e / (KW_ * 2), rem = e % (KW_ * 2), k = rem / 2, f = rem % 2;
      int n = tile * 64 + rr; if (n > 799) n = 799;
      int tau = t + k;
      float v;
      if (tau < TIN_) v = ldc(x, ((size_t)(b * TIN_ + tau) * N_ + n) * F_ + f);
      else if (tau < TIN_ + TP_) v = (f == 0) ? 0.f : ldc(T, (size_t)(b * TP_ + (tau - TIN_)) * N_ + n);
      else v = ldc(x, ((size_t)(b * TIN_ + 0) * N_ + n) * F_ + f);
      tpw[rr][k][f] = v;
    }
  }
  for (int p = 0; p < 36; ++p) {
    int e = tid + p * 192;
    int i = e / 144, jg = e % 144, g = jg / 48, j = jg % 48;
    const TI* w = (g == 0) ? lwz : (g == 1) ? lwr : lwh;
    Wlx[i][jg] = ldc(w, ((size_t)t * 96 + i) * 48 + j);
  }
  __syncthreads();
  {
    int c0 = jl * 4;
    float acc[4][4];
#pragma unroll
    for (int q = 0; q < 4; ++q)
#pragma unroll
      for (int m = 0; m < 4; ++m) acc[q][m] = ldc(conv1_b, c0 + m);
#pragma unroll
    for (int f = 0; f < 2; ++f)
      for (int k = 0; k < KW_; ++k) {
        const float4 w4 = *(const float4*)&cw[f][k][c0];
        float wv[4] = {w4.x, w4.y, w4.z, w4.w};
#pragma unroll
        for (int q = 0; q < 4; ++q) {
          float tv = tpw[rw * 4 + q][k][f];
#pragma unroll
          for (int m = 0; m < 4; ++m) acc[q][m] += tv * wv[m];
        }
      }
#pragma unroll
    for (int q = 0; q < 4; ++q)
      *(float4*)&preS[rw * 4 + q][c0] = make_float4(acc[q][0], acc[q][1], acc[q][2], acc[q][3]);
  }
  __syncthreads();
  {
    int j0r = jl * 12;
    int g = j0r / 48, jj0 = j0r % 48;
    const TI* bx = (g == 0) ? lbz : (g == 1) ? lbr : lbh;
    float acc[4][12];
#pragma unroll
    for (int q = 0; q < 4; ++q)
#pragma unroll
      for (int m = 0; m < 12; ++m) acc[q][m] = 0.f;
    for (int i = 0; i < 48; ++i) {
      const float4 wa = *(const float4*)&Wlx[i][j0r];
      const float4 wb = *(const float4*)&Wlx[i][j0r + 4];
      const float4 wc = *(const float4*)&Wlx[i][j0r + 8];
      float w12[12] = {wa.x, wa.y, wa.z, wa.w, wb.x, wb.y, wb.z, wb.w, wc.x, wc.y, wc.z, wc.w};
      float pv[4];
#pragma unroll
      for (int q = 0; q < 4; ++q) pv[q] = preS[rw * 4 + q][i];
#pragma unroll
      for (int q = 0; q < 4; ++q)
#pragma unroll
        for (int m = 0; m < 12; ++m) acc[q][m] += pv[q] * w12[m];
    }
#pragma unroll
    for (int q = 0; q < 4; ++q) {
      int n = tile * 64 + rw * 4 + q;
      if (n < 800) {
        float v[12];
#pragma unroll
        for (int m = 0; m < 12; ++m)
          v[m] = acc[q][m] + ldc(bx, ((size_t)t * N_ + n) * C_ + jj0 + m);
        size_t ob = ((size_t)((b * TP_ + t) * N_ + n)) * 144 + j0r;
        st4s(decx, ob, v); st4s(decx, ob + 4, v + 4); st4s(decx, ob + 8, v + 8);
      }
    }
  }
}
__global__ __launch_bounds__(192) void k_convx(
    const int* dtf, const void* x, const void* T, const void* cw, const void* cb,
    const void* lwz, const void* lwr, const void* lwh,
    const void* lbz, const void* lbr, const void* lbh, bf16* decx) {
  if (*dtf)
    convx_body<float>((const float*)x, (const float*)T, (const float*)cw, (const float*)cb,
                      (const float*)lwz, (const float*)lwr, (const float*)lwh,
                      (const float*)lbz, (const float*)lbr, (const float*)lbh, decx);
  else
    convx_body<bf16>((const bf16*)x, (const bf16*)T, (const bf16*)cw, (const bf16*)cb,
                     (const bf16*)lwz, (const bf16*)lwr, (const bf16*)lwh,
                     (const bf16*)lbz, (const bf16*)lbr, (const bf16*)lbh, decx);
}

// ---------------- Kernel E: wave-autonomous GRU ----------------------------
// 200 blocks x 128 thr (2 waves). Wave = 4 rows x 12 j-lanes (16 idle lanes).
// All h/rh exchange wave-local (no barrier); 1 barrier/step for shared W dbuf.
// W is f32 (pwf), double-buffered in LDS; W[t+1] reg-prefetched at step top,
// ds-written mid-step (latency hidden under z/r dot). x-parts reg-prefetched.
template <typename TI, typename TO>
__device__ __forceinline__ void gru3_body(
    const bf16* encx, const bf16* decx, const float* pwf,
    const TI* Wout, const TI* bout, TO* out) {
  __shared__ float Wf[2][3 * 48 * 48];       // 55.3 KB
  __shared__ float hS[8][52], rhS[8][52];
  __shared__ float outP[8][12];
  __shared__ float woutS[49];
  int tid = threadIdx.x;
  int lane = tid & 63;
  int rg = lane / 12;                        // 0..3 compute, >=4 idle
  int jl = lane % 12, j0 = jl * 4;
  int rw = (tid >> 6) * 4 + rg;              // 0..7 when active
  bool act = (rg < 4);
  int rowg = blockIdx.x * 8 + (act ? rw : 0);
  int b = rowg / N_, n = rowg % N_;

  if (tid < 48) woutS[tid] = ldc(Wout, tid);
  if (tid == 48) woutS[48] = ldc(bout, 0);
  for (int e = tid; e < 8 * 52; e += 128) (&hS[0][0])[e] = 0.f;

  // stage W[0]
  {
    const float4* src = (const float4*)pwf;
    float4* dst = (float4*)&Wf[0][0];
#pragma unroll
    for (int k = 0; k < 14; ++k) {
      int e = k * 128 + tid;
      if (e < 1728) dst[e] = src[e];
    }
  }
  // x[0] into regs
  ushort4 cxz = {0, 0, 0, 0}, cxr = {0, 0, 0, 0}, cxh = {0, 0, 0, 0};
  if (act) {
    size_t eb = (((size_t)(b * 11)) * N_ + n) * 144;
    const unsigned short* ex = (const unsigned short*)encx;
    cxz = *(const ushort4*)(ex + eb + j0);
    cxr = *(const ushort4*)(ex + eb + 48 + j0);
    cxh = *(const ushort4*)(ex + eb + 96 + j0);
  }
  __syncthreads();

  for (int step = 0; step < 21; ++step) {
    int cur = step & 1;
    // prefetch W[step+1] into regs (all 128 threads)
    float4 pf[14];
    if (step < 20) {
      const float4* src = (const float4*)(pwf + (size_t)(step + 1) * 6912);
#pragma unroll
      for (int k = 0; k < 14; ++k) {
        int e = k * 128 + tid;
        pf[k] = (e < 1728) ? src[e] : make_float4(0.f, 0.f, 0.f, 0.f);
      }
    }
    // prefetch x[step+1]
    ushort4 nxz = cxz, nxr = cxr, nxh = cxh;
    if (act && step < 20) {
      int s1 = step + 1;
      size_t eb = (s1 < 11)
          ? (((size_t)(b * 11 + s1)) * N_ + n) * 144
          : (((size_t)(b * 10 + (s1 - 11))) * N_ + n) * 144;
      const unsigned short* ex = (const unsigned short*)((s1 < 11) ? encx : decx);
      nxz = *(const ushort4*)(ex + eb + j0);
      nxr = *(const ushort4*)(ex + eb + 48 + j0);
      nxh = *(const ushort4*)(ex + eb + 96 + j0);
    }

    const float* W0 = &Wf[cur][0];
    float z[4], ho[4], exh[4];
    if (act) {
      float az[4], ar[4];
      az[0] = bfu(cxz.x); az[1] = bfu(cxz.y); az[2] = bfu(cxz.z); az[3] = bfu(cxz.w);
      ar[0] = bfu(cxr.x); ar[1] = bfu(cxr.y); ar[2] = bfu(cxr.z); ar[3] = bfu(cxr.w);
      exh[0] = bfu(cxh.x); exh[1] = bfu(cxh.y); exh[2] = bfu(cxh.z); exh[3] = bfu(cxh.w);
#pragma unroll
      for (int i4 = 0; i4 < 12; ++i4) {
        float4 h4 = *(const float4*)&hS[rw][i4 * 4];
#pragma unroll
        for (int u = 0; u < 4; ++u) {
          int i = i4 * 4 + u;
          float hv = (u == 0) ? h4.x : (u == 1) ? h4.y : (u == 2) ? h4.z : h4.w;
          const float4 wz4 = *(const float4*)(W0 + i * 48 + j0);
          const float4 wr4 = *(const float4*)(W0 + 2304 + i * 48 + j0);
          az[0] += hv * wz4.x; az[1] += hv * wz4.y; az[2] += hv * wz4.z; az[3] += hv * wz4.w;
          ar[0] += hv * wr4.x; ar[1] += hv * wr4.y; ar[2] += hv * wr4.z; ar[3] += hv * wr4.w;
        }
      }
      float rh4[4];
#pragma unroll
      for (int k = 0; k < 4; ++k) {
        ho[k] = hS[rw][j0 + k];
        z[k] = sigm(az[k]);
        rh4[k] = sigm(ar[k]) * ho[k];
      }
      *(float4*)&rhS[rw][j0] = make_float4(rh4[0], rh4[1], rh4[2], rh4[3]);
    }
    asm volatile("" ::: "memory");  // order rhS write before reads (wave-local)

    // write W[step+1] into the other buffer (hidden under z/r latency)
    if (step < 20) {
      float4* dst = (float4*)&Wf[cur ^ 1][0];
#pragma unroll
      for (int k = 0; k < 14; ++k) {
        int e = k * 128 + tid;
        if (e < 1728) dst[e] = pf[k];
      }
    }

    if (act) {
      float ah[4];
      ah[0] = exh[0]; ah[1] = exh[1]; ah[2] = exh[2]; ah[3] = exh[3];
#pragma unroll
      for (int i4 = 0; i4 < 12; ++i4) {
        float4 r4 = *(const float4*)&rhS[rw][i4 * 4];
#pragma unroll
        for (int u = 0; u < 4; ++u) {
          int i = i4 * 4 + u;
          float rv = (u == 0) ? r4.x : (u == 1) ? r4.y : (u == 2) ? r4.z : r4.w;
          const float4 wh4 = *(const float4*)(W0 + 4608 + i * 48 + j0);
          ah[0] += rv * wh4.x; ah[1] += rv * wh4.y; ah[2] += rv * wh4.z; ah[3] += rv * wh4.w;
        }
      }
      float hn[4];
#pragma unroll
      for (int k = 0; k < 4; ++k)
        hn[k] = (1.f - z[k]) * ho[k] + z[k] * tanh_(ah[k]);
      *(float4*)&hS[rw][j0] = make_float4(hn[0], hn[1], hn[2], hn[3]);
      if (step >= 11) {
        outP[rw][jl] = hn[0] * woutS[j0] + hn[1] * woutS[j0 + 1] +
                       hn[2] * woutS[j0 + 2] + hn[3] * woutS[j0 + 3];
      }
    }
    asm volatile("" ::: "memory");
    if (act && step >= 11 && jl == 0) {
      float s = woutS[48];
#pragma unroll
      for (int q = 0; q < 12; ++q) s += outP[rw][q];
      sto(out, ((size_t)b * TP_ + (step - 11)) * N_ + n, s);
    }
    cxz = nxz; cxr = nxr; cxh = nxh;
    __syncthreads();  // buffer swap point (emits vmcnt/lgkmcnt drain)
  }
}
__global__ __launch_bounds__(128) void k_gru3(
    const int* dtf, const bf16* encx, const bf16* decx, const float* pwf,
    const void* Wout, const void* bout, void* out) {
  if (*dtf)
    gru3_body<float, float>(encx, decx, pwf, (const float*)Wout, (const float*)bout, (float*)out);
  else
    gru3_body<bf16, bf16>(encx, decx, pwf, (const bf16*)Wout, (const bf16*)bout, (bf16*)out);
}

// ---------------------------------------------------------------------------
extern "C" void kernel_launch(void* const* d_in, const int* in_sizes, int n_in,
                              void* d_out, int out_size, void* d_ws, size_t ws_size,
                              hipStream_t stream) {
  (void)in_sizes; (void)n_in; (void)out_size; (void)ws_size;
  const void* x       = d_in[0];
  const void* T       = d_in[1];
  const void* Wq_t    = d_in[3];
  const void* Wk_t    = d_in[4];
  const void* Wv_t    = d_in[5];
  const void* Wq_st   = d_in[6];
  const void* Wk_st   = d_in[7];
  const void* Wv_st   = d_in[8];
  const void* bq_t    = d_in[9];
  const void* bk_t    = d_in[10];
  const void* bv_t    = d_in[11];
  const void* bq_st   = d_in[12];
  const void* bk_st   = d_in[13];
  const void* bv_st   = d_in[14];
  const void* conv1_w = d_in[15];
  const void* conv1_b = d_in[16];
  const void* Wproj_t = d_in[17];
  const void* bproj_t = d_in[18];
  const void* Wproj_st= d_in[19];
  const void* bproj_st= d_in[20];
  const void* xhr_wz  = d_in[21];
  const void* xhr_wr  = d_in[22];
  const void* xhr_wh  = d_in[23];
  const void* xhr_bz  = d_in[24];
  const void* xhr_br  = d_in[25];
  const void* xhr_bh  = d_in[26];
  const void* last_wz = d_in[27];
  const void* last_wr = d_in[28];
  const void* last_wh = d_in[29];
  const void* last_bz = d_in[30];
  const void* last_br = d_in[31];
  const void* last_bh = d_in[32];
  const void* Wout    = d_in[33];
  const void* bout    = d_in[34];

  // ws layout (~13.7 MB; 14.8 MB proven safe in round 2)
  char* wsb = (char*)d_ws;
  int* dtf     = (int*)wsb;                              // 256 B
  bf16* att_t  = (bf16*)(wsb + 256);                     // 2*11*800*48
  bf16* att_st = att_t + (size_t)2 * 11 * 800 * 48;
  bf16* encx   = att_st + (size_t)2 * 11 * 800 * 48;     // 2*11*800*144
  bf16* decx   = encx + (size_t)2 * 11 * 800 * 144;      // 2*10*800*144
  float* pwf   = (float*)(decx + (size_t)2 * 10 * 800 * 144);  // 21*6912 f32

  k_detect<<<1, 64, 0, stream>>>((const unsigned int*)x, dtf);
  k_pack<<<(21 * 6912 + 255) / 256, 256, 0, stream>>>(
      dtf, xhr_wz, xhr_wr, xhr_wh, last_wz, last_wr, last_wh, pwf);
  {
    int total = B_ * (TIN_ - 1) * H_ * N_;
    k_temporal<<<(total + 255) / 256, 256, 0, stream>>>(
        dtf, x, Wq_t, Wk_t, Wv_t, bq_t, bk_t, bv_t, att_t);
  }
  k_spatial2<<<dim3(4, 11, 2), 832, 0, stream>>>(
      dtf, x, Wq_st, Wk_st, Wv_st, bq_st, bk_st, bv_st, att_st);
  k_projx<<<dim3(13, 11, 2), 192, 0, stream>>>(
      dtf, att_t, att_st, Wproj_t, bproj_t, Wproj_st, bproj_st,
      xhr_wz, xhr_wr, xhr_wh, xhr_bz, xhr_br, xhr_bh, encx);
  k_convx<<<dim3(13, 10, 2), 192, 0, stream>>>(
      dtf, x, T, conv1_w, conv1_b, last_wz, last_wr, last_wh,
      last_bz, last_br, last_bh, decx);
  k_gru3<<<200, 128, 0, stream>>>(
      dtf, encx, decx, pwf, Wout, bout, d_out);
}

// Round 7
// 238.768 us; speedup vs baseline: 4.5358x; 1.1048x over previous
//
#include <hip/hip_runtime.h>
#include <hip/hip_bf16.h>

typedef __hip_bfloat16 bf16;

#define B_ 2
#define TIN_ 12
#define N_ 800
#define F_ 2
#define H_ 6
#define D_ 8
#define C_ 48
#define TP_ 10
#define KW_ 14
#define SCALE 0.35355339059327373f  // 1/sqrt(8)
#define LOG2E 1.4426950408889634f

__device__ __forceinline__ float sigm(float x) { return 1.0f / (1.0f + __expf(-x)); }
__device__ __forceinline__ float tanh_(float x) {
  float e = __expf(-2.0f * x);
  return 2.0f / (1.0f + e) - 1.0f;
}
__device__ __forceinline__ float exp2_(float x) { return __builtin_amdgcn_exp2f(x); }
__device__ __forceinline__ float bfu(unsigned short u) {
  return __uint_as_float((unsigned)u << 16);
}
__device__ __forceinline__ float ldc(const float* p, size_t i) { return p[i]; }
__device__ __forceinline__ float ldc(const bf16* p, size_t i) { return __bfloat162float(p[i]); }
__device__ __forceinline__ void ld4(const float* p, size_t i, float o[4]) {
  float4 v = *(const float4*)(p + i);
  o[0] = v.x; o[1] = v.y; o[2] = v.z; o[3] = v.w;
}
__device__ __forceinline__ void ld4(const bf16* p, size_t i, float o[4]) {
  ushort4 v = *(const ushort4*)((const unsigned short*)p + i);
  o[0] = bfu(v.x); o[1] = bfu(v.y); o[2] = bfu(v.z); o[3] = bfu(v.w);
}
__device__ __forceinline__ void sto(float* p, size_t i, float v) { p[i] = v; }
__device__ __forceinline__ void sto(bf16* p, size_t i, float v) { p[i] = __float2bfloat16(v); }
__device__ __forceinline__ void ld4s(const bf16* p, size_t i, float o[4]) { ld4(p, i, o); }
__device__ __forceinline__ void st4s(bf16* p, size_t i, const float v[4]) {
  ushort4 u;
  u.x = __bfloat16_as_ushort(__float2bfloat16(v[0]));
  u.y = __bfloat16_as_ushort(__float2bfloat16(v[1]));
  u.z = __bfloat16_as_ushort(__float2bfloat16(v[2]));
  u.w = __bfloat16_as_ushort(__float2bfloat16(v[3]));
  *(ushort4*)((unsigned short*)p + i) = u;
}

// ---------------- Kernel 0: dtype detector --------------------------------
__global__ void k_detect(const unsigned int* __restrict__ xw, int* __restrict__ flag) {
  int lane = threadIdx.x;  // 64
  unsigned int w = xw[lane];
  int e = (w >> 7) & 0xFF;  // exponent of LOW bf16 slot
  int bad = ((e >= 1 && e < 96) || (e > 150)) ? 1 : 0;
  unsigned long long m = __ballot(bad);
  if (lane == 0) *flag = (__popcll(m) >= 16) ? 1 : 0;
}

// ---------------- Kernel P: pack recurrent GRU weights to f32 -------------
// pwf[step][6912]: steps 0..10 = xhr rows 96:144 (t=1..11); 11..20 = last rows 48:96.
template <typename TI>
__device__ __forceinline__ void pack_body(
    const TI* xwz, const TI* xwr, const TI* xwh,
    const TI* lwz, const TI* lwr, const TI* lwh, float* pwf) {
  int gid = blockIdx.x * 256 + threadIdx.x;
  const int total = 21 * 6912;
  if (gid >= total) return;
  int step = gid / 6912, e = gid % 6912;
  int g = e / 2304, i = (e % 2304) / 48, j = e % 48;
  float v;
  if (step < 11) {
    int t = step + 1;
    const TI* w = (g == 0) ? xwz : (g == 1) ? xwr : xwh;
    v = ldc(w, ((size_t)t * 144 + 96 + i) * 48 + j);
  } else {
    int t = step - 11;
    const TI* w = (g == 0) ? lwz : (g == 1) ? lwr : lwh;
    v = ldc(w, ((size_t)t * 96 + 48 + i) * 48 + j);
  }
  pwf[gid] = v;
}
__global__ void k_pack(const int* dtf, const void* xwz, const void* xwr, const void* xwh,
                       const void* lwz, const void* lwr, const void* lwh, float* pwf) {
  if (*dtf)
    pack_body<float>((const float*)xwz, (const float*)xwr, (const float*)xwh,
                     (const float*)lwz, (const float*)lwr, (const float*)lwh, pwf);
  else
    pack_body<bf16>((const bf16*)xwz, (const bf16*)xwr, (const bf16*)xwh,
                    (const bf16*)lwz, (const bf16*)lwr, (const bf16*)lwh, pwf);
}

// ---------------- Kernel A: temporal causal attention (t=1..11) -----------
template <typename TI>
__device__ __forceinline__ void temporal_body(
    const TI* x, const TI* Wq, const TI* Wk, const TI* Wv,
    const TI* bq, const TI* bk, const TI* bv, bf16* att_t) {
  int gid = blockIdx.x * blockDim.x + threadIdx.x;
  const int total = B_ * (TIN_ - 1) * H_ * N_;
  if (gid >= total) return;
  int n = gid % N_;
  int r = gid / N_;
  int h = r % H_;  r /= H_;
  int t = (r % (TIN_ - 1)) + 1;
  int b = r / (TIN_ - 1);

  float wq[F_][D_], wk[F_][D_], wv[F_][D_], bqv[D_], bkv[D_], bvv[D_];
#pragma unroll
  for (int f = 0; f < F_; ++f)
#pragma unroll
    for (int d = 0; d < D_; ++d) {
      wq[f][d] = ldc(Wq, (h * F_ + f) * D_ + d);
      wk[f][d] = ldc(Wk, (h * F_ + f) * D_ + d);
      wv[f][d] = ldc(Wv, (h * F_ + f) * D_ + d);
    }
#pragma unroll
  for (int d = 0; d < D_; ++d) {
    bqv[d] = ldc(bq, h * D_ + d);
    bkv[d] = ldc(bk, h * D_ + d);
    bvv[d] = ldc(bv, h * D_ + d);
  }
  float xt0 = ldc(x, ((b * TIN_ + t) * N_ + n) * F_ + 0);
  float xt1 = ldc(x, ((b * TIN_ + t) * N_ + n) * F_ + 1);
  float q[D_];
#pragma unroll
  for (int d = 0; d < D_; ++d) q[d] = xt0 * wq[0][d] + xt1 * wq[1][d] + bqv[d];

  float sc[TIN_];
  float mx = -1e30f;
#pragma unroll
  for (int s = 0; s < TIN_; ++s) {
    float xs0 = ldc(x, ((b * TIN_ + s) * N_ + n) * F_ + 0);
    float xs1 = ldc(x, ((b * TIN_ + s) * N_ + n) * F_ + 1);
    float dot = 0.f;
#pragma unroll
    for (int d = 0; d < D_; ++d)
      dot += q[d] * (xs0 * wk[0][d] + xs1 * wk[1][d] + bkv[d]);
    dot *= SCALE;
    sc[s] = (s <= t) ? dot : -1e30f;
    mx = fmaxf(mx, sc[s]);
  }
  float sum = 0.f;
#pragma unroll
  for (int s = 0; s < TIN_; ++s) {
    float p = __expf(sc[s] - mx);
    sc[s] = p;
    sum += p;
  }
  float inv = 1.0f / sum;
  float acc[D_];
#pragma unroll
  for (int d = 0; d < D_; ++d) acc[d] = 0.f;
#pragma unroll
  for (int s = 0; s < TIN_; ++s) {
    float xs0 = ldc(x, ((b * TIN_ + s) * N_ + n) * F_ + 0);
    float xs1 = ldc(x, ((b * TIN_ + s) * N_ + n) * F_ + 1);
#pragma unroll
    for (int d = 0; d < D_; ++d)
      acc[d] += sc[s] * (xs0 * wv[0][d] + xs1 * wv[1][d] + bvv[d]);
  }
  bf16* o = att_t + ((size_t)((b * 11 + (t - 1)) * N_ + n)) * C_ + h * D_;
#pragma unroll
  for (int d = 0; d < D_; ++d) o[d] = __float2bfloat16(acc[d] * inv);
}
__global__ void k_temporal(const int* dtf, const void* x, const void* Wq, const void* Wk,
                           const void* Wv, const void* bq, const void* bk, const void* bv,
                           bf16* att_t) {
  if (*dtf)
    temporal_body<float>((const float*)x, (const float*)Wq, (const float*)Wk, (const float*)Wv,
                         (const float*)bq, (const float*)bk, (const float*)bv, att_t);
  else
    temporal_body<bf16>((const bf16*)x, (const bf16*)Wq, (const bf16*)Wk, (const bf16*)Wv,
                        (const bf16*)bq, (const bf16*)bk, (const bf16*)bv, att_t);
}

// ---------------- Kernel B: spatial attention, rank-2 form ----------------
// s_nm = A_n*x0_m + B_n*x1_m + C_n (F=2). PV = (S0*wv0 + S1*wv1 + Sp*bv)/Sp.
// grid (8 row-tiles, 11 t, 2 b) x 832 thr (100 rows x 8 m-splits = 800 workers).
#define ST_TILES 8
#define ST_ROWS 100
#define ST_MS 8
#define ST_MLEN 100
template <typename TI>
__device__ __forceinline__ void spatial2_body(
    const TI* x, const TI* Wq, const TI* Wk, const TI* Wv,
    const TI* bq, const TI* bk, const TI* bv, bf16* att_st) {
  __shared__ float2 xs[N_];                 // 6.4 KB
  __shared__ float M[H_][9];                // 3x3 per head, SCALE*LOG2E folded
  __shared__ float Vw[H_][3][D_];           // wv0, wv1, bv
  __shared__ float pt[ST_MS][ST_ROWS][19];  // partials Sp,S0,S1 x 6 heads
  int tile = blockIdx.x, ty = blockIdx.y, b = blockIdx.z;
  int t = ty + 1;
  int tid = threadIdx.x;

  for (int m = tid; m < N_; m += 832)
    xs[m] = make_float2(ldc(x, ((b * TIN_ + t) * N_ + m) * F_ + 0),
                        ldc(x, ((b * TIN_ + t) * N_ + m) * F_ + 1));
  if (tid < 54) {  // M[h][a*3+bb] = dot(qa, kb) * SCALE * LOG2E
    int h = tid / 9, e = tid % 9, a = e / 3, bb = e % 3;
    float acc = 0.f;
    for (int d = 0; d < 8; ++d) {
      float qa = (a == 0) ? ldc(Wq, (h * 2 + 0) * 8 + d)
               : (a == 1) ? ldc(Wq, (h * 2 + 1) * 8 + d) : ldc(bq, h * 8 + d);
      float kb = (bb == 0) ? ldc(Wk, (h * 2 + 0) * 8 + d)
               : (bb == 1) ? ldc(Wk, (h * 2 + 1) * 8 + d) : ldc(bk, h * 8 + d);
      acc += qa * kb;
    }
    M[h][e] = acc * SCALE * LOG2E;
  }
  if (tid >= 64 && tid < 64 + 144) {
    int e = tid - 64;
    int h = e / 24, a = (e % 24) / 8, d = e % 8;
    Vw[h][a][d] = (a == 0) ? ldc(Wv, (h * 2 + 0) * 8 + d)
                : (a == 1) ? ldc(Wv, (h * 2 + 1) * 8 + d) : ldc(bv, h * 8 + d);
  }
  __syncthreads();
  if (tid < ST_ROWS * ST_MS) {
    int ms = tid / ST_ROWS, nl = tid % ST_ROWS;
    int n = tile * ST_ROWS + nl;
    float x0 = xs[n].x, x1 = xs[n].y;
    float A[6], Bc[6], Cc[6];
#pragma unroll
    for (int h = 0; h < 6; ++h) {
      A[h]  = M[h][0] * x0 + M[h][3] * x1 + M[h][6];
      Bc[h] = M[h][1] * x0 + M[h][4] * x1 + M[h][7];
      Cc[h] = M[h][2] * x0 + M[h][5] * x1 + M[h][8];
    }
    float Sp[6] = {0, 0, 0, 0, 0, 0}, S0[6] = {0, 0, 0, 0, 0, 0}, S1[6] = {0, 0, 0, 0, 0, 0};
    for (int m = ms * ST_MLEN; m < ms * ST_MLEN + ST_MLEN; ++m) {
      float2 xm = xs[m];
#pragma unroll
      for (int h = 0; h < 6; ++h) {
        float p = exp2_(A[h] * xm.x + Bc[h] * xm.y + Cc[h]);
        Sp[h] += p;
        S0[h] += p * xm.x;
        S1[h] += p * xm.y;
      }
    }
#pragma unroll
    for (int h = 0; h < 6; ++h) {
      pt[ms][nl][h * 3 + 0] = Sp[h];
      pt[ms][nl][h * 3 + 1] = S0[h];
      pt[ms][nl][h * 3 + 2] = S1[h];
    }
  }
  __syncthreads();
  if (tid < ST_ROWS) {
    int n = tile * ST_ROWS + tid;
    bf16* o = att_st + ((size_t)((b * 11 + ty) * N_ + n)) * C_;
#pragma unroll
    for (int h = 0; h < 6; ++h) {
      float Sp = 0.f, S0 = 0.f, S1 = 0.f;
#pragma unroll
      for (int ms = 0; ms < ST_MS; ++ms) {
        Sp += pt[ms][tid][h * 3 + 0];
        S0 += pt[ms][tid][h * 3 + 1];
        S1 += pt[ms][tid][h * 3 + 2];
      }
      float inv = 1.f / Sp;
#pragma unroll
      for (int d = 0; d < 8; ++d)
        o[h * 8 + d] = __float2bfloat16((S0 * Vw[h][0][d] + S1 * Vw[h][1][d] + Sp * Vw[h][2][d]) * inv);
    }
  }
}
__global__ __launch_bounds__(832) void k_spatial2(
    const int* dtf, const void* x, const void* Wq, const void* Wk, const void* Wv,
    const void* bq, const void* bk, const void* bv, bf16* att_st) {
  if (*dtf)
    spatial2_body<float>((const float*)x, (const float*)Wq, (const float*)Wk, (const float*)Wv,
                         (const float*)bq, (const float*)bk, (const float*)bv, att_st);
  else
    spatial2_body<bf16>((const bf16*)x, (const bf16*)Wq, (const bf16*)Wk, (const bf16*)Wv,
                        (const bf16*)bq, (const bf16*)bk, (const bf16*)bv, att_st);
}

// ---------------- Kernel C: proj + encoder x-parts ------------------------
template <typename TI>
__device__ __forceinline__ void projx_body(
    const bf16* att_t, const bf16* att_st,
    const TI* Wpt, const TI* bpt, const TI* Wps, const TI* bps,
    const TI* xhr_wz, const TI* xhr_wr, const TI* xhr_wh,
    const TI* xhr_bz, const TI* xhr_br, const TI* xhr_bh,
    bf16* encx) {
  __shared__ unsigned short raw[64][96];
  __shared__ float catS[64][100];
  __shared__ float Wp[2][48][48];
  int tile = blockIdx.x, ty = blockIdx.y, b = blockIdx.z;
  int t = ty + 1;
  int tid = threadIdx.x;
  int rw = tid / 12, jl = tid % 12;

  for (int p = 0; p < 24; ++p) {
    int e = tid + p * 192;
    int half = e / 2304, k = (e % 2304) / 48, i = e % 48;
    Wp[half][k][i] = half ? ldc(Wps, k * 48 + i) : ldc(Wpt, k * 48 + i);
  }
  for (int p = 0; p < 32; ++p) {
    int e = tid + p * 192;
    int rr = e / 96, c = e % 96;
    int n = tile * 64 + rr; if (n > 799) n = 799;
    size_t base = ((size_t)((b * 11 + ty) * N_ + n)) * C_;
    bf16 v = (c < 48) ? att_t[base + c] : att_st[base + (c - 48)];
    raw[rr][c] = __bfloat16_as_ushort(v);
  }
  __syncthreads();
  {
    int half = (jl >= 6);
    int ii0 = jl * 8 - half * 48;
    float acc[4][8];
#pragma unroll
    for (int q = 0; q < 4; ++q)
#pragma unroll
      for (int m = 0; m < 8; ++m)
        acc[q][m] = half ? ldc(bps, ii0 + m) : ldc(bpt, ii0 + m);
    for (int k = 0; k < 48; ++k) {
      float rv[4];
#pragma unroll
      for (int q = 0; q < 4; ++q)
        rv[q] = __uint_as_float((unsigned)raw[rw * 4 + q][half * 48 + k] << 16);
      const float4 wa = *(const float4*)&Wp[half][k][ii0];
      const float4 wb = *(const float4*)&Wp[half][k][ii0 + 4];
      float w8[8] = {wa.x, wa.y, wa.z, wa.w, wb.x, wb.y, wb.z, wb.w};
#pragma unroll
      for (int q = 0; q < 4; ++q)
#pragma unroll
        for (int m = 0; m < 8; ++m) acc[q][m] += rv[q] * w8[m];
    }
#pragma unroll
    for (int q = 0; q < 4; ++q) {
      *(float4*)&catS[rw * 4 + q][jl * 8] = make_float4(acc[q][0], acc[q][1], acc[q][2], acc[q][3]);
      *(float4*)&catS[rw * 4 + q][jl * 8 + 4] = make_float4(acc[q][4], acc[q][5], acc[q][6], acc[q][7]);
    }
  }
  __syncthreads();
  {
    int j0r = jl * 12;
    int g = j0r / 48, jj0 = j0r % 48;
    const TI* wx = (g == 0) ? xhr_wz : (g == 1) ? xhr_wr : xhr_wh;
    const TI* bx = (g == 0) ? xhr_bz : (g == 1) ? xhr_br : xhr_bh;
    float acc[4][12];
#pragma unroll
    for (int q = 0; q < 4; ++q)
#pragma unroll
      for (int m = 0; m < 12; ++m) acc[q][m] = 0.f;
    for (int i = 0; i < 96; ++i) {
      float w12[12];
      size_t wb = ((size_t)t * 144 + i) * 48 + jj0;
      ld4(wx, wb, w12); ld4(wx, wb + 4, w12 + 4); ld4(wx, wb + 8, w12 + 8);
      float cv[4];
#pragma unroll
      for (int q = 0; q < 4; ++q) cv[q] = catS[rw * 4 + q][i];
#pragma unroll
      for (int q = 0; q < 4; ++q)
#pragma unroll
        for (int m = 0; m < 12; ++m) acc[q][m] += cv[q] * w12[m];
    }
#pragma unroll
    for (int q = 0; q < 4; ++q) {
      int n = tile * 64 + rw * 4 + q;
      if (n < 800) {
        float v[12];
#pragma unroll
        for (int m = 0; m < 12; ++m)
          v[m] = acc[q][m] + ldc(bx, ((size_t)t * N_ + n) * C_ + jj0 + m);
        size_t ob = ((size_t)((b * 11 + ty) * N_ + n)) * 144 + j0r;
        st4s(encx, ob, v); st4s(encx, ob + 4, v + 4); st4s(encx, ob + 8, v + 8);
      }
    }
  }
}
__global__ __launch_bounds__(192) void k_projx(
    const int* dtf, const bf16* att_t, const bf16* att_st,
    const void* Wpt, const void* bpt, const void* Wps, const void* bps,
    const void* xwz, const void* xwr, const void* xwh,
    const void* xbz, const void* xbr, const void* xbh, bf16* encx) {
  if (*dtf)
    projx_body<float>(att_t, att_st, (const float*)Wpt, (const float*)bpt, (const float*)Wps,
                      (const float*)bps, (const float*)xwz, (const float*)xwr, (const float*)xwh,
                      (const float*)xbz, (const float*)xbr, (const float*)xbh, encx);
  else
    projx_body<bf16>(att_t, att_st, (const bf16*)Wpt, (const bf16*)bpt, (const bf16*)Wps,
                     (const bf16*)bps, (const bf16*)xwz, (const bf16*)xwr, (const bf16*)xwh,
                     (const bf16*)xbz, (const bf16*)xbr, (const bf16*)xbh, encx);
}

// ---------------- Kernel D: conv1 + decoder x-parts -----------------------
template <typename TI>
__device__ __forceinline__ void convx_body(
    const TI* x, const TI* T,
    const TI* conv1_w, const TI* conv1_b,
    const TI* lwz, const TI* lwr, const TI* lwh,
    const TI* lbz, const TI* lbr, const TI* lbh,
    bf16* decx) {
  __shared__ float tpw[64][KW_][2];
  __shared__ float cw[2][KW_][48];
  __shared__ float preS[64][48];
  __shared__ float Wlx[48][144];
  int tile = blockIdx.x, t = blockIdx.y, b = blockIdx.z;
  int tid = threadIdx.x;
  int rw = tid / 12, jl = tid % 12;

  for (int p = 0; p < 7; ++p) {
    int e = tid + p * 192;
    int f = e / (KW_ * 48), rem = e % (KW_ * 48), k = rem / 48, c = rem % 48;
    cw[f][k][c] = ldc(conv1_w, (c * F_ + f) * KW_ + k);
  }
  for (int p = 0; p < 10; ++p) {
    int e = tid + p * 192;
    if (e < 64 * KW_ * 2) {
      int rr = e / (KW_ * 2), rem = e % (KW_ * 2), k = rem / 2, f = rem % 2;
      int n = tile * 64 + rr; if (n > 799) n = 799;
      int tau = t + k;
      float v;
      if (tau < TIN_) v = ldc(x, ((size_t)(b * TIN_ + tau) * N_ + n) * F_ + f);
      else if (tau < TIN_ + TP_) v = (f == 0) ? 0.f : ldc(T, (size_t)(b * TP_ + (tau - TIN_)) * N_ + n);
      else v = ldc(x, ((size_t)(b * TIN_ + 0) * N_ + n) * F_ + f);
      tpw[rr][k][f] = v;
    }
  }
  for (int p = 0; p < 36; ++p) {
    int e = tid + p * 192;
    int i = e / 144, jg = e % 144, g = jg / 48, j = jg % 48;
    const TI* w = (g == 0) ? lwz : (g == 1) ? lwr : lwh;
    Wlx[i][jg] = ldc(w, ((size_t)t * 96 + i) * 48 + j);
  }
  __syncthreads();
  {
    int c0 = jl * 4;
    float acc[4][4];
#pragma unroll
    for (int q = 0; q < 4; ++q)
#pragma unroll
      for (int m = 0; m < 4; ++m) acc[q][m] = ldc(conv1_b, c0 + m);
#pragma unroll
    for (int f = 0; f < 2; ++f)
      for (int k = 0; k < KW_; ++k) {
        const float4 w4 = *(const float4*)&cw[f][k][c0];
        float wv[4] = {w4.x, w4.y, w4.z, w4.w};
#pragma unroll
        for (int q = 0; q < 4; ++q) {
          float tv = tpw[rw * 4 + q][k][f];
#pragma unroll
          for (int m = 0; m < 4; ++m) acc[q][m] += tv * wv[m];
        }
      }
#pragma unroll
    for (int q = 0; q < 4; ++q)
      *(float4*)&preS[rw * 4 + q][c0] = make_float4(acc[q][0], acc[q][1], acc[q][2], acc[q][3]);
  }
  __syncthreads();
  {
    int j0r = jl * 12;
    int g = j0r / 48, jj0 = j0r % 48;
    const TI* bx = (g == 0) ? lbz : (g == 1) ? lbr : lbh;
    float acc[4][12];
#pragma unroll
    for (int q = 0; q < 4; ++q)
#pragma unroll
      for (int m = 0; m < 12; ++m) acc[q][m] = 0.f;
    for (int i = 0; i < 48; ++i) {
      const float4 wa = *(const float4*)&Wlx[i][j0r];
      const float4 wb = *(const float4*)&Wlx[i][j0r + 4];
      const float4 wc = *(const float4*)&Wlx[i][j0r + 8];
      float w12[12] = {wa.x, wa.y, wa.z, wa.w, wb.x, wb.y, wb.z, wb.w, wc.x, wc.y, wc.z, wc.w};
      float pv[4];
#pragma unroll
      for (int q = 0; q < 4; ++q) pv[q] = preS[rw * 4 + q][i];
#pragma unroll
      for (int q = 0; q < 4; ++q)
#pragma unroll
        for (int m = 0; m < 12; ++m) acc[q][m] += pv[q] * w12[m];
    }
#pragma unroll
    for (int q = 0; q < 4; ++q) {
      int n = tile * 64 + rw * 4 + q;
      if (n < 800) {
        float v[12];
#pragma unroll
        for (int m = 0; m < 12; ++m)
          v[m] = acc[q][m] + ldc(bx, ((size_t)t * N_ + n) * C_ + jj0 + m);
        size_t ob = ((size_t)((b * TP_ + t) * N_ + n)) * 144 + j0r;
        st4s(decx, ob, v); st4s(decx, ob + 4, v + 4); st4s(decx, ob + 8, v + 8);
      }
    }
  }
}
__global__ __launch_bounds__(192) void k_convx(
    const int* dtf, const void* x, const void* T, const void* cw, const void* cb,
    const void* lwz, const void* lwr, const void* lwh,
    const void* lbz, const void* lbr, const void* lbh, bf16* decx) {
  if (*dtf)
    convx_body<float>((const float*)x, (const float*)T, (const float*)cw, (const float*)cb,
                      (const float*)lwz, (const float*)lwr, (const float*)lwh,
                      (const float*)lbz, (const float*)lbr, (const float*)lbh, decx);
  else
    convx_body<bf16>((const bf16*)x, (const bf16*)T, (const bf16*)cw, (const bf16*)cb,
                     (const bf16*)lwz, (const bf16*)lwr, (const bf16*)lwh,
                     (const bf16*)lbz, (const bf16*)lbr, (const bf16*)lbh, decx);
}

// ---------------- Kernel E: register-W GRU (1 wave, 4 rows, no barriers) ---
// 400 blocks x 64 thr. Lane L: jl=L>>2 (col group, 0..11 active), rg=L&3
// (i-range 12rg..12rg+12 AND row index). W tiles live in REGISTERS, loaded
// straight from L2 each step (per-step weights; LDS staging buys nothing).
// Partial dots reduced over rg via shfl_xor(1,2). h/rh in 1.5 KB LDS
// (wave-local; DS pipe is in-order per wave; compiler fence pins order).
template <typename TI, typename TO>
__device__ __forceinline__ void gru4_body(
    const bf16* encx, const bf16* decx, const float* pwf,
    const TI* Wout, const TI* bout, TO* out) {
  __shared__ float hL[4][48];
  __shared__ float rhL[4][48];
  int lane = threadIdx.x;
  int jl = lane >> 2, rg = lane & 3;
  bool act = (jl < 12);
  int jlc = act ? jl : 11;
  int j0 = jlc * 4;
  int rowg = blockIdx.x * 4 + rg;
  int b = rowg / N_, n = rowg % N_;

  float wo0 = ldc(Wout, j0), wo1 = ldc(Wout, j0 + 1);
  float wo2 = ldc(Wout, j0 + 2), wo3 = ldc(Wout, j0 + 3);
  float bo = ldc(bout, 0);
  if (act) *(float4*)&hL[rg][j0] = make_float4(0.f, 0.f, 0.f, 0.f);
  asm volatile("" ::: "memory");

  for (int step = 0; step < 21; ++step) {
    const float* Wp = pwf + (size_t)step * 6912;
    // x-parts for row rg, cols j0..j0+3
    size_t eb = (step < 11)
        ? (((size_t)(b * 11 + step)) * N_ + n) * 144
        : (((size_t)(b * 10 + (step - 11))) * N_ + n) * 144;
    const unsigned short* ex = (const unsigned short*)((step < 11) ? encx : decx);
    ushort4 xz = {0, 0, 0, 0}, xr = {0, 0, 0, 0}, xh = {0, 0, 0, 0};
    if (act) {
      xz = *(const ushort4*)(ex + eb + j0);
      xr = *(const ushort4*)(ex + eb + 48 + j0);
      xh = *(const ushort4*)(ex + eb + 96 + j0);
    }
    // Wz, Wr register tiles: i in [12rg, 12rg+12), j in [j0, j0+4)
    float4 Wz[12], Wr[12];
#pragma unroll
    for (int ii = 0; ii < 12; ++ii) {
      Wz[ii] = *(const float4*)(Wp + (rg * 12 + ii) * 48 + j0);
      Wr[ii] = *(const float4*)(Wp + 2304 + (rg * 12 + ii) * 48 + j0);
    }
    float az[4][4], ar[4][4];
#pragma unroll
    for (int r = 0; r < 4; ++r)
#pragma unroll
      for (int j = 0; j < 4; ++j) { az[r][j] = 0.f; ar[r][j] = 0.f; }
#pragma unroll
    for (int r = 0; r < 4; ++r) {
#pragma unroll
      for (int k = 0; k < 3; ++k) {
        float4 h4 = *(const float4*)&hL[r][rg * 12 + k * 4];
#pragma unroll
        for (int u = 0; u < 4; ++u) {
          int ii = k * 4 + u;
          float hv = (u == 0) ? h4.x : (u == 1) ? h4.y : (u == 2) ? h4.z : h4.w;
          az[r][0] += hv * Wz[ii].x; az[r][1] += hv * Wz[ii].y;
          az[r][2] += hv * Wz[ii].z; az[r][3] += hv * Wz[ii].w;
          ar[r][0] += hv * Wr[ii].x; ar[r][1] += hv * Wr[ii].y;
          ar[r][2] += hv * Wr[ii].z; ar[r][3] += hv * Wr[ii].w;
        }
      }
    }
    // reduce over the 4 rg lanes of each jl group
#pragma unroll
    for (int r = 0; r < 4; ++r)
#pragma unroll
      for (int j = 0; j < 4; ++j) {
        az[r][j] += __shfl_xor(az[r][j], 1);
        az[r][j] += __shfl_xor(az[r][j], 2);
        ar[r][j] += __shfl_xor(ar[r][j], 1);
        ar[r][j] += __shfl_xor(ar[r][j], 2);
      }
    float azr[4], arr_[4];
#pragma unroll
    for (int j = 0; j < 4; ++j) {
      azr[j] = (rg == 0) ? az[0][j] : (rg == 1) ? az[1][j] : (rg == 2) ? az[2][j] : az[3][j];
      arr_[j] = (rg == 0) ? ar[0][j] : (rg == 1) ? ar[1][j] : (rg == 2) ? ar[2][j] : ar[3][j];
    }
    float hold[4] = {0.f, 0.f, 0.f, 0.f};
    if (act) {
      float4 t4 = *(const float4*)&hL[rg][j0];
      hold[0] = t4.x; hold[1] = t4.y; hold[2] = t4.z; hold[3] = t4.w;
    }
    float z[4], rh4[4];
    float xzf[4] = {bfu(xz.x), bfu(xz.y), bfu(xz.z), bfu(xz.w)};
    float xrf[4] = {bfu(xr.x), bfu(xr.y), bfu(xr.z), bfu(xr.w)};
#pragma unroll
    for (int k = 0; k < 4; ++k) {
      z[k] = sigm(azr[k] + xzf[k]);
      rh4[k] = sigm(arr_[k] + xrf[k]) * hold[k];
    }
    if (act) *(float4*)&rhL[rg][j0] = make_float4(rh4[0], rh4[1], rh4[2], rh4[3]);
    asm volatile("" ::: "memory");  // rh write before rh reads (wave in-order DS)
    // Wh tile
    float4 Wh[12];
#pragma unroll
    for (int ii = 0; ii < 12; ++ii)
      Wh[ii] = *(const float4*)(Wp + 4608 + (rg * 12 + ii) * 48 + j0);
    float ah[4][4];
#pragma unroll
    for (int r = 0; r < 4; ++r)
#pragma unroll
      for (int j = 0; j < 4; ++j) ah[r][j] = 0.f;
#pragma unroll
    for (int r = 0; r < 4; ++r) {
#pragma unroll
      for (int k = 0; k < 3; ++k) {
        float4 r4 = *(const float4*)&rhL[r][rg * 12 + k * 4];
#pragma unroll
        for (int u = 0; u < 4; ++u) {
          int ii = k * 4 + u;
          float rv = (u == 0) ? r4.x : (u == 1) ? r4.y : (u == 2) ? r4.z : r4.w;
          ah[r][0] += rv * Wh[ii].x; ah[r][1] += rv * Wh[ii].y;
          ah[r][2] += rv * Wh[ii].z; ah[r][3] += rv * Wh[ii].w;
        }
      }
    }
#pragma unroll
    for (int r = 0; r < 4; ++r)
#pragma unroll
      for (int j = 0; j < 4; ++j) {
        ah[r][j] += __shfl_xor(ah[r][j], 1);
        ah[r][j] += __shfl_xor(ah[r][j], 2);
      }
    float ahr[4];
#pragma unroll
    for (int j = 0; j < 4; ++j)
      ahr[j] = (rg == 0) ? ah[0][j] : (rg == 1) ? ah[1][j] : (rg == 2) ? ah[2][j] : ah[3][j];
    float xhf[4] = {bfu(xh.x), bfu(xh.y), bfu(xh.z), bfu(xh.w)};
    float hn[4];
#pragma unroll
    for (int k = 0; k < 4; ++k)
      hn[k] = (1.f - z[k]) * hold[k] + z[k] * tanh_(ahr[k] + xhf[k]);
    if (act) *(float4*)&hL[rg][j0] = make_float4(hn[0], hn[1], hn[2], hn[3]);
    if (step >= 11) {
      float part = act ? (hn[0] * wo0 + hn[1] * wo1 + hn[2] * wo2 + hn[3] * wo3) : 0.f;
      part += __shfl_xor(part, 4);
      part += __shfl_xor(part, 8);
      part += __shfl_xor(part, 16);
      part += __shfl_xor(part, 32);
      if (lane < 4)  // lane == rg, jl == 0
        sto(out, ((size_t)b * TP_ + (step - 11)) * N_ + n, part + bo);
    }
    asm volatile("" ::: "memory");  // h write before next step's h reads
  }
}
__global__ __launch_bounds__(64) void k_gru4(
    const int* dtf, const bf16* encx, const bf16* decx, const float* pwf,
    const void* Wout, const void* bout, void* out) {
  if (*dtf)
    gru4_body<float, float>(encx, decx, pwf, (const float*)Wout, (const float*)bout, (float*)out);
  else
    gru4_body<bf16, bf16>(encx, decx, pwf, (const bf16*)Wout, (const bf16*)bout, (bf16*)out);
}

// ---------------------------------------------------------------------------
extern "C" void kernel_launch(void* const* d_in, const int* in_sizes, int n_in,
                              void* d_out, int out_size, void* d_ws, size_t ws_size,
                              hipStream_t stream) {
  (void)in_sizes; (void)n_in; (void)out_size; (void)ws_size;
  const void* x       = d_in[0];
  const void* T       = d_in[1];
  const void* Wq_t    = d_in[3];
  const void* Wk_t    = d_in[4];
  const void* Wv_t    = d_in[5];
  const void* Wq_st   = d_in[6];
  const void* Wk_st   = d_in[7];
  const void* Wv_st   = d_in[8];
  const void* bq_t    = d_in[9];
  const void* bk_t    = d_in[10];
  const void* bv_t    = d_in[11];
  const void* bq_st   = d_in[12];
  const void* bk_st   = d_in[13];
  const void* bv_st   = d_in[14];
  const void* conv1_w = d_in[15];
  const void* conv1_b = d_in[16];
  const void* Wproj_t = d_in[17];
  const void* bproj_t = d_in[18];
  const void* Wproj_st= d_in[19];
  const void* bproj_st= d_in[20];
  const void* xhr_wz  = d_in[21];
  const void* xhr_wr  = d_in[22];
  const void* xhr_wh  = d_in[23];
  const void* xhr_bz  = d_in[24];
  const void* xhr_br  = d_in[25];
  const void* xhr_bh  = d_in[26];
  const void* last_wz = d_in[27];
  const void* last_wr = d_in[28];
  const void* last_wh = d_in[29];
  const void* last_bz = d_in[30];
  const void* last_br = d_in[31];
  const void* last_bh = d_in[32];
  const void* Wout    = d_in[33];
  const void* bout    = d_in[34];

  // ws layout (~13.7 MB; 14.8 MB proven safe in round 2)
  char* wsb = (char*)d_ws;
  int* dtf     = (int*)wsb;                              // 256 B
  bf16* att_t  = (bf16*)(wsb + 256);                     // 2*11*800*48
  bf16* att_st = att_t + (size_t)2 * 11 * 800 * 48;
  bf16* encx   = att_st + (size_t)2 * 11 * 800 * 48;     // 2*11*800*144
  bf16* decx   = encx + (size_t)2 * 11 * 800 * 144;      // 2*10*800*144
  float* pwf   = (float*)(decx + (size_t)2 * 10 * 800 * 144);  // 21*6912 f32

  k_detect<<<1, 64, 0, stream>>>((const unsigned int*)x, dtf);
  k_pack<<<(21 * 6912 + 255) / 256, 256, 0, stream>>>(
      dtf, xhr_wz, xhr_wr, xhr_wh, last_wz, last_wr, last_wh, pwf);
  {
    int total = B_ * (TIN_ - 1) * H_ * N_;
    k_temporal<<<(total + 255) / 256, 256, 0, stream>>>(
        dtf, x, Wq_t, Wk_t, Wv_t, bq_t, bk_t, bv_t, att_t);
  }
  k_spatial2<<<dim3(ST_TILES, 11, 2), 832, 0, stream>>>(
      dtf, x, Wq_st, Wk_st, Wv_st, bq_st, bk_st, bv_st, att_st);
  k_projx<<<dim3(13, 11, 2), 192, 0, stream>>>(
      dtf, att_t, att_st, Wproj_t, bproj_t, Wproj_st, bproj_st,
      xhr_wz, xhr_wr, xhr_wh, xhr_bz, xhr_br, xhr_bh, encx);
  k_convx<<<dim3(13, 10, 2), 192, 0, stream>>>(
      dtf, x, T, conv1_w, conv1_b, last_wz, last_wr, last_wh,
      last_bz, last_br, last_bh, decx);
  k_gru4<<<400, 64, 0, stream>>>(
      dtf, encx, decx, pwf, Wout, bout, d_out);
}

// Round 8
// 192.773 us; speedup vs baseline: 5.6180x; 1.2386x over previous
//
#include <hip/hip_runtime.h>
#include <hip/hip_bf16.h>

typedef __hip_bfloat16 bf16;
typedef __attribute__((ext_vector_type(8))) short s8b;   // 8 bf16 (4 VGPR)
typedef __attribute__((ext_vector_type(4))) float f4;    // MFMA C/D

#define B_ 2
#define TIN_ 12
#define N_ 800
#define F_ 2
#define H_ 6
#define D_ 8
#define C_ 48
#define TP_ 10
#define KW_ 14
#define SCALE 0.35355339059327373f  // 1/sqrt(8)
#define LOG2E 1.4426950408889634f

__device__ __forceinline__ float sigm(float x) { return 1.0f / (1.0f + __expf(-x)); }
__device__ __forceinline__ float tanh_(float x) {
  float e = __expf(-2.0f * x);
  return 2.0f / (1.0f + e) - 1.0f;
}
__device__ __forceinline__ float exp2_(float x) { return __builtin_amdgcn_exp2f(x); }
__device__ __forceinline__ float bfu(unsigned short u) {
  return __uint_as_float((unsigned)u << 16);
}
__device__ __forceinline__ float ldc(const float* p, size_t i) { return p[i]; }
__device__ __forceinline__ float ldc(const bf16* p, size_t i) { return __bfloat162float(p[i]); }
__device__ __forceinline__ void ld4(const float* p, size_t i, float o[4]) {
  float4 v = *(const float4*)(p + i);
  o[0] = v.x; o[1] = v.y; o[2] = v.z; o[3] = v.w;
}
__device__ __forceinline__ void ld4(const bf16* p, size_t i, float o[4]) {
  ushort4 v = *(const ushort4*)((const unsigned short*)p + i);
  o[0] = bfu(v.x); o[1] = bfu(v.y); o[2] = bfu(v.z); o[3] = bfu(v.w);
}
__device__ __forceinline__ void sto(float* p, size_t i, float v) { p[i] = v; }
__device__ __forceinline__ void sto(bf16* p, size_t i, float v) { p[i] = __float2bfloat16(v); }
__device__ __forceinline__ void st4s(bf16* p, size_t i, const float v[4]) {
  ushort4 u;
  u.x = __bfloat16_as_ushort(__float2bfloat16(v[0]));
  u.y = __bfloat16_as_ushort(__float2bfloat16(v[1]));
  u.z = __bfloat16_as_ushort(__float2bfloat16(v[2]));
  u.w = __bfloat16_as_ushort(__float2bfloat16(v[3]));
  *(ushort4*)((unsigned short*)p + i) = u;
}

// ---------------- Kernel 0: dtype detector --------------------------------
__global__ void k_detect(const unsigned int* __restrict__ xw, int* __restrict__ flag) {
  int lane = threadIdx.x;  // 64
  unsigned int w = xw[lane];
  int e = (w >> 7) & 0xFF;  // exponent of LOW bf16 slot
  int bad = ((e >= 1 && e < 96) || (e > 150)) ? 1 : 0;
  unsigned long long m = __ballot(bad);
  if (lane == 0) *flag = (__popcll(m) >= 16) ? 1 : 0;
}

// ---------------- Kernel P: pack recurrent weights to MFMA B-fragments ----
// pwb[step][gate][nt][chunk][lane][j] (bf16): B[k][n] with k=32*chunk+(lane>>4)*8+j,
// n = nt*16+(lane&15); k>=48 -> 0. steps 0..10 = xhr rows 96:144 (t=1..11);
// steps 11..20 = last rows 48:96 (t=0..9).
template <typename TI>
__device__ __forceinline__ void pack_body(
    const TI* xwz, const TI* xwr, const TI* xwh,
    const TI* lwz, const TI* lwr, const TI* lwh, bf16* pwb) {
  int gid = blockIdx.x * 256 + threadIdx.x;
  const int total = 21 * 27648;
  if (gid >= total) return;
  int step = gid / 27648, r = gid % 27648;
  int g = r / 9216;  r %= 9216;
  int nt = r / 3072; r %= 3072;
  int c = r / 1536;  r %= 1536;
  int lane = r / 8, j = r % 8;
  int k = 32 * c + (lane >> 4) * 8 + j;
  int n = nt * 16 + (lane & 15);
  float v = 0.f;
  if (k < 48) {
    if (step < 11) {
      int t = step + 1;
      const TI* w = (g == 0) ? xwz : (g == 1) ? xwr : xwh;
      v = ldc(w, ((size_t)t * 144 + 96 + k) * 48 + n);
    } else {
      int t = step - 11;
      const TI* w = (g == 0) ? lwz : (g == 1) ? lwr : lwh;
      v = ldc(w, ((size_t)t * 96 + 48 + k) * 48 + n);
    }
  }
  pwb[gid] = __float2bfloat16(v);
}
__global__ void k_pack(const int* dtf, const void* xwz, const void* xwr, const void* xwh,
                       const void* lwz, const void* lwr, const void* lwh, bf16* pwb) {
  if (*dtf)
    pack_body<float>((const float*)xwz, (const float*)xwr, (const float*)xwh,
                     (const float*)lwz, (const float*)lwr, (const float*)lwh, pwb);
  else
    pack_body<bf16>((const bf16*)xwz, (const bf16*)xwr, (const bf16*)xwh,
                    (const bf16*)lwz, (const bf16*)lwr, (const bf16*)lwh, pwb);
}

// ---------------- Kernel A: temporal causal attention (t=1..11) -----------
template <typename TI>
__device__ __forceinline__ void temporal_body(
    const TI* x, const TI* Wq, const TI* Wk, const TI* Wv,
    const TI* bq, const TI* bk, const TI* bv, bf16* att_t) {
  int gid = blockIdx.x * blockDim.x + threadIdx.x;
  const int total = B_ * (TIN_ - 1) * H_ * N_;
  if (gid >= total) return;
  int n = gid % N_;
  int r = gid / N_;
  int h = r % H_;  r /= H_;
  int t = (r % (TIN_ - 1)) + 1;
  int b = r / (TIN_ - 1);

  float wq[F_][D_], wk[F_][D_], wv[F_][D_], bqv[D_], bkv[D_], bvv[D_];
#pragma unroll
  for (int f = 0; f < F_; ++f)
#pragma unroll
    for (int d = 0; d < D_; ++d) {
      wq[f][d] = ldc(Wq, (h * F_ + f) * D_ + d);
      wk[f][d] = ldc(Wk, (h * F_ + f) * D_ + d);
      wv[f][d] = ldc(Wv, (h * F_ + f) * D_ + d);
    }
#pragma unroll
  for (int d = 0; d < D_; ++d) {
    bqv[d] = ldc(bq, h * D_ + d);
    bkv[d] = ldc(bk, h * D_ + d);
    bvv[d] = ldc(bv, h * D_ + d);
  }
  float xt0 = ldc(x, ((b * TIN_ + t) * N_ + n) * F_ + 0);
  float xt1 = ldc(x, ((b * TIN_ + t) * N_ + n) * F_ + 1);
  float q[D_];
#pragma unroll
  for (int d = 0; d < D_; ++d) q[d] = xt0 * wq[0][d] + xt1 * wq[1][d] + bqv[d];

  float sc[TIN_];
  float mx = -1e30f;
#pragma unroll
  for (int s = 0; s < TIN_; ++s) {
    float xs0 = ldc(x, ((b * TIN_ + s) * N_ + n) * F_ + 0);
    float xs1 = ldc(x, ((b * TIN_ + s) * N_ + n) * F_ + 1);
    float dot = 0.f;
#pragma unroll
    for (int d = 0; d < D_; ++d)
      dot += q[d] * (xs0 * wk[0][d] + xs1 * wk[1][d] + bkv[d]);
    dot *= SCALE;
    sc[s] = (s <= t) ? dot : -1e30f;
    mx = fmaxf(mx, sc[s]);
  }
  float sum = 0.f;
#pragma unroll
  for (int s = 0; s < TIN_; ++s) {
    float p = __expf(sc[s] - mx);
    sc[s] = p;
    sum += p;
  }
  float inv = 1.0f / sum;
  float acc[D_];
#pragma unroll
  for (int d = 0; d < D_; ++d) acc[d] = 0.f;
#pragma unroll
  for (int s = 0; s < TIN_; ++s) {
    float xs0 = ldc(x, ((b * TIN_ + s) * N_ + n) * F_ + 0);
    float xs1 = ldc(x, ((b * TIN_ + s) * N_ + n) * F_ + 1);
#pragma unroll
    for (int d = 0; d < D_; ++d)
      acc[d] += sc[s] * (xs0 * wv[0][d] + xs1 * wv[1][d] + bvv[d]);
  }
  bf16* o = att_t + ((size_t)((b * 11 + (t - 1)) * N_ + n)) * C_ + h * D_;
#pragma unroll
  for (int d = 0; d < D_; ++d) o[d] = __float2bfloat16(acc[d] * inv);
}
__global__ void k_temporal(const int* dtf, const void* x, const void* Wq, const void* Wk,
                           const void* Wv, const void* bq, const void* bk, const void* bv,
                           bf16* att_t) {
  if (*dtf)
    temporal_body<float>((const float*)x, (const float*)Wq, (const float*)Wk, (const float*)Wv,
                         (const float*)bq, (const float*)bk, (const float*)bv, att_t);
  else
    temporal_body<bf16>((const bf16*)x, (const bf16*)Wq, (const bf16*)Wk, (const bf16*)Wv,
                        (const bf16*)bq, (const bf16*)bk, (const bf16*)bv, att_t);
}

// ---------------- Kernel B: spatial attention, rank-2 form ----------------
#define ST_TILES 8
#define ST_ROWS 100
#define ST_MS 8
#define ST_MLEN 100
template <typename TI>
__device__ __forceinline__ void spatial2_body(
    const TI* x, const TI* Wq, const TI* Wk, const TI* Wv,
    const TI* bq, const TI* bk, const TI* bv, bf16* att_st) {
  __shared__ float2 xs[N_];
  __shared__ float M[H_][9];
  __shared__ float Vw[H_][3][D_];
  __shared__ float pt[ST_MS][ST_ROWS][19];
  int tile = blockIdx.x, ty = blockIdx.y, b = blockIdx.z;
  int t = ty + 1;
  int tid = threadIdx.x;

  for (int m = tid; m < N_; m += 832)
    xs[m] = make_float2(ldc(x, ((b * TIN_ + t) * N_ + m) * F_ + 0),
                        ldc(x, ((b * TIN_ + t) * N_ + m) * F_ + 1));
  if (tid < 54) {
    int h = tid / 9, e = tid % 9, a = e / 3, bb = e % 3;
    float acc = 0.f;
    for (int d = 0; d < 8; ++d) {
      float qa = (a == 0) ? ldc(Wq, (h * 2 + 0) * 8 + d)
               : (a == 1) ? ldc(Wq, (h * 2 + 1) * 8 + d) : ldc(bq, h * 8 + d);
      float kb = (bb == 0) ? ldc(Wk, (h * 2 + 0) * 8 + d)
               : (bb == 1) ? ldc(Wk, (h * 2 + 1) * 8 + d) : ldc(bk, h * 8 + d);
      acc += qa * kb;
    }
    M[h][e] = acc * SCALE * LOG2E;
  }
  if (tid >= 64 && tid < 64 + 144) {
    int e = tid - 64;
    int h = e / 24, a = (e % 24) / 8, d = e % 8;
    Vw[h][a][d] = (a == 0) ? ldc(Wv, (h * 2 + 0) * 8 + d)
                : (a == 1) ? ldc(Wv, (h * 2 + 1) * 8 + d) : ldc(bv, h * 8 + d);
  }
  __syncthreads();
  if (tid < ST_ROWS * ST_MS) {
    int ms = tid / ST_ROWS, nl = tid % ST_ROWS;
    int n = tile * ST_ROWS + nl;
    float x0 = xs[n].x, x1 = xs[n].y;
    float A[6], Bc[6], Cc[6];
#pragma unroll
    for (int h = 0; h < 6; ++h) {
      A[h]  = M[h][0] * x0 + M[h][3] * x1 + M[h][6];
      Bc[h] = M[h][1] * x0 + M[h][4] * x1 + M[h][7];
      Cc[h] = M[h][2] * x0 + M[h][5] * x1 + M[h][8];
    }
    float Sp[6] = {0, 0, 0, 0, 0, 0}, S0[6] = {0, 0, 0, 0, 0, 0}, S1[6] = {0, 0, 0, 0, 0, 0};
    for (int m = ms * ST_MLEN; m < ms * ST_MLEN + ST_MLEN; ++m) {
      float2 xm = xs[m];
#pragma unroll
      for (int h = 0; h < 6; ++h) {
        float p = exp2_(A[h] * xm.x + Bc[h] * xm.y + Cc[h]);
        Sp[h] += p;
        S0[h] += p * xm.x;
        S1[h] += p * xm.y;
      }
    }
#pragma unroll
    for (int h = 0; h < 6; ++h) {
      pt[ms][nl][h * 3 + 0] = Sp[h];
      pt[ms][nl][h * 3 + 1] = S0[h];
      pt[ms][nl][h * 3 + 2] = S1[h];
    }
  }
  __syncthreads();
  if (tid < ST_ROWS) {
    int n = tile * ST_ROWS + tid;
    bf16* o = att_st + ((size_t)((b * 11 + ty) * N_ + n)) * C_;
#pragma unroll
    for (int h = 0; h < 6; ++h) {
      float Sp = 0.f, S0 = 0.f, S1 = 0.f;
#pragma unroll
      for (int ms = 0; ms < ST_MS; ++ms) {
        Sp += pt[ms][tid][h * 3 + 0];
        S0 += pt[ms][tid][h * 3 + 1];
        S1 += pt[ms][tid][h * 3 + 2];
      }
      float inv = 1.f / Sp;
#pragma unroll
      for (int d = 0; d < 8; ++d)
        o[h * 8 + d] = __float2bfloat16((S0 * Vw[h][0][d] + S1 * Vw[h][1][d] + Sp * Vw[h][2][d]) * inv);
    }
  }
}
__global__ __launch_bounds__(832) void k_spatial2(
    const int* dtf, const void* x, const void* Wq, const void* Wk, const void* Wv,
    const void* bq, const void* bk, const void* bv, bf16* att_st) {
  if (*dtf)
    spatial2_body<float>((const float*)x, (const float*)Wq, (const float*)Wk, (const float*)Wv,
                         (const float*)bq, (const float*)bk, (const float*)bv, att_st);
  else
    spatial2_body<bf16>((const bf16*)x, (const bf16*)Wq, (const bf16*)Wk, (const bf16*)Wv,
                        (const bf16*)bq, (const bf16*)bk, (const bf16*)bv, att_st);
}

// ---------------- Kernel C: proj + encoder x-parts ------------------------
template <typename TI>
__device__ __forceinline__ void projx_body(
    const bf16* att_t, const bf16* att_st,
    const TI* Wpt, const TI* bpt, const TI* Wps, const TI* bps,
    const TI* xhr_wz, const TI* xhr_wr, const TI* xhr_wh,
    const TI* xhr_bz, const TI* xhr_br, const TI* xhr_bh,
    bf16* encx) {
  __shared__ unsigned short raw[64][96];
  __shared__ float catS[64][100];
  __shared__ float Wp[2][48][48];
  int tile = blockIdx.x, ty = blockIdx.y, b = blockIdx.z;
  int t = ty + 1;
  int tid = threadIdx.x;
  int rw = tid / 12, jl = tid % 12;

  for (int p = 0; p < 24; ++p) {
    int e = tid + p * 192;
    int half = e / 2304, k = (e % 2304) / 48, i = e % 48;
    Wp[half][k][i] = half ? ldc(Wps, k * 48 + i) : ldc(Wpt, k * 48 + i);
  }
  for (int p = 0; p < 32; ++p) {
    int e = tid + p * 192;
    int rr = e / 96, c = e % 96;
    int n = tile * 64 + rr; if (n > 799) n = 799;
    size_t base = ((size_t)((b * 11 + ty) * N_ + n)) * C_;
    bf16 v = (c < 48) ? att_t[base + c] : att_st[base + (c - 48)];
    raw[rr][c] = __bfloat16_as_ushort(v);
  }
  __syncthreads();
  {
    int half = (jl >= 6);
    int ii0 = jl * 8 - half * 48;
    float acc[4][8];
#pragma unroll
    for (int q = 0; q < 4; ++q)
#pragma unroll
      for (int m = 0; m < 8; ++m)
        acc[q][m] = half ? ldc(bps, ii0 + m) : ldc(bpt, ii0 + m);
    for (int k = 0; k < 48; ++k) {
      float rv[4];
#pragma unroll
      for (int q = 0; q < 4; ++q)
        rv[q] = __uint_as_float((unsigned)raw[rw * 4 + q][half * 48 + k] << 16);
      const float4 wa = *(const float4*)&Wp[half][k][ii0];
      const float4 wb = *(const float4*)&Wp[half][k][ii0 + 4];
      float w8[8] = {wa.x, wa.y, wa.z, wa.w, wb.x, wb.y, wb.z, wb.w};
#pragma unroll
      for (int q = 0; q < 4; ++q)
#pragma unroll
        for (int m = 0; m < 8; ++m) acc[q][m] += rv[q] * w8[m];
    }
#pragma unroll
    for (int q = 0; q < 4; ++q) {
      *(float4*)&catS[rw * 4 + q][jl * 8] = make_float4(acc[q][0], acc[q][1], acc[q][2], acc[q][3]);
      *(float4*)&catS[rw * 4 + q][jl * 8 + 4] = make_float4(acc[q][4], acc[q][5], acc[q][6], acc[q][7]);
    }
  }
  __syncthreads();
  {
    int j0r = jl * 12;
    int g = j0r / 48, jj0 = j0r % 48;
    const TI* wx = (g == 0) ? xhr_wz : (g == 1) ? xhr_wr : xhr_wh;
    const TI* bx = (g == 0) ? xhr_bz : (g == 1) ? xhr_br : xhr_bh;
    float acc[4][12];
#pragma unroll
    for (int q = 0; q < 4; ++q)
#pragma unroll
      for (int m = 0; m < 12; ++m) acc[q][m] = 0.f;
    for (int i = 0; i < 96; ++i) {
      float w12[12];
      size_t wb = ((size_t)t * 144 + i) * 48 + jj0;
      ld4(wx, wb, w12); ld4(wx, wb + 4, w12 + 4); ld4(wx, wb + 8, w12 + 8);
      float cv[4];
#pragma unroll
      for (int q = 0; q < 4; ++q) cv[q] = catS[rw * 4 + q][i];
#pragma unroll
      for (int q = 0; q < 4; ++q)
#pragma unroll
        for (int m = 0; m < 12; ++m) acc[q][m] += cv[q] * w12[m];
    }
#pragma unroll
    for (int q = 0; q < 4; ++q) {
      int n = tile * 64 + rw * 4 + q;
      if (n < 800) {
        float v[12];
#pragma unroll
        for (int m = 0; m < 12; ++m)
          v[m] = acc[q][m] + ldc(bx, ((size_t)t * N_ + n) * C_ + jj0 + m);
        size_t ob = ((size_t)((b * 11 + ty) * N_ + n)) * 144 + j0r;
        st4s(encx, ob, v); st4s(encx, ob + 4, v + 4); st4s(encx, ob + 8, v + 8);
      }
    }
  }
}
__global__ __launch_bounds__(192) void k_projx(
    const int* dtf, const bf16* att_t, const bf16* att_st,
    const void* Wpt, const void* bpt, const void* Wps, const void* bps,
    const void* xwz, const void* xwr, const void* xwh,
    const void* xbz, const void* xbr, const void* xbh, bf16* encx) {
  if (*dtf)
    projx_body<float>(att_t, att_st, (const float*)Wpt, (const float*)bpt, (const float*)Wps,
                      (const float*)bps, (const float*)xwz, (const float*)xwr, (const float*)xwh,
                      (const float*)xbz, (const float*)xbr, (const float*)xbh, encx);
  else
    projx_body<bf16>(att_t, att_st, (const bf16*)Wpt, (const bf16*)bpt, (const bf16*)Wps,
                     (const bf16*)bps, (const bf16*)xwz, (const bf16*)xwr, (const bf16*)xwh,
                     (const bf16*)xbz, (const bf16*)xbr, (const bf16*)xbh, encx);
}

// ---------------- Kernel D: conv1 + decoder x-parts -----------------------
template <typename TI>
__device__ __forceinline__ void convx_body(
    const TI* x, const TI* T,
    const TI* conv1_w, const TI* conv1_b,
    const TI* lwz, const TI* lwr, const TI* lwh,
    const TI* lbz, const TI* lbr, const TI* lbh,
    bf16* decx) {
  __shared__ float tpw[64][KW_][2];
  __shared__ float cw[2][KW_][48];
  __shared__ float preS[64][48];
  __shared__ float Wlx[48][144];
  int tile = blockIdx.x, t = blockIdx.y, b = blockIdx.z;
  int tid = threadIdx.x;
  int rw = tid / 12, jl = tid % 12;

  for (int p = 0; p < 7; ++p) {
    int e = tid + p * 192;
    int f = e / (KW_ * 48), rem = e % (KW_ * 48), k = rem / 48, c = rem % 48;
    cw[f][k][c] = ldc(conv1_w, (c * F_ + f) * KW_ + k);
  }
  for (int p = 0; p < 10; ++p) {
    int e = tid + p * 192;
    if (e < 64 * KW_ * 2) {
      int rr = e / (KW_ * 2), rem = e % (KW_ * 2), k = rem / 2, f = rem % 2;
      int n = tile * 64 + rr; if (n > 799) n = 799;
      int tau = t + k;
      float v;
      if (tau < TIN_) v = ldc(x, ((size_t)(b * TIN_ + tau) * N_ + n) * F_ + f);
      else if (tau < TIN_ + TP_) v = (f == 0) ? 0.f : ldc(T, (size_t)(b * TP_ + (tau - TIN_)) * N_ + n);
      else v = ldc(x, ((size_t)(b * TIN_ + 0) * N_ + n) * F_ + f);
      tpw[rr][k][f] = v;
    }
  }
  for (int p = 0; p < 36; ++p) {
    int e = tid + p * 192;
    int i = e / 144, jg = e % 144, g = jg / 48, j = jg % 48;
    const TI* w = (g == 0) ? lwz : (g == 1) ? lwr : lwh;
    Wlx[i][jg] = ldc(w, ((size_t)t * 96 + i) * 48 + j);
  }
  __syncthreads();
  {
    int c0 = jl * 4;
    float acc[4][4];
#pragma unroll
    for (int q = 0; q < 4; ++q)
#pragma unroll
      for (int m = 0; m < 4; ++m) acc[q][m] = ldc(conv1_b, c0 + m);
#pragma unroll
    for (int f = 0; f < 2; ++f)
      for (int k = 0; k < KW_; ++k) {
        const float4 w4 = *(const float4*)&cw[f][k][c0];
        float wv[4] = {w4.x, w4.y, w4.z, w4.w};
#pragma unroll
        for (int q = 0; q < 4; ++q) {
          float tv = tpw[rw * 4 + q][k][f];
#pragma unroll
          for (int m = 0; m < 4; ++m) acc[q][m] += tv * wv[m];
        }
      }
#pragma unroll
    for (int q = 0; q < 4; ++q)
      *(float4*)&preS[rw * 4 + q][c0] = make_float4(acc[q][0], acc[q][1], acc[q][2], acc[q][3]);
  }
  __syncthreads();
  {
    int j0r = jl * 12;
    int g = j0r / 48, jj0 = j0r % 48;
    const TI* bx = (g == 0) ? lbz : (g == 1) ? lbr : lbh;
    float acc[4][12];
#pragma unroll
    for (int q = 0; q < 4; ++q)
#pragma unroll
      for (int m = 0; m < 12; ++m) acc[q][m] = 0.f;
    for (int i = 0; i < 48; ++i) {
      const float4 wa = *(const float4*)&Wlx[i][j0r];
      const float4 wb = *(const float4*)&Wlx[i][j0r + 4];
      const float4 wc = *(const float4*)&Wlx[i][j0r + 8];
      float w12[12] = {wa.x, wa.y, wa.z, wa.w, wb.x, wb.y, wb.z, wb.w, wc.x, wc.y, wc.z, wc.w};
      float pv[4];
#pragma unroll
      for (int q = 0; q < 4; ++q) pv[q] = preS[rw * 4 + q][i];
#pragma unroll
      for (int q = 0; q < 4; ++q)
#pragma unroll
        for (int m = 0; m < 12; ++m) acc[q][m] += pv[q] * w12[m];
    }
#pragma unroll
    for (int q = 0; q < 4; ++q) {
      int n = tile * 64 + rw * 4 + q;
      if (n < 800) {
        float v[12];
#pragma unroll
        for (int m = 0; m < 12; ++m)
          v[m] = acc[q][m] + ldc(bx, ((size_t)t * N_ + n) * C_ + jj0 + m);
        size_t ob = ((size_t)((b * TP_ + t) * N_ + n)) * 144 + j0r;
        st4s(decx, ob, v); st4s(decx, ob + 4, v + 4); st4s(decx, ob + 8, v + 8);
      }
    }
  }
}
__global__ __launch_bounds__(192) void k_convx(
    const int* dtf, const void* x, const void* T, const void* cw, const void* cb,
    const void* lwz, const void* lwr, const void* lwh,
    const void* lbz, const void* lbr, const void* lbh, bf16* decx) {
  if (*dtf)
    convx_body<float>((const float*)x, (const float*)T, (const float*)cw, (const float*)cb,
                      (const float*)lwz, (const float*)lwr, (const float*)lwh,
                      (const float*)lbz, (const float*)lbr, (const float*)lbh, decx);
  else
    convx_body<bf16>((const bf16*)x, (const bf16*)T, (const bf16*)cw, (const bf16*)cb,
                     (const bf16*)lwz, (const bf16*)lwr, (const bf16*)lwh,
                     (const bf16*)lbz, (const bf16*)lbr, (const bf16*)lbh, decx);
}

// ---------------- Kernel E: MFMA GRU (1 wave = 16 rows, 100 blocks) -------
// Per gate per step: D(16x48) = h(16x48 bf16) * W(48x48 bf16) via 3 N-tiles
// x 2 K-chunks of mfma_f32_16x16x32_bf16, C initialized with x-parts.
// h kept in C-layout f32 regs (col=lane&15, row=(lane>>4)*4+reg); C->A
// transpose via 2.3KB LDS tile (wave-internal, fence-ordered, no barriers).
// Weight B-fragments prefetched from pre-packed global right after last use.
template <typename TI, typename TO>
__device__ __forceinline__ void gru5_body(
    const bf16* encx, const bf16* decx, const unsigned short* pwb,
    const TI* Wout, const TI* bout, TO* out) {
  __shared__ alignas(16) unsigned short hT[16][72];   // pitch 72 bf16 = 144B
  __shared__ alignas(16) unsigned short rhT[16][72];
  int l = threadIdx.x;          // 64
  int cg = l >> 4, cl = l & 15; // k-group / col
  int blk = blockIdx.x;
  int b = blk / 50;
  int n0 = (blk % 50) * 16;

  for (int e = l; e < 16 * 72; e += 64) { (&hT[0][0])[e] = 0; (&rhT[0][0])[e] = 0; }
  float wo[3], bo = ldc(bout, 0);
#pragma unroll
  for (int nt = 0; nt < 3; ++nt) wo[nt] = ldc(Wout, nt * 16 + cl);

  float ho[3][4];
#pragma unroll
  for (int nt = 0; nt < 3; ++nt)
#pragma unroll
    for (int r = 0; r < 4; ++r) ho[nt][r] = 0.f;

  s8b wz[3][2], wr[3][2], wh[3][2];
  float xz[3][4], xr[3][4], xh[3][4];
  {  // load step 0 weights + x-parts
    const unsigned short* pb = pwb + (size_t)l * 8;
#pragma unroll
    for (int nt = 0; nt < 3; ++nt)
#pragma unroll
      for (int c = 0; c < 2; ++c) {
        wz[nt][c] = *(const s8b*)(pb + 0 * 9216 + nt * 3072 + c * 1536);
        wr[nt][c] = *(const s8b*)(pb + 1 * 9216 + nt * 3072 + c * 1536);
        wh[nt][c] = *(const s8b*)(pb + 2 * 9216 + nt * 3072 + c * 1536);
      }
    size_t rb = (size_t)(b * 11) * 800;
#pragma unroll
    for (int nt = 0; nt < 3; ++nt)
#pragma unroll
      for (int r = 0; r < 4; ++r) {
        size_t rowoff = (rb + n0 + cg * 4 + r) * 144;
        xz[nt][r] = ldc(encx, rowoff + 0 + nt * 16 + cl);
        xr[nt][r] = ldc(encx, rowoff + 48 + nt * 16 + cl);
        xh[nt][r] = ldc(encx, rowoff + 96 + nt * 16 + cl);
      }
  }
  asm volatile("" ::: "memory");  // hT zero-fill ordered before A-frag reads

  for (int step = 0; step < 21; ++step) {
    // h A-fragments (chunk0: k 0..31, chunk1: k 32..63 with 48..63 zero pad)
    s8b hA0 = *(const s8b*)&hT[cl][cg * 8];
    s8b hA1 = *(const s8b*)&hT[cl][32 + cg * 8];
    f4 az[3], ar[3];
#pragma unroll
    for (int nt = 0; nt < 3; ++nt) {
      f4 cz = {xz[nt][0], xz[nt][1], xz[nt][2], xz[nt][3]};
      cz = __builtin_amdgcn_mfma_f32_16x16x32_bf16(hA0, wz[nt][0], cz, 0, 0, 0);
      cz = __builtin_amdgcn_mfma_f32_16x16x32_bf16(hA1, wz[nt][1], cz, 0, 0, 0);
      az[nt] = cz;
      f4 cr = {xr[nt][0], xr[nt][1], xr[nt][2], xr[nt][3]};
      cr = __builtin_amdgcn_mfma_f32_16x16x32_bf16(hA0, wr[nt][0], cr, 0, 0, 0);
      cr = __builtin_amdgcn_mfma_f32_16x16x32_bf16(hA1, wr[nt][1], cr, 0, 0, 0);
      ar[nt] = cr;
    }
    if (step < 20) {  // prefetch next wz/wr into just-freed regs
      const unsigned short* pb = pwb + (size_t)(step + 1) * 27648 + (size_t)l * 8;
#pragma unroll
      for (int nt = 0; nt < 3; ++nt)
#pragma unroll
        for (int c = 0; c < 2; ++c) {
          wz[nt][c] = *(const s8b*)(pb + 0 * 9216 + nt * 3072 + c * 1536);
          wr[nt][c] = *(const s8b*)(pb + 1 * 9216 + nt * 3072 + c * 1536);
        }
    }
    float z[3][4];
#pragma unroll
    for (int nt = 0; nt < 3; ++nt)
#pragma unroll
      for (int r = 0; r < 4; ++r) {
        z[nt][r] = sigm(az[nt][r]);
        float rv = sigm(ar[nt][r]) * ho[nt][r];
        rhT[cg * 4 + r][nt * 16 + cl] = __bfloat16_as_ushort(__float2bfloat16(rv));
      }
    asm volatile("" ::: "memory");  // rh writes ordered before rh A-frag reads
    s8b rA0 = *(const s8b*)&rhT[cl][cg * 8];
    s8b rA1 = *(const s8b*)&rhT[cl][32 + cg * 8];
    f4 ah[3];
#pragma unroll
    for (int nt = 0; nt < 3; ++nt) {
      f4 ch = {xh[nt][0], xh[nt][1], xh[nt][2], xh[nt][3]};
      ch = __builtin_amdgcn_mfma_f32_16x16x32_bf16(rA0, wh[nt][0], ch, 0, 0, 0);
      ch = __builtin_amdgcn_mfma_f32_16x16x32_bf16(rA1, wh[nt][1], ch, 0, 0, 0);
      ah[nt] = ch;
    }
    if (step < 20) {  // prefetch next wh + x-parts
      const unsigned short* pb = pwb + (size_t)(step + 1) * 27648 + (size_t)l * 8;
#pragma unroll
      for (int nt = 0; nt < 3; ++nt)
#pragma unroll
        for (int c = 0; c < 2; ++c)
          wh[nt][c] = *(const s8b*)(pb + 2 * 9216 + nt * 3072 + c * 1536);
      int s1 = step + 1;
      const bf16* ex = (s1 < 11) ? encx : decx;
      size_t rb = (s1 < 11) ? (size_t)(b * 11 + s1) * 800
                            : (size_t)(b * 10 + (s1 - 11)) * 800;
#pragma unroll
      for (int nt = 0; nt < 3; ++nt)
#pragma unroll
        for (int r = 0; r < 4; ++r) {
          size_t rowoff = (rb + n0 + cg * 4 + r) * 144;
          xz[nt][r] = ldc(ex, rowoff + 0 + nt * 16 + cl);
          xr[nt][r] = ldc(ex, rowoff + 48 + nt * 16 + cl);
          xh[nt][r] = ldc(ex, rowoff + 96 + nt * 16 + cl);
        }
    }
    float pout[4] = {0.f, 0.f, 0.f, 0.f};
#pragma unroll
    for (int nt = 0; nt < 3; ++nt)
#pragma unroll
      for (int r = 0; r < 4; ++r) {
        float hn = (1.f - z[nt][r]) * ho[nt][r] + z[nt][r] * tanh_(ah[nt][r]);
        ho[nt][r] = hn;
        hT[cg * 4 + r][nt * 16 + cl] = __bfloat16_as_ushort(__float2bfloat16(hn));
        pout[r] += hn * wo[nt];
      }
    if (step >= 11) {
#pragma unroll
      for (int r = 0; r < 4; ++r) {
        float p = pout[r];
        p += __shfl_xor(p, 1);
        p += __shfl_xor(p, 2);
        p += __shfl_xor(p, 4);
        p += __shfl_xor(p, 8);
        if (cl == 0)
          sto(out, ((size_t)b * TP_ + (step - 11)) * N_ + n0 + cg * 4 + r, p + bo);
      }
    }
    asm volatile("" ::: "memory");  // h writes ordered before next-step reads
  }
}
__global__ __launch_bounds__(64) void k_gru5(
    const int* dtf, const bf16* encx, const bf16* decx, const bf16* pwb,
    const void* Wout, const void* bout, void* out) {
  if (*dtf)
    gru5_body<float, float>(encx, decx, (const unsigned short*)pwb,
                            (const float*)Wout, (const float*)bout, (float*)out);
  else
    gru5_body<bf16, bf16>(encx, decx, (const unsigned short*)pwb,
                          (const bf16*)Wout, (const bf16*)bout, (bf16*)out);
}

// ---------------------------------------------------------------------------
extern "C" void kernel_launch(void* const* d_in, const int* in_sizes, int n_in,
                              void* d_out, int out_size, void* d_ws, size_t ws_size,
                              hipStream_t stream) {
  (void)in_sizes; (void)n_in; (void)out_size; (void)ws_size;
  const void* x       = d_in[0];
  const void* T       = d_in[1];
  const void* Wq_t    = d_in[3];
  const void* Wk_t    = d_in[4];
  const void* Wv_t    = d_in[5];
  const void* Wq_st   = d_in[6];
  const void* Wk_st   = d_in[7];
  const void* Wv_st   = d_in[8];
  const void* bq_t    = d_in[9];
  const void* bk_t    = d_in[10];
  const void* bv_t    = d_in[11];
  const void* bq_st   = d_in[12];
  const void* bk_st   = d_in[13];
  const void* bv_st   = d_in[14];
  const void* conv1_w = d_in[15];
  const void* conv1_b = d_in[16];
  const void* Wproj_t = d_in[17];
  const void* bproj_t = d_in[18];
  const void* Wproj_st= d_in[19];
  const void* bproj_st= d_in[20];
  const void* xhr_wz  = d_in[21];
  const void* xhr_wr  = d_in[22];
  const void* xhr_wh  = d_in[23];
  const void* xhr_bz  = d_in[24];
  const void* xhr_br  = d_in[25];
  const void* xhr_bh  = d_in[26];
  const void* last_wz = d_in[27];
  const void* last_wr = d_in[28];
  const void* last_wh = d_in[29];
  const void* last_bz = d_in[30];
  const void* last_br = d_in[31];
  const void* last_bh = d_in[32];
  const void* Wout    = d_in[33];
  const void* bout    = d_in[34];

  // ws layout (~14.2 MB; 14.75 MB proven safe in round 2)
  char* wsb = (char*)d_ws;
  int* dtf     = (int*)wsb;                              // 256 B
  bf16* att_t  = (bf16*)(wsb + 256);                     // 2*11*800*48
  bf16* att_st = att_t + (size_t)2 * 11 * 800 * 48;
  bf16* encx   = att_st + (size_t)2 * 11 * 800 * 48;     // 2*11*800*144
  bf16* decx   = encx + (size_t)2 * 11 * 800 * 144;      // 2*10*800*144
  bf16* pwb    = decx + (size_t)2 * 10 * 800 * 144;      // 21*27648 bf16 fragments

  k_detect<<<1, 64, 0, stream>>>((const unsigned int*)x, dtf);
  k_pack<<<(21 * 27648 + 255) / 256, 256, 0, stream>>>(
      dtf, xhr_wz, xhr_wr, xhr_wh, last_wz, last_wr, last_wh, pwb);
  {
    int total = B_ * (TIN_ - 1) * H_ * N_;
    k_temporal<<<(total + 255) / 256, 256, 0, stream>>>(
        dtf, x, Wq_t, Wk_t, Wv_t, bq_t, bk_t, bv_t, att_t);
  }
  k_spatial2<<<dim3(ST_TILES, 11, 2), 832, 0, stream>>>(
      dtf, x, Wq_st, Wk_st, Wv_st, bq_st, bk_st, bv_st, att_st);
  k_projx<<<dim3(13, 11, 2), 192, 0, stream>>>(
      dtf, att_t, att_st, Wproj_t, bproj_t, Wproj_st, bproj_st,
      xhr_wz, xhr_wr, xhr_wh, xhr_bz, xhr_br, xhr_bh, encx);
  k_convx<<<dim3(13, 10, 2), 192, 0, stream>>>(
      dtf, x, T, conv1_w, conv1_b, last_wz, last_wr, last_wh,
      last_bz, last_br, last_bh, decx);
  k_gru5<<<100, 64, 0, stream>>>(
      dtf, encx, decx, pwb, Wout, bout, d_out);
}